// Round 6
// baseline (542.266 us; speedup 1.0000x reference)
//
#include <hip/hip_runtime.h>
#include <hip/hip_bf16.h>

typedef unsigned short u16;
typedef unsigned int u32;

#define NXg 784
#define NYg 480
constexpr int N0c = NXg * NYg;   // 376320
constexpr int N1c = N0c / 4;     // 94080
constexpr int N2c = N0c / 16;    // 23520
constexpr int NTc = N0c + N1c + N2c;
constexpr int E0c = 4 * N0c;     // 1505280
constexpr int E1c = 4 * N1c;     // 376320
constexpr int E2c = 4 * N2c;     // 94080
constexpr int Etot = E0c + E1c + E2c;
constexpr int P0c = E0c + 3 * N0c;
constexpr int P1c = E1c + 3 * N1c;
constexpr int P2c = E2c + 3 * N2c;
constexpr int Ptot = P0c + P1c + P2c;
constexpr int NB0 = (N0c + 1023) / 1024;   // 368
constexpr int NB1 = (N1c + 1023) / 1024;   // 92
constexpr int NB2 = (N2c + 1023) / 1024;   // 23
constexpr int NBt = NB0 + NB1 + NB2;       // 483

__device__ __forceinline__ float bf2f(u16 v) {
    union { u32 u; float f; } t; t.u = ((u32)v) << 16; return t.f;
}
__device__ __forceinline__ u16 f2bf(float f) {
    union { float f; u32 u; } t; t.f = f;
    u32 u = t.u;
    u32 r = (u + 0x7fffu + ((u >> 16) & 1u)) >> 16;   // RNE
    return (u16)r;
}
__device__ __forceinline__ float rdf(const void* p, int i, int isf32) {
    if (isf32) return ((const float*)p)[i];
    return bf2f(((const u16*)p)[i]);
}

// ---- ys storage traits: fp32 or bf16 ----
struct F32S {
    typedef float T;
    static __device__ __forceinline__ float ld(const T* p, size_t i) { return p[i]; }
    static __device__ __forceinline__ void st(T* p, size_t i, float v) { p[i] = v; }
};
struct BF16S {
    typedef u16 T;
    static __device__ __forceinline__ float ld(const T* p, size_t i) { return bf2f(p[i]); }
    static __device__ __forceinline__ void st(T* p, size_t i, float v) { p[i] = f2bf(v); }
};

__device__ __forceinline__ void lvl_of_bin(int b, int& lv, int& bl) {
    if (b < NB0) { lv = 0; bl = b; }
    else if (b < NB0 + NB1) { lv = 1; bl = b - NB0; }
    else { lv = 2; bl = b - NB0 - NB1; }
}

// ------------- dtype detection -------------
__global__ void k_detect(const u32* __restrict__ xw, int* __restrict__ flag) {
    __shared__ int cnt;
    if (threadIdx.x == 0) cnt = 0;
    __syncthreads();
    u32 w = xw[threadIdx.x];
    int e = (int)((w >> 7) & 0xFFu);
    int hit = ((e >= 90 && e <= 135) || ((w & 0x7FFFu) == 0u)) ? 1 : 0;
    atomicAdd(&cnt, hit);
    __syncthreads();
    if (threadIdx.x == 0) *flag = (cnt < 192) ? 1 : 0;   // 1 => fp32 inputs
}

// ------------- init: zero bin counters + ys dummy rows -------------
__global__ void k_init(int* __restrict__ binCnt, u16* __restrict__ y0,
                       float* __restrict__ y1, float* __restrict__ y2) {
    int t = blockIdx.x * blockDim.x + threadIdx.x;
    if (t < NBt) binCnt[t] = 0;
    if (t < 32) { y0[t] = 0; y1[t] = 0.0f; y2[t] = 0.0f; }
}

// ------------- phase A: bin counts -------------
__global__ void kA_count(const int* __restrict__ ei0, const int* __restrict__ ei1,
                         const int* __restrict__ ei2, int* __restrict__ binCnt) {
    __shared__ int lc[NB0];
    int b = blockIdx.x, t = threadIdx.x;
    int lv, bl; lvl_of_bin(b, lv, bl);
    const int* dstp; int E, nb, binB;
    if (lv == 0) { dstp = ei0 + E0c; E = E0c; nb = NB0; binB = 0; }
    else if (lv == 1) { dstp = ei1 + E1c; E = E1c; nb = NB1; binB = NB0; }
    else { dstp = ei2 + E2c; E = E2c; nb = NB2; binB = NB0 + NB1; }
    for (int i = t; i < nb; i += 256) lc[i] = 0;
    __syncthreads();
    int e0 = bl * 4096, e1 = min(E, e0 + 4096);
    for (int i = e0 + t; i < e1; i += 256) atomicAdd(&lc[dstp[i] >> 10], 1);
    __syncthreads();
    for (int i = t; i < nb; i += 256) if (lc[i]) atomicAdd(&binCnt[binB + i], lc[i]);
}

// ------------- phase B: scan bin counts -------------
__global__ void kB_scan(const int* __restrict__ binCnt, int* __restrict__ binStart,
                        int* __restrict__ binCursor) {
    __shared__ int s[512];
    int t = threadIdx.x;
    int v = (t < NBt) ? binCnt[t] : 0;
    s[t] = v;
    __syncthreads();
    for (int off = 1; off < 512; off <<= 1) {
        int x = (t >= off) ? s[t - off] : 0;
        __syncthreads();
        s[t] += x;
        __syncthreads();
    }
    if (t < NBt) { int e = s[t] - v; binStart[t] = e; binCursor[t] = e; }
    if (t == 0) binStart[NBt] = Etot;
}

// ------------- phase C: place (src,dst) into bin regions -------------
__global__ void kC_place(const int* __restrict__ ei0, const int* __restrict__ ei1,
                         const int* __restrict__ ei2, int* __restrict__ binCursor,
                         int2* __restrict__ BE) {
    __shared__ int lc[NB0];
    __shared__ int lb[NB0];
    int b = blockIdx.x, t = threadIdx.x;
    int lv, bl; lvl_of_bin(b, lv, bl);
    const int* srcp; const int* dstp; int E, nb, binB;
    if (lv == 0) { srcp = ei0; dstp = ei0 + E0c; E = E0c; nb = NB0; binB = 0; }
    else if (lv == 1) { srcp = ei1; dstp = ei1 + E1c; E = E1c; nb = NB1; binB = NB0; }
    else { srcp = ei2; dstp = ei2 + E2c; E = E2c; nb = NB2; binB = NB0 + NB1; }
    for (int i = t; i < nb; i += 256) lc[i] = 0;
    __syncthreads();
    int e0 = bl * 4096, e1 = min(E, e0 + 4096);
    for (int i = e0 + t; i < e1; i += 256) atomicAdd(&lc[dstp[i] >> 10], 1);
    __syncthreads();
    for (int i = t; i < nb; i += 256) {
        int c = lc[i];
        lb[i] = c ? atomicAdd(&binCursor[binB + i], c) : 0;
        lc[i] = 0;
    }
    __syncthreads();
    for (int i = e0 + t; i < e1; i += 256) {
        int d = dstp[i];
        int bn = d >> 10;
        int p = atomicAdd(&lc[bn], 1);
        BE[lb[bn] + p] = make_int2(srcp[i], d);
    }
}

// ------------- phase D1: per-bin node counts -> CNT, DINV, padded bin total -------------
__global__ void kD1_count(const int2* __restrict__ BE, const int* __restrict__ binStart,
                          int* __restrict__ CNT, float* __restrict__ DINV,
                          int* __restrict__ binPadTot) {
    __shared__ int lc[1024];
    __shared__ int red[256];
    int b = blockIdx.x, t = threadIdx.x;
    int lv, bl; lvl_of_bin(b, lv, bl);
    int cbase, nLev;
    if (lv == 0) { cbase = 0; nLev = N0c; }
    else if (lv == 1) { cbase = N0c; nLev = N1c; }
    else { cbase = N0c + N1c; nLev = N2c; }
    for (int i = t; i < 1024; i += 256) lc[i] = 0;
    __syncthreads();
    int s0 = binStart[b], s1 = binStart[b + 1];
    for (int i = s0 + t; i < s1; i += 256) {
        int2 e = BE[i];
        atomicAdd(&lc[e.y & 1023], 1);
    }
    __syncthreads();
    int nodeB = bl << 10;
    int ps = 0;
#pragma unroll
    for (int j = 0; j < 4; j++) {
        int li = t * 4 + j;
        int node = nodeB + li;
        if (node < nLev) {
            int c = lc[li];
            CNT[cbase + node] = c;
            DINV[cbase + node] = rsqrtf((float)c + 1.0f);
            ps += (c + 3) & ~3;
        }
    }
    red[t] = ps;
    __syncthreads();
    for (int off = 128; off > 0; off >>= 1) {
        if (t < off) red[t] += red[t + off];
        __syncthreads();
    }
    if (t == 0) binPadTot[b] = red[0];
}

// ------------- phase D2: scan padded bin totals -------------
__global__ void kD2_scan(const int* __restrict__ binPadTot, int* __restrict__ binPadStart) {
    __shared__ int s[512];
    __shared__ int tot0, tot01;
    int t = threadIdx.x;
    int v = (t < NBt) ? binPadTot[t] : 0;
    s[t] = v;
    __syncthreads();
    for (int off = 1; off < 512; off <<= 1) {
        int x = (t >= off) ? s[t - off] : 0;
        __syncthreads();
        s[t] += x;
        __syncthreads();
    }
    if (t == 0) { tot0 = s[NB0 - 1]; tot01 = s[NB0 + NB1 - 1]; }
    __syncthreads();
    if (t < NBt) {
        int ex = s[t] - v;
        int cb, sub;
        if (t < NB0) { cb = 0; sub = 0; }
        else if (t < NB0 + NB1) { cb = P0c; sub = tot0; }
        else { cb = P0c + P1c; sub = tot01; }
        binPadStart[t] = cb + ex - sub;
    }
}

// ------------- phase D3: per-bin rowptr + COL scatter -------------
__global__ void kD3_final(const int2* __restrict__ BE, const int* __restrict__ binStart,
                          const int* __restrict__ CNT, const int* __restrict__ binPadStart,
                          int* __restrict__ rowptr, int* __restrict__ colAll) {
    __shared__ int lst[1024];
    __shared__ int lcur[1024];
    __shared__ int red[256];
    int b = blockIdx.x, t = threadIdx.x;
    int lv, bl; lvl_of_bin(b, lv, bl);
    int cbase, nLev, dummy;
    if (lv == 0) { cbase = 0; nLev = N0c; dummy = N0c; }
    else if (lv == 1) { cbase = N0c; nLev = N1c; dummy = N1c; }
    else { cbase = N0c + N1c; nLev = N2c; dummy = N2c; }
    int nodeB = bl << 10;
    int pc[4];
    int ps = 0;
#pragma unroll
    for (int j = 0; j < 4; j++) {
        int li = t * 4 + j;
        int node = nodeB + li;
        int c = (node < nLev) ? CNT[cbase + node] : 0;
        pc[j] = (c + 3) & ~3;
        ps += pc[j];
    }
    red[t] = ps;
    __syncthreads();
    for (int off = 1; off < 256; off <<= 1) {
        int x = (t >= off) ? red[t - off] : 0;
        __syncthreads();
        red[t] += x;
        __syncthreads();
    }
    int ex = red[t] - ps;
    int tot = red[255];
    int off = ex;
#pragma unroll
    for (int j = 0; j < 4; j++) {
        int li = t * 4 + j;
        lst[li] = off;
        lcur[li] = off;
        off += pc[j];
    }
    int cb = binPadStart[b];
#pragma unroll
    for (int j = 0; j < 4; j++) {
        int li = t * 4 + j;
        int node = nodeB + li;
        if (node < nLev) rowptr[cbase + node] = cb + lst[li];
    }
    __syncthreads();
    for (int i = t; i < tot; i += 256) colAll[cb + i] = dummy;
    __syncthreads();
    int s0 = binStart[b], s1 = binStart[b + 1];
    for (int i = s0 + t; i < s1; i += 256) {
        int2 e = BE[i];
        int p = atomicAdd(&lcur[e.y & 1023], 1);
        colAll[cb + p] = e.x;
    }
}

// ---------------- gather core ----------------
template <class SIn>
__device__ __forceinline__ float gather4(const typename SIn::T* __restrict__ ys,
                                         const int* __restrict__ rp,
                                         const int* __restrict__ cnt,
                                         const int* __restrict__ col,
                                         const float* __restrict__ dinv,
                                         int node, int c) {
    int s0 = rp[node];
    int nch = (cnt[node] + 3) >> 2;
    float a = SIn::ld(ys, (size_t)node * 32 + c);
    const int4* c4 = (const int4*)(col + s0);
    for (int i = 0; i < nch; i++) {
        int4 cs = c4[i];
        float a0 = SIn::ld(ys, (size_t)cs.x * 32 + c);
        float a1 = SIn::ld(ys, (size_t)cs.y * 32 + c);
        float a2 = SIn::ld(ys, (size_t)cs.z * 32 + c);
        float a3 = SIn::ld(ys, (size_t)cs.w * 32 + c);
        a += (a0 + a1) + (a2 + a3);
    }
    return a * dinv[node];
}

// ---------------- K1: fc1 + relu + prep1 -> bf16 ys ----------------
__global__ void k_fc1prep(const void* __restrict__ x, const void* __restrict__ fw,
                          const void* __restrict__ fb, const void* __restrict__ w1,
                          const float* __restrict__ d0, u16* __restrict__ ys1,
                          const int* __restrict__ flag) {
    int isf32 = *flag;
    __shared__ float sx[32];
    __shared__ float sh[256];
    int t = threadIdx.x;
    int nodeBase = blockIdx.x * 8;
    if (t < 32) sx[t] = rdf(x, nodeBase * 4 + t, isf32);
    __syncthreads();
    int local = t >> 5, c = t & 31;
    float a = rdf(fb, c, isf32);
#pragma unroll
    for (int k = 0; k < 4; k++) a = fmaf(sx[local * 4 + k], rdf(fw, k * 32 + c, isf32), a);
    sh[t] = fmaxf(a, 0.0f);
    __syncthreads();
    float s = 0.0f;
#pragma unroll
    for (int k = 0; k < 32; k++) s = fmaf(sh[local * 32 + k], rdf(w1, k * 32 + c, isf32), s);
    int node = nodeBase + local;
    BF16S::st(ys1, (size_t)node * 32 + c, s * d0[node]);
}

// ---------------- K2/K3: gather + relu -> O; fused prep_next on downsample ----------------
template <class SIn, class SOut>
__global__ void k_gds(const typename SIn::T* __restrict__ ys_in, const int* __restrict__ rp,
                      const int* __restrict__ cnt, const int* __restrict__ col,
                      const float* __restrict__ dinv_p, const void* __restrict__ b,
                      float* __restrict__ O, const void* __restrict__ wn,
                      const float* __restrict__ dinv_c, typename SOut::T* __restrict__ ys_out,
                      int cols, const int* __restrict__ flag) {
    int isf32 = *flag;
    __shared__ float sv[256];
    int t = threadIdx.x;
    int nodeBase = blockIdx.x * 8;
    int local = t >> 5, c = t & 31;
    int node = nodeBase + local;
    float v = fmaxf(gather4<SIn>(ys_in, rp, cnt, col, dinv_p, node, c) + rdf(b, c, isf32), 0.0f);
    O[(size_t)node * 32 + c] = v;
    sv[t] = v;
    __syncthreads();
    int rb = nodeBase / cols;
    if (!(rb & 1) && t < 128) {
        int row = t >> 5;
        int lc = row * 2;
        int cc = (nodeBase - rb * cols) + lc;
        int dn = (rb >> 1) * (cols >> 1) + (cc >> 1);
        int ci = t & 31;
        float a = 0.0f;
#pragma unroll
        for (int k = 0; k < 32; k++) a = fmaf(sv[lc * 32 + k], rdf(wn, k * 32 + ci, isf32), a);
        SOut::st(ys_out, (size_t)dn * 32 + ci, a * dinv_c[dn]);
    }
}

// ---------------- K4/K5: gather + up-residual + prep_next for 4 children ----------------
template <class SIn, class SOut>
__global__ void k_gup(const typename SIn::T* __restrict__ ys_in, const int* __restrict__ rp,
                      const int* __restrict__ cnt, const int* __restrict__ col,
                      const float* __restrict__ dinv_p, const void* __restrict__ b,
                      const float* __restrict__ R, const void* __restrict__ wn,
                      const float* __restrict__ dinv_c, typename SOut::T* __restrict__ ys_out,
                      int cols_p, const int* __restrict__ flag) {
    int isf32 = *flag;
    __shared__ float sv[256];
    __shared__ float sch[1024];
    int t = threadIdx.x;
    int nodeBase = blockIdx.x * 8;
    int local = t >> 5, c = t & 31;
    int node = nodeBase + local;
    float v = fmaxf(gather4<SIn>(ys_in, rp, cnt, col, dinv_p, node, c) + rdf(b, c, isf32), 0.0f);
    sv[t] = v;
    __syncthreads();
    int rb = nodeBase / cols_p;
    int ccb = nodeBase - rb * cols_p;
    int cols_c = cols_p * 2;
#pragma unroll
    for (int i = 0; i < 4; i++) {
        int item = t + i * 256;
        int row = item >> 5, k = item & 31;
        int lp = row >> 2, j = row & 3;
        int ch = (2 * rb + (j >> 1)) * cols_c + 2 * (ccb + lp) + (j & 1);
        sch[item] = R[(size_t)ch * 32 + k] + sv[lp * 32 + k];
    }
    __syncthreads();
#pragma unroll
    for (int i = 0; i < 4; i++) {
        int item = t + i * 256;
        int row = item >> 5, ci = item & 31;
        int lp = row >> 2, j = row & 3;
        int ch = (2 * rb + (j >> 1)) * cols_c + 2 * (ccb + lp) + (j & 1);
        float a = 0.0f;
#pragma unroll
        for (int k = 0; k < 32; k++) a = fmaf(sch[row * 32 + k], rdf(wn, k * 32 + ci, isf32), a);
        SOut::st(ys_out, (size_t)ch * 32 + ci, a * dinv_c[ch]);
    }
}

// ---------------- K6: gather + relu + fc2 -> out ----------------
__global__ void k_gfc2(const u16* __restrict__ ys, const int* __restrict__ rp,
                       const int* __restrict__ cnt, const int* __restrict__ col,
                       const float* __restrict__ dinv, const void* __restrict__ b5,
                       const void* __restrict__ fw, const void* __restrict__ fb,
                       void* __restrict__ out, int n, const int* __restrict__ flag) {
    int isf32 = *flag;
    __shared__ float sv[256];
    __shared__ float sw[96];
    __shared__ float sfb[3];
    int t = threadIdx.x;
    if (t < 96) sw[t] = rdf(fw, t, isf32);
    if (t < 3) sfb[t] = rdf(fb, t, isf32);
    int node = blockIdx.x * 8 + (t >> 5);
    int c = t & 31;
    float v = fmaxf(gather4<BF16S>(ys, rp, cnt, col, dinv, node, c) + rdf(b5, c, isf32), 0.0f);
    sv[t] = v;
    __syncthreads();
    if (t < 24) {
        int ln = t / 3, j = t - ln * 3;
        int gn = blockIdx.x * 8 + ln;
        float o = sfb[j];
#pragma unroll
        for (int k = 0; k < 32; k++) o = fmaf(sv[ln * 32 + k], sw[k * 3 + j], o);
        if (isf32) ((float*)out)[(size_t)gn * 3 + j] = o;
        else ((u16*)out)[(size_t)gn * 3 + j] = f2bf(o);
    }
}

extern "C" void kernel_launch(void* const* d_in, const int* in_sizes, int n_in,
                              void* d_out, int out_size, void* d_ws, size_t ws_size,
                              hipStream_t stream) {
    const void* x    = d_in[0];
    const void* fc1w = d_in[1];
    const void* fc1b = d_in[2];
    const void* w1 = d_in[3];  const void* b1 = d_in[4];
    const void* w2 = d_in[5];  const void* b2 = d_in[6];
    const void* w3 = d_in[7];  const void* b3 = d_in[8];
    const void* w4 = d_in[9];  const void* b4 = d_in[10];
    const void* w5 = d_in[11]; const void* b5 = d_in[12];
    const void* fc2w = d_in[13]; const void* fc2b = d_in[14];
    const int* ei0 = (const int*)d_in[18];
    const int* ei1 = (const int*)d_in[19];
    const int* ei2 = (const int*)d_in[20];

    // layout (all offsets keep 16B alignment for COLA int4 reads)
    u16* YS0 = (u16*)d_ws;                              // (N0+1)*32 u16
    float* A    = (float*)(YS0 + (size_t)(N0c + 1) * 32); // N0*32 f32
    float* YS1  = A   + (size_t)N0c * 32;                 // (N1+1)*32
    float* H1   = YS1 + (size_t)(N1c + 1) * 32;           // N1*32
    float* YS2  = H1  + (size_t)N1c * 32;                 // (N2+1)*32
    float* DINV = YS2 + (size_t)(N2c + 1) * 32;           // NT
    int* CNT   = (int*)(DINV + NTc);                      // NT
    int* RPA   = CNT + NTc;                               // NT
    int* COLA  = RPA + NTc;                               // Ptot
    int2* BE   = (int2*)(COLA + Ptot);                    // Etot
    int* binCnt      = (int*)(BE + Etot);
    int* binStart    = binCnt + NBt;
    int* binCursor   = binStart + NBt + 1;
    int* binPadTot   = binCursor + NBt;
    int* binPadStart = binPadTot + NBt;
    int* FLAG        = binPadStart + NBt;

    float* D0 = DINV; float* D1 = D0 + N0c; float* D2 = D1 + N1c;
    int* C0 = CNT;  int* C1 = C0 + N0c;  int* C2 = C1 + N1c;
    int* RP0 = RPA; int* RP1 = RP0 + N0c; int* RP2 = RP1 + N1c;

    const int Bk = 256;

    k_detect<<<1, 256, 0, stream>>>((const u32*)x, FLAG);
    k_init<<<2, 256, 0, stream>>>(binCnt, YS0 + (size_t)N0c * 32,
                                  YS1 + (size_t)N1c * 32, YS2 + (size_t)N2c * 32);

    // binned CSR build
    kA_count<<<NBt, Bk, 0, stream>>>(ei0, ei1, ei2, binCnt);
    kB_scan<<<1, 512, 0, stream>>>(binCnt, binStart, binCursor);
    kC_place<<<NBt, Bk, 0, stream>>>(ei0, ei1, ei2, binCursor, BE);
    kD1_count<<<NBt, Bk, 0, stream>>>(BE, binStart, CNT, DINV, binPadTot);
    kD2_scan<<<1, 512, 0, stream>>>(binPadTot, binPadStart);
    kD3_final<<<NBt, Bk, 0, stream>>>(BE, binStart, CNT, binPadStart, RPA, COLA);

    // K1: fc1+relu+prep1 -> YS0 (bf16)
    k_fc1prep<<<N0c / 8, Bk, 0, stream>>>(x, fc1w, fc1b, w1, D0, YS0, FLAG);
    // K2: gather1(bf16 ys) -> A, fused prep2 -> YS1 (f32)
    k_gds<BF16S, F32S><<<N0c / 8, Bk, 0, stream>>>(YS0, RP0, C0, COLA, D0, b1, A, w2, D1, YS1, NYg, FLAG);
    // K3: gather2 -> H1, fused prep3 -> YS2 (f32)
    k_gds<F32S, F32S><<<N1c / 8, Bk, 0, stream>>>(YS1, RP1, C1, COLA, D1, b2, H1, w3, D2, YS2, NYg / 2, FLAG);
    // K4: gather3 + up-residual(H1) + prep4 -> YS1 (f32)
    k_gup<F32S, F32S><<<N2c / 8, Bk, 0, stream>>>(YS2, RP2, C2, COLA, D2, b3, H1, w4, D1, YS1, NYg / 4, FLAG);
    // K5: gather4 + up-residual(A) + prep5 -> YS0 (bf16)
    k_gup<F32S, BF16S><<<N1c / 8, Bk, 0, stream>>>(YS1, RP1, C1, COLA, D1, b4, A, w5, D0, YS0, NYg / 2, FLAG);
    // K6: gather5(bf16 ys) + fc2 -> out
    k_gfc2<<<N0c / 8, Bk, 0, stream>>>(YS0, RP0, C0, COLA, D0, b5, fc2w, fc2b, d_out, N0c, FLAG);
}

// Round 7
// 497.997 us; speedup vs baseline: 1.0889x; 1.0889x over previous
//
#include <hip/hip_runtime.h>
#include <hip/hip_bf16.h>

typedef unsigned short u16;
typedef unsigned int u32;

#define NXg 784
#define NYg 480
constexpr int N0c = NXg * NYg;   // 376320
constexpr int N1c = N0c / 4;     // 94080
constexpr int N2c = N0c / 16;    // 23520
constexpr int NTc = N0c + N1c + N2c;
constexpr int E0c = 4 * N0c;
constexpr int E1c = 4 * N1c;
constexpr int E2c = 4 * N2c;
constexpr int Etot = E0c + E1c + E2c;
constexpr int P0c = E0c + 3 * N0c;
constexpr int P1c = E1c + 3 * N1c;
constexpr int P2c = E2c + 3 * N2c;
constexpr int Ptot = P0c + P1c + P2c;
constexpr int NB0 = (N0c + 1023) / 1024;   // 368
constexpr int NB1 = (N1c + 1023) / 1024;   // 92
constexpr int NB2 = (N2c + 1023) / 1024;   // 23
constexpr int NBt = NB0 + NB1 + NB2;       // 483

__device__ __forceinline__ float bf2f(u16 v) {
    union { u32 u; float f; } t; t.u = ((u32)v) << 16; return t.f;
}
__device__ __forceinline__ u16 f2bf(float f) {
    union { float f; u32 u; } t; t.f = f;
    u32 u = t.u;
    u32 r = (u + 0x7fffu + ((u >> 16) & 1u)) >> 16;   // RNE
    return (u16)r;
}
__device__ __forceinline__ float rdf(const void* p, int i, int isf32) {
    if (isf32) return ((const float*)p)[i];
    return bf2f(((const u16*)p)[i]);
}
// stage n floats from a flag-dtyped buffer into LDS (single branch, coalesced)
__device__ __forceinline__ void stage(float* dst, const void* src, int n, int isf32) {
    int t = threadIdx.x;
    if (isf32) {
        const float* s = (const float*)src;
        for (int i = t; i < n; i += 256) dst[i] = s[i];
    } else {
        const u16* s = (const u16*)src;
        for (int i = t; i < n; i += 256) dst[i] = bf2f(s[i]);
    }
}

// ---- ys storage traits ----
struct F32S {
    typedef float T;
    static __device__ __forceinline__ float ld(const T* p, size_t i) { return p[i]; }
    static __device__ __forceinline__ void st(T* p, size_t i, float v) { p[i] = v; }
};
struct BF16S {
    typedef u16 T;
    static __device__ __forceinline__ float ld(const T* p, size_t i) { return bf2f(p[i]); }
    static __device__ __forceinline__ void st(T* p, size_t i, float v) { p[i] = f2bf(v); }
};

__device__ __forceinline__ void lvl_of_bin(int b, int& lv, int& bl) {
    if (b < NB0) { lv = 0; bl = b; }
    else if (b < NB0 + NB1) { lv = 1; bl = b - NB0; }
    else { lv = 2; bl = b - NB0 - NB1; }
}

// ------------- dtype detection -------------
__global__ void k_detect(const u32* __restrict__ xw, int* __restrict__ flag) {
    __shared__ int cnt;
    if (threadIdx.x == 0) cnt = 0;
    __syncthreads();
    u32 w = xw[threadIdx.x];
    int e = (int)((w >> 7) & 0xFFu);
    int hit = ((e >= 90 && e <= 135) || ((w & 0x7FFFu) == 0u)) ? 1 : 0;
    atomicAdd(&cnt, hit);
    __syncthreads();
    if (threadIdx.x == 0) *flag = (cnt < 192) ? 1 : 0;
}

// ------------- init -------------
__global__ void k_init(int* __restrict__ binCnt, u16* __restrict__ y0,
                       float* __restrict__ y1, float* __restrict__ y2) {
    int t = blockIdx.x * blockDim.x + threadIdx.x;
    if (t < NBt) binCnt[t] = 0;
    if (t < 32) { y0[t] = 0; y1[t] = 0.0f; y2[t] = 0.0f; }
}

// ------------- phase A: bin counts -------------
__global__ void kA_count(const int* __restrict__ ei0, const int* __restrict__ ei1,
                         const int* __restrict__ ei2, int* __restrict__ binCnt) {
    __shared__ int lc[NB0];
    int b = blockIdx.x, t = threadIdx.x;
    int lv, bl; lvl_of_bin(b, lv, bl);
    const int* dstp; int E, nb, binB;
    if (lv == 0) { dstp = ei0 + E0c; E = E0c; nb = NB0; binB = 0; }
    else if (lv == 1) { dstp = ei1 + E1c; E = E1c; nb = NB1; binB = NB0; }
    else { dstp = ei2 + E2c; E = E2c; nb = NB2; binB = NB0 + NB1; }
    for (int i = t; i < nb; i += 256) lc[i] = 0;
    __syncthreads();
    int e0 = bl * 4096, e1 = min(E, e0 + 4096);
    for (int i = e0 + t; i < e1; i += 256) atomicAdd(&lc[dstp[i] >> 10], 1);
    __syncthreads();
    for (int i = t; i < nb; i += 256) if (lc[i]) atomicAdd(&binCnt[binB + i], lc[i]);
}

// ------------- phase B -------------
__global__ void kB_scan(const int* __restrict__ binCnt, int* __restrict__ binStart,
                        int* __restrict__ binCursor) {
    __shared__ int s[512];
    int t = threadIdx.x;
    int v = (t < NBt) ? binCnt[t] : 0;
    s[t] = v;
    __syncthreads();
    for (int off = 1; off < 512; off <<= 1) {
        int x = (t >= off) ? s[t - off] : 0;
        __syncthreads();
        s[t] += x;
        __syncthreads();
    }
    if (t < NBt) { int e = s[t] - v; binStart[t] = e; binCursor[t] = e; }
    if (t == 0) binStart[NBt] = Etot;
}

// ------------- phase C -------------
__global__ void kC_place(const int* __restrict__ ei0, const int* __restrict__ ei1,
                         const int* __restrict__ ei2, int* __restrict__ binCursor,
                         int2* __restrict__ BE) {
    __shared__ int lc[NB0];
    __shared__ int lb[NB0];
    int b = blockIdx.x, t = threadIdx.x;
    int lv, bl; lvl_of_bin(b, lv, bl);
    const int* srcp; const int* dstp; int E, nb, binB;
    if (lv == 0) { srcp = ei0; dstp = ei0 + E0c; E = E0c; nb = NB0; binB = 0; }
    else if (lv == 1) { srcp = ei1; dstp = ei1 + E1c; E = E1c; nb = NB1; binB = NB0; }
    else { srcp = ei2; dstp = ei2 + E2c; E = E2c; nb = NB2; binB = NB0 + NB1; }
    for (int i = t; i < nb; i += 256) lc[i] = 0;
    __syncthreads();
    int e0 = bl * 4096, e1 = min(E, e0 + 4096);
    for (int i = e0 + t; i < e1; i += 256) atomicAdd(&lc[dstp[i] >> 10], 1);
    __syncthreads();
    for (int i = t; i < nb; i += 256) {
        int c = lc[i];
        lb[i] = c ? atomicAdd(&binCursor[binB + i], c) : 0;
        lc[i] = 0;
    }
    __syncthreads();
    for (int i = e0 + t; i < e1; i += 256) {
        int d = dstp[i];
        int bn = d >> 10;
        int p = atomicAdd(&lc[bn], 1);
        BE[lb[bn] + p] = make_int2(srcp[i], d);
    }
}

// ------------- phase D1 -------------
__global__ void kD1_count(const int2* __restrict__ BE, const int* __restrict__ binStart,
                          int* __restrict__ CNT, float* __restrict__ DINV,
                          int* __restrict__ binPadTot) {
    __shared__ int lc[1024];
    __shared__ int red[256];
    int b = blockIdx.x, t = threadIdx.x;
    int lv, bl; lvl_of_bin(b, lv, bl);
    int cbase, nLev;
    if (lv == 0) { cbase = 0; nLev = N0c; }
    else if (lv == 1) { cbase = N0c; nLev = N1c; }
    else { cbase = N0c + N1c; nLev = N2c; }
    for (int i = t; i < 1024; i += 256) lc[i] = 0;
    __syncthreads();
    int s0 = binStart[b], s1 = binStart[b + 1];
    for (int i = s0 + t; i < s1; i += 256) {
        int2 e = BE[i];
        atomicAdd(&lc[e.y & 1023], 1);
    }
    __syncthreads();
    int nodeB = bl << 10;
    int ps = 0;
#pragma unroll
    for (int j = 0; j < 4; j++) {
        int li = t * 4 + j;
        int node = nodeB + li;
        if (node < nLev) {
            int c = lc[li];
            CNT[cbase + node] = c;
            DINV[cbase + node] = rsqrtf((float)c + 1.0f);
            ps += (c + 3) & ~3;
        }
    }
    red[t] = ps;
    __syncthreads();
    for (int off = 128; off > 0; off >>= 1) {
        if (t < off) red[t] += red[t + off];
        __syncthreads();
    }
    if (t == 0) binPadTot[b] = red[0];
}

// ------------- phase D2 -------------
__global__ void kD2_scan(const int* __restrict__ binPadTot, int* __restrict__ binPadStart) {
    __shared__ int s[512];
    __shared__ int tot0, tot01;
    int t = threadIdx.x;
    int v = (t < NBt) ? binPadTot[t] : 0;
    s[t] = v;
    __syncthreads();
    for (int off = 1; off < 512; off <<= 1) {
        int x = (t >= off) ? s[t - off] : 0;
        __syncthreads();
        s[t] += x;
        __syncthreads();
    }
    if (t == 0) { tot0 = s[NB0 - 1]; tot01 = s[NB0 + NB1 - 1]; }
    __syncthreads();
    if (t < NBt) {
        int ex = s[t] - v;
        int cb, sub;
        if (t < NB0) { cb = 0; sub = 0; }
        else if (t < NB0 + NB1) { cb = P0c; sub = tot0; }
        else { cb = P0c + P1c; sub = tot01; }
        binPadStart[t] = cb + ex - sub;
    }
}

// ------------- phase D3 -------------
__global__ void kD3_final(const int2* __restrict__ BE, const int* __restrict__ binStart,
                          const int* __restrict__ CNT, const int* __restrict__ binPadStart,
                          int* __restrict__ rowptr, int* __restrict__ colAll) {
    __shared__ int lst[1024];
    __shared__ int lcur[1024];
    __shared__ int red[256];
    int b = blockIdx.x, t = threadIdx.x;
    int lv, bl; lvl_of_bin(b, lv, bl);
    int cbase, nLev, dummy;
    if (lv == 0) { cbase = 0; nLev = N0c; dummy = N0c; }
    else if (lv == 1) { cbase = N0c; nLev = N1c; dummy = N1c; }
    else { cbase = N0c + N1c; nLev = N2c; dummy = N2c; }
    int nodeB = bl << 10;
    int pc[4];
    int ps = 0;
#pragma unroll
    for (int j = 0; j < 4; j++) {
        int li = t * 4 + j;
        int node = nodeB + li;
        int c = (node < nLev) ? CNT[cbase + node] : 0;
        pc[j] = (c + 3) & ~3;
        ps += pc[j];
    }
    red[t] = ps;
    __syncthreads();
    for (int off = 1; off < 256; off <<= 1) {
        int x = (t >= off) ? red[t - off] : 0;
        __syncthreads();
        red[t] += x;
        __syncthreads();
    }
    int ex = red[t] - ps;
    int tot = red[255];
    int off = ex;
#pragma unroll
    for (int j = 0; j < 4; j++) {
        int li = t * 4 + j;
        lst[li] = off;
        lcur[li] = off;
        off += pc[j];
    }
    int cb = binPadStart[b];
#pragma unroll
    for (int j = 0; j < 4; j++) {
        int li = t * 4 + j;
        int node = nodeB + li;
        if (node < nLev) rowptr[cbase + node] = cb + lst[li];
    }
    __syncthreads();
    for (int i = t; i < tot; i += 256) colAll[cb + i] = dummy;
    __syncthreads();
    int s0 = binStart[b], s1 = binStart[b + 1];
    for (int i = s0 + t; i < s1; i += 256) {
        int2 e = BE[i];
        int p = atomicAdd(&lcur[e.y & 1023], 1);
        colAll[cb + p] = e.x;
    }
}

// ---------------- gather core ----------------
template <class SIn>
__device__ __forceinline__ float gather4(const typename SIn::T* __restrict__ ys,
                                         const int* __restrict__ rp,
                                         const int* __restrict__ cnt,
                                         const int* __restrict__ col,
                                         const float* __restrict__ dinv,
                                         int node, int c) {
    int s0 = rp[node];
    int nch = (cnt[node] + 3) >> 2;
    float a = SIn::ld(ys, (size_t)node * 32 + c);
    const int4* c4 = (const int4*)(col + s0);
    for (int i = 0; i < nch; i++) {
        int4 cs = c4[i];
        float a0 = SIn::ld(ys, (size_t)cs.x * 32 + c);
        float a1 = SIn::ld(ys, (size_t)cs.y * 32 + c);
        float a2 = SIn::ld(ys, (size_t)cs.z * 32 + c);
        float a3 = SIn::ld(ys, (size_t)cs.w * 32 + c);
        a += (a0 + a1) + (a2 + a3);
    }
    return a * dinv[node];
}

// ---------------- K1: fc1 + relu + prep1 -> bf16 ys (weights in LDS) ----------------
__global__ void k_fc1prep(const void* __restrict__ x, const void* __restrict__ fw,
                          const void* __restrict__ fb, const void* __restrict__ w1,
                          const float* __restrict__ d0, u16* __restrict__ ys1,
                          const int* __restrict__ flag) {
    int isf32 = *flag;
    __shared__ float sx[32];
    __shared__ float sh[256];
    __shared__ float sfw[128];
    __shared__ float sfb[32];
    __shared__ float sw1[1024];
    int t = threadIdx.x;
    int nodeBase = blockIdx.x * 8;
    stage(sw1, w1, 1024, isf32);
    stage(sfw, fw, 128, isf32);
    if (t < 32) {
        sx[t] = rdf(x, nodeBase * 4 + t, isf32);
        sfb[t] = rdf(fb, t, isf32);
    }
    __syncthreads();
    int local = t >> 5, c = t & 31;
    float a = sfb[c];
#pragma unroll
    for (int k = 0; k < 4; k++) a = fmaf(sx[local * 4 + k], sfw[k * 32 + c], a);
    sh[t] = fmaxf(a, 0.0f);
    __syncthreads();
    float s = 0.0f;
#pragma unroll
    for (int k = 0; k < 32; k++) s = fmaf(sh[local * 32 + k], sw1[k * 32 + c], s);
    int node = nodeBase + local;
    BF16S::st(ys1, (size_t)node * 32 + c, s * d0[node]);
}

// ---------------- K2/K3: gather + relu -> O; fused prep_next (weights in LDS) ----------------
template <class SIn, class SOut>
__global__ void k_gds(const typename SIn::T* __restrict__ ys_in, const int* __restrict__ rp,
                      const int* __restrict__ cnt, const int* __restrict__ col,
                      const float* __restrict__ dinv_p, const void* __restrict__ b,
                      float* __restrict__ O, const void* __restrict__ wn,
                      const float* __restrict__ dinv_c, typename SOut::T* __restrict__ ys_out,
                      int cols, const int* __restrict__ flag) {
    int isf32 = *flag;
    __shared__ float sv[256];
    __shared__ float swn[1024];
    int t = threadIdx.x;
    int nodeBase = blockIdx.x * 8;
    int rb = nodeBase / cols;
    if (!(rb & 1)) stage(swn, wn, 1024, isf32);   // block-uniform condition
    int local = t >> 5, c = t & 31;
    int node = nodeBase + local;
    float v = fmaxf(gather4<SIn>(ys_in, rp, cnt, col, dinv_p, node, c) + rdf(b, c, isf32), 0.0f);
    O[(size_t)node * 32 + c] = v;
    sv[t] = v;
    __syncthreads();
    if (!(rb & 1) && t < 128) {
        int row = t >> 5;
        int lc = row * 2;
        int cc = (nodeBase - rb * cols) + lc;
        int dn = (rb >> 1) * (cols >> 1) + (cc >> 1);
        int ci = t & 31;
        float a = 0.0f;
#pragma unroll
        for (int k = 0; k < 32; k++) a = fmaf(sv[lc * 32 + k], swn[k * 32 + ci], a);
        SOut::st(ys_out, (size_t)dn * 32 + ci, a * dinv_c[dn]);
    }
}

// ---------------- K4/K5: gather + up-residual + prep_next (weights in LDS) ----------------
template <class SIn, class SOut>
__global__ void k_gup(const typename SIn::T* __restrict__ ys_in, const int* __restrict__ rp,
                      const int* __restrict__ cnt, const int* __restrict__ col,
                      const float* __restrict__ dinv_p, const void* __restrict__ b,
                      const float* __restrict__ R, const void* __restrict__ wn,
                      const float* __restrict__ dinv_c, typename SOut::T* __restrict__ ys_out,
                      int cols_p, const int* __restrict__ flag) {
    int isf32 = *flag;
    __shared__ float sv[256];
    __shared__ float sch[1024];
    __shared__ float swn[1024];
    int t = threadIdx.x;
    int nodeBase = blockIdx.x * 8;
    stage(swn, wn, 1024, isf32);
    int local = t >> 5, c = t & 31;
    int node = nodeBase + local;
    float v = fmaxf(gather4<SIn>(ys_in, rp, cnt, col, dinv_p, node, c) + rdf(b, c, isf32), 0.0f);
    sv[t] = v;
    __syncthreads();
    int rb = nodeBase / cols_p;
    int ccb = nodeBase - rb * cols_p;
    int cols_c = cols_p * 2;
#pragma unroll
    for (int i = 0; i < 4; i++) {
        int item = t + i * 256;
        int row = item >> 5, k = item & 31;
        int lp = row >> 2, j = row & 3;
        int ch = (2 * rb + (j >> 1)) * cols_c + 2 * (ccb + lp) + (j & 1);
        sch[item] = R[(size_t)ch * 32 + k] + sv[lp * 32 + k];
    }
    __syncthreads();
#pragma unroll
    for (int i = 0; i < 4; i++) {
        int item = t + i * 256;
        int row = item >> 5, ci = item & 31;
        int lp = row >> 2, j = row & 3;
        int ch = (2 * rb + (j >> 1)) * cols_c + 2 * (ccb + lp) + (j & 1);
        float a = 0.0f;
#pragma unroll
        for (int k = 0; k < 32; k++) a = fmaf(sch[row * 32 + k], swn[k * 32 + ci], a);
        SOut::st(ys_out, (size_t)ch * 32 + ci, a * dinv_c[ch]);
    }
}

// ---------------- K6: gather + relu + fc2 -> out ----------------
__global__ void k_gfc2(const u16* __restrict__ ys, const int* __restrict__ rp,
                       const int* __restrict__ cnt, const int* __restrict__ col,
                       const float* __restrict__ dinv, const void* __restrict__ b5,
                       const void* __restrict__ fw, const void* __restrict__ fb,
                       void* __restrict__ out, int n, const int* __restrict__ flag) {
    int isf32 = *flag;
    __shared__ float sv[256];
    __shared__ float sw[96];
    __shared__ float sfb[3];
    int t = threadIdx.x;
    if (t < 96) sw[t] = rdf(fw, t, isf32);
    if (t < 3) sfb[t] = rdf(fb, t, isf32);
    int node = blockIdx.x * 8 + (t >> 5);
    int c = t & 31;
    float v = fmaxf(gather4<BF16S>(ys, rp, cnt, col, dinv, node, c) + rdf(b5, c, isf32), 0.0f);
    sv[t] = v;
    __syncthreads();
    if (t < 24) {
        int ln = t / 3, j = t - ln * 3;
        int gn = blockIdx.x * 8 + ln;
        float o = sfb[j];
#pragma unroll
        for (int k = 0; k < 32; k++) o = fmaf(sv[ln * 32 + k], sw[k * 3 + j], o);
        if (isf32) ((float*)out)[(size_t)gn * 3 + j] = o;
        else ((u16*)out)[(size_t)gn * 3 + j] = f2bf(o);
    }
}

extern "C" void kernel_launch(void* const* d_in, const int* in_sizes, int n_in,
                              void* d_out, int out_size, void* d_ws, size_t ws_size,
                              hipStream_t stream) {
    const void* x    = d_in[0];
    const void* fc1w = d_in[1];
    const void* fc1b = d_in[2];
    const void* w1 = d_in[3];  const void* b1 = d_in[4];
    const void* w2 = d_in[5];  const void* b2 = d_in[6];
    const void* w3 = d_in[7];  const void* b3 = d_in[8];
    const void* w4 = d_in[9];  const void* b4 = d_in[10];
    const void* w5 = d_in[11]; const void* b5 = d_in[12];
    const void* fc2w = d_in[13]; const void* fc2b = d_in[14];
    const int* ei0 = (const int*)d_in[18];
    const int* ei1 = (const int*)d_in[19];
    const int* ei2 = (const int*)d_in[20];

    u16* YS0 = (u16*)d_ws;                                // (N0+1)*32 u16
    float* A    = (float*)(YS0 + (size_t)(N0c + 1) * 32); // N0*32 f32
    float* YS1  = A   + (size_t)N0c * 32;
    float* H1   = YS1 + (size_t)(N1c + 1) * 32;
    float* YS2  = H1  + (size_t)N1c * 32;
    float* DINV = YS2 + (size_t)(N2c + 1) * 32;
    int* CNT   = (int*)(DINV + NTc);
    int* RPA   = CNT + NTc;
    int* COLA  = RPA + NTc;
    int2* BE   = (int2*)(COLA + Ptot);
    int* binCnt      = (int*)(BE + Etot);
    int* binStart    = binCnt + NBt;
    int* binCursor   = binStart + NBt + 1;
    int* binPadTot   = binCursor + NBt;
    int* binPadStart = binPadTot + NBt;
    int* FLAG        = binPadStart + NBt;

    float* D0 = DINV; float* D1 = D0 + N0c; float* D2 = D1 + N1c;
    int* C0 = CNT;  int* C1 = C0 + N0c;  int* C2 = C1 + N1c;
    int* RP0 = RPA; int* RP1 = RP0 + N0c; int* RP2 = RP1 + N1c;

    const int Bk = 256;

    k_detect<<<1, 256, 0, stream>>>((const u32*)x, FLAG);
    k_init<<<2, 256, 0, stream>>>(binCnt, YS0 + (size_t)N0c * 32,
                                  YS1 + (size_t)N1c * 32, YS2 + (size_t)N2c * 32);

    kA_count<<<NBt, Bk, 0, stream>>>(ei0, ei1, ei2, binCnt);
    kB_scan<<<1, 512, 0, stream>>>(binCnt, binStart, binCursor);
    kC_place<<<NBt, Bk, 0, stream>>>(ei0, ei1, ei2, binCursor, BE);
    kD1_count<<<NBt, Bk, 0, stream>>>(BE, binStart, CNT, DINV, binPadTot);
    kD2_scan<<<1, 512, 0, stream>>>(binPadTot, binPadStart);
    kD3_final<<<NBt, Bk, 0, stream>>>(BE, binStart, CNT, binPadStart, RPA, COLA);

    // K1: fc1+relu+prep1 -> YS0 (bf16)
    k_fc1prep<<<N0c / 8, Bk, 0, stream>>>(x, fc1w, fc1b, w1, D0, YS0, FLAG);
    // K2: gather1(bf16) -> A, fused prep2 -> YS1 (f32)
    k_gds<BF16S, F32S><<<N0c / 8, Bk, 0, stream>>>(YS0, RP0, C0, COLA, D0, b1, A, w2, D1, YS1, NYg, FLAG);
    // K3: gather2 -> H1, fused prep3 -> YS2 (f32)
    k_gds<F32S, F32S><<<N1c / 8, Bk, 0, stream>>>(YS1, RP1, C1, COLA, D1, b2, H1, w3, D2, YS2, NYg / 2, FLAG);
    // K4: gather3 + up-residual(H1) + prep4 -> YS1 (f32)
    k_gup<F32S, F32S><<<N2c / 8, Bk, 0, stream>>>(YS2, RP2, C2, COLA, D2, b3, H1, w4, D1, YS1, NYg / 4, FLAG);
    // K5: gather4 + up-residual(A) + prep5 -> YS0 (bf16)
    k_gup<F32S, BF16S><<<N1c / 8, Bk, 0, stream>>>(YS1, RP1, C1, COLA, D1, b4, A, w5, D0, YS0, NYg / 2, FLAG);
    // K6: gather5(bf16) + fc2 -> out
    k_gfc2<<<N0c / 8, Bk, 0, stream>>>(YS0, RP0, C0, COLA, D0, b5, fc2w, fc2b, d_out, N0c, FLAG);
}

// Round 9
// 429.522 us; speedup vs baseline: 1.2625x; 1.1594x over previous
//
#include <hip/hip_runtime.h>
#include <hip/hip_bf16.h>

typedef unsigned short u16;
typedef unsigned int u32;
typedef float fx2 __attribute__((ext_vector_type(2)));

#define NXg 784
#define NYg 480
constexpr int N0c = NXg * NYg;   // 376320
constexpr int N1c = N0c / 4;     // 94080
constexpr int N2c = N0c / 16;    // 23520
constexpr int NTc = N0c + N1c + N2c;
constexpr int E0c = 4 * N0c;
constexpr int E1c = 4 * N1c;
constexpr int E2c = 4 * N2c;
constexpr int Etot = E0c + E1c + E2c;
constexpr int P0c = E0c + 3 * N0c;
constexpr int P1c = E1c + 3 * N1c;
constexpr int P2c = E2c + 3 * N2c;
constexpr int Ptot = P0c + P1c + P2c;
constexpr int NB0 = (N0c + 1023) / 1024;   // 368
constexpr int NB1 = (N1c + 1023) / 1024;   // 92
constexpr int NB2 = (N2c + 1023) / 1024;   // 23
constexpr int NBt = NB0 + NB1 + NB2;       // 483

__device__ __forceinline__ float bf2f(u16 v) {
    union { u32 u; float f; } t; t.u = ((u32)v) << 16; return t.f;
}
__device__ __forceinline__ u16 f2bf(float f) {
    union { float f; u32 u; } t; t.f = f;
    u32 u = t.u;
    u32 r = (u + 0x7fffu + ((u >> 16) & 1u)) >> 16;   // RNE
    return (u16)r;
}
__device__ __forceinline__ float rdf(const void* p, int i, int isf32) {
    if (isf32) return ((const float*)p)[i];
    return bf2f(((const u16*)p)[i]);
}
__device__ __forceinline__ void stage(float* dst, const void* src, int n, int isf32) {
    int t = threadIdx.x;
    if (isf32) {
        const float* s = (const float*)src;
        for (int i = t; i < n; i += 256) dst[i] = s[i];
    } else {
        const u16* s = (const u16*)src;
        for (int i = t; i < n; i += 256) dst[i] = bf2f(s[i]);
    }
}

// ---- ys storage traits (scalar + 2-wide) ----
struct F32S {
    typedef float T;
    static __device__ __forceinline__ float ld(const T* p, size_t i) { return p[i]; }
    static __device__ __forceinline__ void st(T* p, size_t i, float v) { p[i] = v; }
    static __device__ __forceinline__ fx2 ld2(const T* p, size_t i) {
        return ((const fx2*)p)[i];
    }
};
struct BF16S {
    typedef u16 T;
    static __device__ __forceinline__ float ld(const T* p, size_t i) { return bf2f(p[i]); }
    static __device__ __forceinline__ void st(T* p, size_t i, float v) { p[i] = f2bf(v); }
    static __device__ __forceinline__ fx2 ld2(const T* p, size_t i) {
        u32 w = ((const u32*)p)[i];
        fx2 r; r.x = bf2f((u16)(w & 0xffffu)); r.y = bf2f((u16)(w >> 16));
        return r;
    }
};

__device__ __forceinline__ void lvl_of_bin(int b, int& lv, int& bl) {
    if (b < NB0) { lv = 0; bl = b; }
    else if (b < NB0 + NB1) { lv = 1; bl = b - NB0; }
    else { lv = 2; bl = b - NB0 - NB1; }
}

// ------------- dtype detection -------------
__global__ void k_detect(const u32* __restrict__ xw, int* __restrict__ flag) {
    __shared__ int cnt;
    if (threadIdx.x == 0) cnt = 0;
    __syncthreads();
    u32 w = xw[threadIdx.x];
    int e = (int)((w >> 7) & 0xFFu);
    int hit = ((e >= 90 && e <= 135) || ((w & 0x7FFFu) == 0u)) ? 1 : 0;
    atomicAdd(&cnt, hit);
    __syncthreads();
    if (threadIdx.x == 0) *flag = (cnt < 192) ? 1 : 0;
}

// ------------- init -------------
__global__ void k_init(int* __restrict__ binCnt, u16* __restrict__ y0,
                       float* __restrict__ y1, float* __restrict__ y2) {
    int t = blockIdx.x * blockDim.x + threadIdx.x;
    if (t < NBt) binCnt[t] = 0;
    if (t < 32) { y0[t] = 0; y1[t] = 0.0f; y2[t] = 0.0f; }
}

// ------------- phase A -------------
__global__ void kA_count(const int* __restrict__ ei0, const int* __restrict__ ei1,
                         const int* __restrict__ ei2, int* __restrict__ binCnt) {
    __shared__ int lc[NB0];
    int b = blockIdx.x, t = threadIdx.x;
    int lv, bl; lvl_of_bin(b, lv, bl);
    const int* dstp; int E, nb, binB;
    if (lv == 0) { dstp = ei0 + E0c; E = E0c; nb = NB0; binB = 0; }
    else if (lv == 1) { dstp = ei1 + E1c; E = E1c; nb = NB1; binB = NB0; }
    else { dstp = ei2 + E2c; E = E2c; nb = NB2; binB = NB0 + NB1; }
    for (int i = t; i < nb; i += 256) lc[i] = 0;
    __syncthreads();
    int e0 = bl * 4096, e1 = min(E, e0 + 4096);
    for (int i = e0 + t; i < e1; i += 256) atomicAdd(&lc[dstp[i] >> 10], 1);
    __syncthreads();
    for (int i = t; i < nb; i += 256) if (lc[i]) atomicAdd(&binCnt[binB + i], lc[i]);
}

// ------------- phase B -------------
__global__ void kB_scan(const int* __restrict__ binCnt, int* __restrict__ binStart,
                        int* __restrict__ binCursor) {
    __shared__ int s[512];
    int t = threadIdx.x;
    int v = (t < NBt) ? binCnt[t] : 0;
    s[t] = v;
    __syncthreads();
    for (int off = 1; off < 512; off <<= 1) {
        int x = (t >= off) ? s[t - off] : 0;
        __syncthreads();
        s[t] += x;
        __syncthreads();
    }
    if (t < NBt) { int e = s[t] - v; binStart[t] = e; binCursor[t] = e; }
    if (t == 0) binStart[NBt] = Etot;
}

// ------------- phase C -------------
__global__ void kC_place(const int* __restrict__ ei0, const int* __restrict__ ei1,
                         const int* __restrict__ ei2, int* __restrict__ binCursor,
                         int2* __restrict__ BE) {
    __shared__ int lc[NB0];
    __shared__ int lb[NB0];
    int b = blockIdx.x, t = threadIdx.x;
    int lv, bl; lvl_of_bin(b, lv, bl);
    const int* srcp; const int* dstp; int E, nb, binB;
    if (lv == 0) { srcp = ei0; dstp = ei0 + E0c; E = E0c; nb = NB0; binB = 0; }
    else if (lv == 1) { srcp = ei1; dstp = ei1 + E1c; E = E1c; nb = NB1; binB = NB0; }
    else { srcp = ei2; dstp = ei2 + E2c; E = E2c; nb = NB2; binB = NB0 + NB1; }
    for (int i = t; i < nb; i += 256) lc[i] = 0;
    __syncthreads();
    int e0 = bl * 4096, e1 = min(E, e0 + 4096);
    for (int i = e0 + t; i < e1; i += 256) atomicAdd(&lc[dstp[i] >> 10], 1);
    __syncthreads();
    for (int i = t; i < nb; i += 256) {
        int c = lc[i];
        lb[i] = c ? atomicAdd(&binCursor[binB + i], c) : 0;
        lc[i] = 0;
    }
    __syncthreads();
    for (int i = e0 + t; i < e1; i += 256) {
        int d = dstp[i];
        int bn = d >> 10;
        int p = atomicAdd(&lc[bn], 1);
        BE[lb[bn] + p] = make_int2(srcp[i], d);
    }
}

// ------------- phase D1 -------------
__global__ void kD1_count(const int2* __restrict__ BE, const int* __restrict__ binStart,
                          int* __restrict__ CNT, float* __restrict__ DINV,
                          int* __restrict__ binPadTot) {
    __shared__ int lc[1024];
    __shared__ int red[256];
    int b = blockIdx.x, t = threadIdx.x;
    int lv, bl; lvl_of_bin(b, lv, bl);
    int cbase, nLev;
    if (lv == 0) { cbase = 0; nLev = N0c; }
    else if (lv == 1) { cbase = N0c; nLev = N1c; }
    else { cbase = N0c + N1c; nLev = N2c; }
    for (int i = t; i < 1024; i += 256) lc[i] = 0;
    __syncthreads();
    int s0 = binStart[b], s1 = binStart[b + 1];
    for (int i = s0 + t; i < s1; i += 256) {
        int2 e = BE[i];
        atomicAdd(&lc[e.y & 1023], 1);
    }
    __syncthreads();
    int nodeB = bl << 10;
    int ps = 0;
#pragma unroll
    for (int j = 0; j < 4; j++) {
        int li = t * 4 + j;
        int node = nodeB + li;
        if (node < nLev) {
            int c = lc[li];
            CNT[cbase + node] = c;
            DINV[cbase + node] = rsqrtf((float)c + 1.0f);
            ps += (c + 3) & ~3;
        }
    }
    red[t] = ps;
    __syncthreads();
    for (int off = 128; off > 0; off >>= 1) {
        if (t < off) red[t] += red[t + off];
        __syncthreads();
    }
    if (t == 0) binPadTot[b] = red[0];
}

// ------------- phase D2 -------------
__global__ void kD2_scan(const int* __restrict__ binPadTot, int* __restrict__ binPadStart) {
    __shared__ int s[512];
    __shared__ int tot0, tot01;
    int t = threadIdx.x;
    int v = (t < NBt) ? binPadTot[t] : 0;
    s[t] = v;
    __syncthreads();
    for (int off = 1; off < 512; off <<= 1) {
        int x = (t >= off) ? s[t - off] : 0;
        __syncthreads();
        s[t] += x;
        __syncthreads();
    }
    if (t == 0) { tot0 = s[NB0 - 1]; tot01 = s[NB0 + NB1 - 1]; }
    __syncthreads();
    if (t < NBt) {
        int ex = s[t] - v;
        int cb, sub;
        if (t < NB0) { cb = 0; sub = 0; }
        else if (t < NB0 + NB1) { cb = P0c; sub = tot0; }
        else { cb = P0c + P1c; sub = tot01; }
        binPadStart[t] = cb + ex - sub;
    }
}

// ------------- phase D3 -------------
__global__ void kD3_final(const int2* __restrict__ BE, const int* __restrict__ binStart,
                          const int* __restrict__ CNT, const int* __restrict__ binPadStart,
                          int* __restrict__ rowptr, int* __restrict__ colAll) {
    __shared__ int lst[1024];
    __shared__ int lcur[1024];
    __shared__ int red[256];
    int b = blockIdx.x, t = threadIdx.x;
    int lv, bl; lvl_of_bin(b, lv, bl);
    int cbase, nLev, dummy;
    if (lv == 0) { cbase = 0; nLev = N0c; dummy = N0c; }
    else if (lv == 1) { cbase = N0c; nLev = N1c; dummy = N1c; }
    else { cbase = N0c + N1c; nLev = N2c; dummy = N2c; }
    int nodeB = bl << 10;
    int pc[4];
    int ps = 0;
#pragma unroll
    for (int j = 0; j < 4; j++) {
        int li = t * 4 + j;
        int node = nodeB + li;
        int c = (node < nLev) ? CNT[cbase + node] : 0;
        pc[j] = (c + 3) & ~3;
        ps += pc[j];
    }
    red[t] = ps;
    __syncthreads();
    for (int off = 1; off < 256; off <<= 1) {
        int x = (t >= off) ? red[t - off] : 0;
        __syncthreads();
        red[t] += x;
        __syncthreads();
    }
    int ex = red[t] - ps;
    int tot = red[255];
    int off = ex;
#pragma unroll
    for (int j = 0; j < 4; j++) {
        int li = t * 4 + j;
        lst[li] = off;
        lcur[li] = off;
        off += pc[j];
    }
    int cb = binPadStart[b];
#pragma unroll
    for (int j = 0; j < 4; j++) {
        int li = t * 4 + j;
        int node = nodeB + li;
        if (node < nLev) rowptr[cbase + node] = cb + lst[li];
    }
    __syncthreads();
    for (int i = t; i < tot; i += 256) colAll[cb + i] = dummy;
    __syncthreads();
    int s0 = binStart[b], s1 = binStart[b + 1];
    for (int i = s0 + t; i < s1; i += 256) {
        int2 e = BE[i];
        int p = atomicAdd(&lcur[e.y & 1023], 1);
        colAll[cb + p] = e.x;
    }
}

// ---------------- 2-wide gather core: thread = (node, channel-pair) ----------------
template <class SIn>
__device__ __forceinline__ fx2 gather2(const typename SIn::T* __restrict__ ys,
                                       const int* __restrict__ rp,
                                       const int* __restrict__ cnt,
                                       const int* __restrict__ col,
                                       const float* __restrict__ dinv,
                                       int node, int cp) {
    int s0 = rp[node];
    int nch = (cnt[node] + 3) >> 2;
    fx2 a = SIn::ld2(ys, (size_t)node * 16 + cp);
    const int4* c4 = (const int4*)(col + s0);
    for (int i = 0; i < nch; i++) {
        int4 cs = c4[i];
        fx2 a0 = SIn::ld2(ys, (size_t)cs.x * 16 + cp);
        fx2 a1 = SIn::ld2(ys, (size_t)cs.y * 16 + cp);
        fx2 a2 = SIn::ld2(ys, (size_t)cs.z * 16 + cp);
        fx2 a3 = SIn::ld2(ys, (size_t)cs.w * 16 + cp);
        a += (a0 + a1) + (a2 + a3);
    }
    float di = dinv[node];
    a *= di;
    return a;
}

// ---------------- K1: fc1 + relu + prep1 -> bf16 ys ----------------
__global__ void k_fc1prep(const void* __restrict__ x, const void* __restrict__ fw,
                          const void* __restrict__ fb, const void* __restrict__ w1,
                          const float* __restrict__ d0, u16* __restrict__ ys1,
                          const int* __restrict__ flag) {
    int isf32 = *flag;
    __shared__ float sx[32];
    __shared__ float sh[256];
    __shared__ float sfw[128];
    __shared__ float sfb[32];
    __shared__ float sw1[1024];
    int t = threadIdx.x;
    int nodeBase = blockIdx.x * 8;
    stage(sw1, w1, 1024, isf32);
    stage(sfw, fw, 128, isf32);
    if (t < 32) {
        sx[t] = rdf(x, nodeBase * 4 + t, isf32);
        sfb[t] = rdf(fb, t, isf32);
    }
    __syncthreads();
    int local = t >> 5, c = t & 31;
    float a = sfb[c];
#pragma unroll
    for (int k = 0; k < 4; k++) a = fmaf(sx[local * 4 + k], sfw[k * 32 + c], a);
    sh[t] = fmaxf(a, 0.0f);
    __syncthreads();
    float s = 0.0f;
#pragma unroll
    for (int k = 0; k < 32; k++) s = fmaf(sh[local * 32 + k], sw1[k * 32 + c], s);
    int node = nodeBase + local;
    BF16S::st(ys1, (size_t)node * 32 + c, s * d0[node]);
}

// ---------------- K2/K3: 16 nodes/block, 2-wide gather + relu -> O; fused prep_next ----------------
template <class SIn, class SOut>
__global__ void k_gds(const typename SIn::T* __restrict__ ys_in, const int* __restrict__ rp,
                      const int* __restrict__ cnt, const int* __restrict__ col,
                      const float* __restrict__ dinv_p, const void* __restrict__ b,
                      float* __restrict__ O, const void* __restrict__ wn,
                      const float* __restrict__ dinv_c, typename SOut::T* __restrict__ ys_out,
                      int cols, const int* __restrict__ flag) {
    int isf32 = *flag;
    __shared__ float sv[512];
    __shared__ float swn[1024];
    int t = threadIdx.x;
    int nodeBase = blockIdx.x * 16;
    int rb = nodeBase / cols;
    if (!(rb & 1)) stage(swn, wn, 1024, isf32);   // block-uniform
    int local = t >> 4, cp = t & 15;
    int node = nodeBase + local;
    fx2 g = gather2<SIn>(ys_in, rp, cnt, col, dinv_p, node, cp);
    fx2 v;
    v.x = fmaxf(g.x + rdf(b, 2 * cp, isf32), 0.0f);
    v.y = fmaxf(g.y + rdf(b, 2 * cp + 1, isf32), 0.0f);
    __builtin_nontemporal_store(v, (fx2*)O + (size_t)node * 16 + cp);
    sv[local * 32 + 2 * cp] = v.x;
    sv[local * 32 + 2 * cp + 1] = v.y;
    __syncthreads();
    if (!(rb & 1)) {
        int childIdx = t >> 5;           // 0..7
        int ci = t & 31;
        int lc = childIdx * 2;           // even local node
        int cc = (nodeBase - rb * cols) + lc;
        int dn = (rb >> 1) * (cols >> 1) + (cc >> 1);
        float a = 0.0f;
#pragma unroll
        for (int k = 0; k < 32; k++) a = fmaf(sv[lc * 32 + k], swn[k * 32 + ci], a);
        SOut::st(ys_out, (size_t)dn * 32 + ci, a * dinv_c[dn]);
    }
}

// ---------------- K4/K5: NPB parents/block, 2-wide gather + up-residual + prep_next ----------------
template <class SIn, class SOut, int NPB>
__global__ void k_gup(const typename SIn::T* __restrict__ ys_in, const int* __restrict__ rp,
                      const int* __restrict__ cnt, const int* __restrict__ col,
                      const float* __restrict__ dinv_p, const void* __restrict__ b,
                      const float* __restrict__ R, const void* __restrict__ wn,
                      const float* __restrict__ dinv_c, typename SOut::T* __restrict__ ys_out,
                      int cols_p, const int* __restrict__ flag) {
    int isf32 = *flag;
    __shared__ float sv[NPB * 32];
    __shared__ float sch[NPB * 128];
    __shared__ float swn[1024];
    int t = threadIdx.x;
    int nodeBase = blockIdx.x * NPB;
    stage(swn, wn, 1024, isf32);
    if (t < NPB * 16) {
        int local = t >> 4, cp = t & 15;
        int node = nodeBase + local;
        fx2 g = gather2<SIn>(ys_in, rp, cnt, col, dinv_p, node, cp);
        sv[local * 32 + 2 * cp] = fmaxf(g.x + rdf(b, 2 * cp, isf32), 0.0f);
        sv[local * 32 + 2 * cp + 1] = fmaxf(g.y + rdf(b, 2 * cp + 1, isf32), 0.0f);
    }
    __syncthreads();
    int rb = nodeBase / cols_p;
    int ccb = nodeBase - rb * cols_p;
    int cols_c = cols_p * 2;
#pragma unroll
    for (int i = 0; i < NPB / 2; i++) {
        int item = t + i * 256;
        int row = item >> 5, k = item & 31;
        int lp = row >> 2, j = row & 3;
        int ch = (2 * rb + (j >> 1)) * cols_c + 2 * (ccb + lp) + (j & 1);
        sch[item] = R[(size_t)ch * 32 + k] + sv[lp * 32 + k];
    }
    __syncthreads();
#pragma unroll
    for (int i = 0; i < NPB / 2; i++) {
        int item = t + i * 256;
        int row = item >> 5, ci = item & 31;
        int lp = row >> 2, j = row & 3;
        int ch = (2 * rb + (j >> 1)) * cols_c + 2 * (ccb + lp) + (j & 1);
        float a = 0.0f;
#pragma unroll
        for (int k = 0; k < 32; k++) a = fmaf(sch[row * 32 + k], swn[k * 32 + ci], a);
        SOut::st(ys_out, (size_t)ch * 32 + ci, a * dinv_c[ch]);
    }
}

// ---------------- K6: 16 nodes/block, 2-wide gather + relu + fc2 -> out ----------------
__global__ void k_gfc2(const u16* __restrict__ ys, const int* __restrict__ rp,
                       const int* __restrict__ cnt, const int* __restrict__ col,
                       const float* __restrict__ dinv, const void* __restrict__ b5,
                       const void* __restrict__ fw, const void* __restrict__ fb,
                       void* __restrict__ out, int n, const int* __restrict__ flag) {
    int isf32 = *flag;
    __shared__ float sv[512];
    __shared__ float sw[96];
    __shared__ float sfb[3];
    int t = threadIdx.x;
    if (t < 96) sw[t] = rdf(fw, t, isf32);
    if (t < 3) sfb[t] = rdf(fb, t, isf32);
    int nodeBase = blockIdx.x * 16;
    int local = t >> 4, cp = t & 15;
    int node = nodeBase + local;
    fx2 g = gather2<BF16S>(ys, rp, cnt, col, dinv, node, cp);
    sv[local * 32 + 2 * cp] = fmaxf(g.x + rdf(b5, 2 * cp, isf32), 0.0f);
    sv[local * 32 + 2 * cp + 1] = fmaxf(g.y + rdf(b5, 2 * cp + 1, isf32), 0.0f);
    __syncthreads();
    if (t < 48) {
        int ln = t / 3, j = t - ln * 3;
        int gn = nodeBase + ln;
        float o = sfb[j];
#pragma unroll
        for (int k = 0; k < 32; k++) o = fmaf(sv[ln * 32 + k], sw[k * 3 + j], o);
        if (isf32) ((float*)out)[(size_t)gn * 3 + j] = o;
        else ((u16*)out)[(size_t)gn * 3 + j] = f2bf(o);
    }
}

extern "C" void kernel_launch(void* const* d_in, const int* in_sizes, int n_in,
                              void* d_out, int out_size, void* d_ws, size_t ws_size,
                              hipStream_t stream) {
    const void* x    = d_in[0];
    const void* fc1w = d_in[1];
    const void* fc1b = d_in[2];
    const void* w1 = d_in[3];  const void* b1 = d_in[4];
    const void* w2 = d_in[5];  const void* b2 = d_in[6];
    const void* w3 = d_in[7];  const void* b3 = d_in[8];
    const void* w4 = d_in[9];  const void* b4 = d_in[10];
    const void* w5 = d_in[11]; const void* b5 = d_in[12];
    const void* fc2w = d_in[13]; const void* fc2b = d_in[14];
    const int* ei0 = (const int*)d_in[18];
    const int* ei1 = (const int*)d_in[19];
    const int* ei2 = (const int*)d_in[20];

    u16* YS0 = (u16*)d_ws;                                // (N0+1)*32 u16
    float* A    = (float*)(YS0 + (size_t)(N0c + 1) * 32); // N0*32 f32
    float* YS1  = A   + (size_t)N0c * 32;
    float* H1   = YS1 + (size_t)(N1c + 1) * 32;
    float* YS2  = H1  + (size_t)N1c * 32;
    float* DINV = YS2 + (size_t)(N2c + 1) * 32;
    int* CNT   = (int*)(DINV + NTc);
    int* RPA   = CNT + NTc;
    int* COLA  = RPA + NTc;
    int2* BE   = (int2*)(COLA + Ptot);
    int* binCnt      = (int*)(BE + Etot);
    int* binStart    = binCnt + NBt;
    int* binCursor   = binStart + NBt + 1;
    int* binPadTot   = binCursor + NBt;
    int* binPadStart = binPadTot + NBt;
    int* FLAG        = binPadStart + NBt;

    float* D0 = DINV; float* D1 = D0 + N0c; float* D2 = D1 + N1c;
    int* C0 = CNT;  int* C1 = C0 + N0c;  int* C2 = C1 + N1c;
    int* RP0 = RPA; int* RP1 = RP0 + N0c; int* RP2 = RP1 + N1c;

    const int Bk = 256;

    k_detect<<<1, 256, 0, stream>>>((const u32*)x, FLAG);
    k_init<<<2, 256, 0, stream>>>(binCnt, YS0 + (size_t)N0c * 32,
                                  YS1 + (size_t)N1c * 32, YS2 + (size_t)N2c * 32);

    kA_count<<<NBt, Bk, 0, stream>>>(ei0, ei1, ei2, binCnt);
    kB_scan<<<1, 512, 0, stream>>>(binCnt, binStart, binCursor);
    kC_place<<<NBt, Bk, 0, stream>>>(ei0, ei1, ei2, binCursor, BE);
    kD1_count<<<NBt, Bk, 0, stream>>>(BE, binStart, CNT, DINV, binPadTot);
    kD2_scan<<<1, 512, 0, stream>>>(binPadTot, binPadStart);
    kD3_final<<<NBt, Bk, 0, stream>>>(BE, binStart, CNT, binPadStart, RPA, COLA);

    // K1: fc1+relu+prep1 -> YS0 (bf16)
    k_fc1prep<<<N0c / 8, Bk, 0, stream>>>(x, fc1w, fc1b, w1, D0, YS0, FLAG);
    // K2: gather1(bf16x2) -> A, fused prep2 -> YS1 (f32)
    k_gds<BF16S, F32S><<<N0c / 16, Bk, 0, stream>>>(YS0, RP0, C0, COLA, D0, b1, A, w2, D1, YS1, NYg, FLAG);
    // K3: gather2(f32x2) -> H1, fused prep3 -> YS2 (f32)
    k_gds<F32S, F32S><<<N1c / 16, Bk, 0, stream>>>(YS1, RP1, C1, COLA, D1, b2, H1, w3, D2, YS2, NYg / 2, FLAG);
    // K4: gather3 + up-residual(H1) + prep4 -> YS1 (f32); 8 parents (120-col grid)
    k_gup<F32S, F32S, 8><<<N2c / 8, Bk, 0, stream>>>(YS2, RP2, C2, COLA, D2, b3, H1, w4, D1, YS1, NYg / 4, FLAG);
    // K5: gather4 + up-residual(A) + prep5 -> YS0 (bf16); 16 parents
    k_gup<F32S, BF16S, 16><<<N1c / 16, Bk, 0, stream>>>(YS1, RP1, C1, COLA, D1, b4, A, w5, D0, YS0, NYg / 2, FLAG);
    // K6: gather5(bf16x2) + fc2 -> out
    k_gfc2<<<N0c / 16, Bk, 0, stream>>>(YS0, RP0, C0, COLA, D0, b5, fc2w, fc2b, d_out, N0c, FLAG);
}

// Round 10
// 408.871 us; speedup vs baseline: 1.3263x; 1.0505x over previous
//
#include <hip/hip_runtime.h>
#include <hip/hip_bf16.h>

typedef unsigned short u16;
typedef unsigned int u32;
typedef float fx2 __attribute__((ext_vector_type(2)));

#define NXg 784
#define NYg 480
constexpr int N0c = NXg * NYg;   // 376320
constexpr int N1c = N0c / 4;     // 94080
constexpr int N2c = N0c / 16;    // 23520
constexpr int NTc = N0c + N1c + N2c;
constexpr int E0c = 4 * N0c;
constexpr int E1c = 4 * N1c;
constexpr int E2c = 4 * N2c;
constexpr int Etot = E0c + E1c + E2c;
constexpr int P0c = E0c + 3 * N0c;
constexpr int P1c = E1c + 3 * N1c;
constexpr int P2c = E2c + 3 * N2c;
constexpr int Ptot = P0c + P1c + P2c;
constexpr int NB0 = (N0c + 1023) / 1024;   // 368
constexpr int NB1 = (N1c + 1023) / 1024;   // 92
constexpr int NB2 = (N2c + 1023) / 1024;   // 23
constexpr int NBt = NB0 + NB1 + NB2;       // 483

__device__ __forceinline__ float bf2f(u16 v) {
    union { u32 u; float f; } t; t.u = ((u32)v) << 16; return t.f;
}
__device__ __forceinline__ u16 f2bf(float f) {
    union { float f; u32 u; } t; t.f = f;
    u32 u = t.u;
    u32 r = (u + 0x7fffu + ((u >> 16) & 1u)) >> 16;   // RNE
    return (u16)r;
}
__device__ __forceinline__ float rdf(const void* p, int i, int isf32) {
    if (isf32) return ((const float*)p)[i];
    return bf2f(((const u16*)p)[i]);
}
__device__ __forceinline__ void stage(float* dst, const void* src, int n, int isf32) {
    int t = threadIdx.x;
    if (isf32) {
        const float* s = (const float*)src;
        for (int i = t; i < n; i += 256) dst[i] = s[i];
    } else {
        const u16* s = (const u16*)src;
        for (int i = t; i < n; i += 256) dst[i] = bf2f(s[i]);
    }
}

// ---- ys storage traits ----
struct F32S {
    typedef float T;
    static __device__ __forceinline__ float ld(const T* p, size_t i) { return p[i]; }
    static __device__ __forceinline__ void st(T* p, size_t i, float v) { p[i] = v; }
    static __device__ __forceinline__ fx2 ld2(const T* p, size_t i) {
        return ((const fx2*)p)[i];
    }
};
struct BF16S {
    typedef u16 T;
    static __device__ __forceinline__ float ld(const T* p, size_t i) { return bf2f(p[i]); }
    static __device__ __forceinline__ void st(T* p, size_t i, float v) { p[i] = f2bf(v); }
    static __device__ __forceinline__ fx2 ld2(const T* p, size_t i) {
        u32 w = ((const u32*)p)[i];
        fx2 r; r.x = bf2f((u16)(w & 0xffffu)); r.y = bf2f((u16)(w >> 16));
        return r;
    }
};

__device__ __forceinline__ void lvl_of_bin(int b, int& lv, int& bl) {
    if (b < NB0) { lv = 0; bl = b; }
    else if (b < NB0 + NB1) { lv = 1; bl = b - NB0; }
    else { lv = 2; bl = b - NB0 - NB1; }
}

// ------------- dtype detection -------------
__global__ void k_detect(const u32* __restrict__ xw, int* __restrict__ flag) {
    __shared__ int cnt;
    if (threadIdx.x == 0) cnt = 0;
    __syncthreads();
    u32 w = xw[threadIdx.x];
    int e = (int)((w >> 7) & 0xFFu);
    int hit = ((e >= 90 && e <= 135) || ((w & 0x7FFFu) == 0u)) ? 1 : 0;
    atomicAdd(&cnt, hit);
    __syncthreads();
    if (threadIdx.x == 0) *flag = (cnt < 192) ? 1 : 0;
}

// ------------- init -------------
__global__ void k_init(int* __restrict__ binCnt, u16* __restrict__ y0,
                       float* __restrict__ y1, float* __restrict__ y2) {
    int t = blockIdx.x * blockDim.x + threadIdx.x;
    if (t < NBt) binCnt[t] = 0;
    if (t < 32) { y0[t] = 0; y1[t] = 0.0f; y2[t] = 0.0f; }
}

// ------------- phase A -------------
__global__ void kA_count(const int* __restrict__ ei0, const int* __restrict__ ei1,
                         const int* __restrict__ ei2, int* __restrict__ binCnt) {
    __shared__ int lc[NB0];
    int b = blockIdx.x, t = threadIdx.x;
    int lv, bl; lvl_of_bin(b, lv, bl);
    const int* dstp; int E, nb, binB;
    if (lv == 0) { dstp = ei0 + E0c; E = E0c; nb = NB0; binB = 0; }
    else if (lv == 1) { dstp = ei1 + E1c; E = E1c; nb = NB1; binB = NB0; }
    else { dstp = ei2 + E2c; E = E2c; nb = NB2; binB = NB0 + NB1; }
    for (int i = t; i < nb; i += 256) lc[i] = 0;
    __syncthreads();
    int e0 = bl * 4096, e1 = min(E, e0 + 4096);
    for (int i = e0 + t; i < e1; i += 256) atomicAdd(&lc[dstp[i] >> 10], 1);
    __syncthreads();
    for (int i = t; i < nb; i += 256) if (lc[i]) atomicAdd(&binCnt[binB + i], lc[i]);
}

// ------------- phase B -------------
__global__ void kB_scan(const int* __restrict__ binCnt, int* __restrict__ binStart,
                        int* __restrict__ binCursor) {
    __shared__ int s[512];
    int t = threadIdx.x;
    int v = (t < NBt) ? binCnt[t] : 0;
    s[t] = v;
    __syncthreads();
    for (int off = 1; off < 512; off <<= 1) {
        int x = (t >= off) ? s[t - off] : 0;
        __syncthreads();
        s[t] += x;
        __syncthreads();
    }
    if (t < NBt) { int e = s[t] - v; binStart[t] = e; binCursor[t] = e; }
    if (t == 0) binStart[NBt] = Etot;
}

// ------------- phase C -------------
__global__ void kC_place(const int* __restrict__ ei0, const int* __restrict__ ei1,
                         const int* __restrict__ ei2, int* __restrict__ binCursor,
                         int2* __restrict__ BE) {
    __shared__ int lc[NB0];
    __shared__ int lb[NB0];
    int b = blockIdx.x, t = threadIdx.x;
    int lv, bl; lvl_of_bin(b, lv, bl);
    const int* srcp; const int* dstp; int E, nb, binB;
    if (lv == 0) { srcp = ei0; dstp = ei0 + E0c; E = E0c; nb = NB0; binB = 0; }
    else if (lv == 1) { srcp = ei1; dstp = ei1 + E1c; E = E1c; nb = NB1; binB = NB0; }
    else { srcp = ei2; dstp = ei2 + E2c; E = E2c; nb = NB2; binB = NB0 + NB1; }
    for (int i = t; i < nb; i += 256) lc[i] = 0;
    __syncthreads();
    int e0 = bl * 4096, e1 = min(E, e0 + 4096);
    for (int i = e0 + t; i < e1; i += 256) atomicAdd(&lc[dstp[i] >> 10], 1);
    __syncthreads();
    for (int i = t; i < nb; i += 256) {
        int c = lc[i];
        lb[i] = c ? atomicAdd(&binCursor[binB + i], c) : 0;
        lc[i] = 0;
    }
    __syncthreads();
    for (int i = e0 + t; i < e1; i += 256) {
        int d = dstp[i];
        int bn = d >> 10;
        int p = atomicAdd(&lc[bn], 1);
        BE[lb[bn] + p] = make_int2(srcp[i], d);
    }
}

// ------------- phase D1 -------------
__global__ void kD1_count(const int2* __restrict__ BE, const int* __restrict__ binStart,
                          int* __restrict__ CNT, float* __restrict__ DINV,
                          int* __restrict__ binPadTot) {
    __shared__ int lc[1024];
    __shared__ int red[256];
    int b = blockIdx.x, t = threadIdx.x;
    int lv, bl; lvl_of_bin(b, lv, bl);
    int cbase, nLev;
    if (lv == 0) { cbase = 0; nLev = N0c; }
    else if (lv == 1) { cbase = N0c; nLev = N1c; }
    else { cbase = N0c + N1c; nLev = N2c; }
    for (int i = t; i < 1024; i += 256) lc[i] = 0;
    __syncthreads();
    int s0 = binStart[b], s1 = binStart[b + 1];
    for (int i = s0 + t; i < s1; i += 256) {
        int2 e = BE[i];
        atomicAdd(&lc[e.y & 1023], 1);
    }
    __syncthreads();
    int nodeB = bl << 10;
    int ps = 0;
#pragma unroll
    for (int j = 0; j < 4; j++) {
        int li = t * 4 + j;
        int node = nodeB + li;
        if (node < nLev) {
            int c = lc[li];
            CNT[cbase + node] = c;
            DINV[cbase + node] = rsqrtf((float)c + 1.0f);
            ps += (c + 3) & ~3;
        }
    }
    red[t] = ps;
    __syncthreads();
    for (int off = 128; off > 0; off >>= 1) {
        if (t < off) red[t] += red[t + off];
        __syncthreads();
    }
    if (t == 0) binPadTot[b] = red[0];
}

// ------------- phase D2 -------------
__global__ void kD2_scan(const int* __restrict__ binPadTot, int* __restrict__ binPadStart) {
    __shared__ int s[512];
    __shared__ int tot0, tot01;
    int t = threadIdx.x;
    int v = (t < NBt) ? binPadTot[t] : 0;
    s[t] = v;
    __syncthreads();
    for (int off = 1; off < 512; off <<= 1) {
        int x = (t >= off) ? s[t - off] : 0;
        __syncthreads();
        s[t] += x;
        __syncthreads();
    }
    if (t == 0) { tot0 = s[NB0 - 1]; tot01 = s[NB0 + NB1 - 1]; }
    __syncthreads();
    if (t < NBt) {
        int ex = s[t] - v;
        int cb, sub;
        if (t < NB0) { cb = 0; sub = 0; }
        else if (t < NB0 + NB1) { cb = P0c; sub = tot0; }
        else { cb = P0c + P1c; sub = tot01; }
        binPadStart[t] = cb + ex - sub;
    }
}

// ------------- phase D3 -------------
__global__ void kD3_final(const int2* __restrict__ BE, const int* __restrict__ binStart,
                          const int* __restrict__ CNT, const int* __restrict__ binPadStart,
                          int* __restrict__ rowptr, int* __restrict__ colAll) {
    __shared__ int lst[1024];
    __shared__ int lcur[1024];
    __shared__ int red[256];
    int b = blockIdx.x, t = threadIdx.x;
    int lv, bl; lvl_of_bin(b, lv, bl);
    int cbase, nLev, dummy;
    if (lv == 0) { cbase = 0; nLev = N0c; dummy = N0c; }
    else if (lv == 1) { cbase = N0c; nLev = N1c; dummy = N1c; }
    else { cbase = N0c + N1c; nLev = N2c; dummy = N2c; }
    int nodeB = bl << 10;
    int pc[4];
    int ps = 0;
#pragma unroll
    for (int j = 0; j < 4; j++) {
        int li = t * 4 + j;
        int node = nodeB + li;
        int c = (node < nLev) ? CNT[cbase + node] : 0;
        pc[j] = (c + 3) & ~3;
        ps += pc[j];
    }
    red[t] = ps;
    __syncthreads();
    for (int off = 1; off < 256; off <<= 1) {
        int x = (t >= off) ? red[t - off] : 0;
        __syncthreads();
        red[t] += x;
        __syncthreads();
    }
    int ex = red[t] - ps;
    int tot = red[255];
    int off = ex;
#pragma unroll
    for (int j = 0; j < 4; j++) {
        int li = t * 4 + j;
        lst[li] = off;
        lcur[li] = off;
        off += pc[j];
    }
    int cb = binPadStart[b];
#pragma unroll
    for (int j = 0; j < 4; j++) {
        int li = t * 4 + j;
        int node = nodeB + li;
        if (node < nLev) rowptr[cbase + node] = cb + lst[li];
    }
    __syncthreads();
    for (int i = t; i < tot; i += 256) colAll[cb + i] = dummy;
    __syncthreads();
    int s0 = binStart[b], s1 = binStart[b + 1];
    for (int i = s0 + t; i < s1; i += 256) {
        int2 e = BE[i];
        int p = atomicAdd(&lcur[e.y & 1023], 1);
        colAll[cb + p] = e.x;
    }
}

// ---------------- 2-wide gather core ----------------
template <class SIn>
__device__ __forceinline__ fx2 gather2(const typename SIn::T* __restrict__ ys,
                                       const int* __restrict__ rp,
                                       const int* __restrict__ cnt,
                                       const int* __restrict__ col,
                                       const float* __restrict__ dinv,
                                       int node, int cp) {
    int s0 = rp[node];
    int nch = (cnt[node] + 3) >> 2;
    fx2 a = SIn::ld2(ys, (size_t)node * 16 + cp);
    const int4* c4 = (const int4*)(col + s0);
    for (int i = 0; i < nch; i++) {
        int4 cs = c4[i];
        fx2 a0 = SIn::ld2(ys, (size_t)cs.x * 16 + cp);
        fx2 a1 = SIn::ld2(ys, (size_t)cs.y * 16 + cp);
        fx2 a2 = SIn::ld2(ys, (size_t)cs.z * 16 + cp);
        fx2 a3 = SIn::ld2(ys, (size_t)cs.w * 16 + cp);
        a += (a0 + a1) + (a2 + a3);
    }
    float di = dinv[node];
    a *= di;
    return a;
}

// ---------------- K1: persistent fc1 + relu + prep1 -> bf16 ys ----------------
constexpr int FC1_TILES = N0c / 64;   // 5880
__global__ void k_fc1prep(const void* __restrict__ x, const void* __restrict__ fw,
                          const void* __restrict__ fb, const void* __restrict__ w1,
                          const float* __restrict__ d0, u16* __restrict__ ys1,
                          const int* __restrict__ flag) {
    int isf32 = *flag;
    __shared__ float sx[256];
    __shared__ float sh[2048];
    __shared__ float sfw[128];
    __shared__ float sfb[32];
    __shared__ float sw1[1024];
    int t = threadIdx.x;
    stage(sw1, w1, 1024, isf32);
    stage(sfw, fw, 128, isf32);
    stage(sfb, fb, 32, isf32);
    __syncthreads();
    int c = t & 31;
    int ng = t >> 5;   // 0..7
    for (int tile = blockIdx.x; tile < FC1_TILES; tile += gridDim.x) {
        int nodeBase = tile * 64;
        sx[t] = rdf(x, nodeBase * 4 + t, isf32);
        __syncthreads();
#pragma unroll
        for (int i = 0; i < 8; i++) {
            int ln = ng + i * 8;
            float a = sfb[c];
#pragma unroll
            for (int k = 0; k < 4; k++) a = fmaf(sx[ln * 4 + k], sfw[k * 32 + c], a);
            sh[ln * 32 + c] = fmaxf(a, 0.0f);
        }
        __syncthreads();
#pragma unroll
        for (int i = 0; i < 8; i++) {
            int ln = ng + i * 8;
            float s = 0.0f;
#pragma unroll
            for (int k = 0; k < 32; k++) s = fmaf(sh[ln * 32 + k], sw1[k * 32 + c], s);
            int node = nodeBase + ln;
            BF16S::st(ys1, (size_t)node * 32 + c, s * d0[node]);
        }
        __syncthreads();
    }
}

// ---------------- K2/K3: NPB nodes/block, 2-wide gather + relu -> O; fused prep_next ----------------
template <class SIn, class SOut, int NPB>
__global__ void k_gds(const typename SIn::T* __restrict__ ys_in, const int* __restrict__ rp,
                      const int* __restrict__ cnt, const int* __restrict__ col,
                      const float* __restrict__ dinv_p, const void* __restrict__ b,
                      float* __restrict__ O, const void* __restrict__ wn,
                      const float* __restrict__ dinv_c, typename SOut::T* __restrict__ ys_out,
                      int cols, const int* __restrict__ flag) {
    int isf32 = *flag;
    __shared__ float sv[NPB * 32];
    __shared__ float swn[1024];
    int t = threadIdx.x;
    int nodeBase = blockIdx.x * NPB;
    int rb = nodeBase / cols;                    // cols % NPB == 0 -> whole block same row
    if (!(rb & 1)) stage(swn, wn, 1024, isf32);  // block-uniform
    int cp = t & 15;
#pragma unroll
    for (int i = 0; i < NPB / 16; i++) {
        int local = (t >> 4) + i * 16;
        int node = nodeBase + local;
        fx2 g = gather2<SIn>(ys_in, rp, cnt, col, dinv_p, node, cp);
        fx2 v;
        v.x = fmaxf(g.x + rdf(b, 2 * cp, isf32), 0.0f);
        v.y = fmaxf(g.y + rdf(b, 2 * cp + 1, isf32), 0.0f);
        __builtin_nontemporal_store(v, (fx2*)O + (size_t)node * 16 + cp);
        sv[local * 32 + 2 * cp] = v.x;
        sv[local * 32 + 2 * cp + 1] = v.y;
    }
    __syncthreads();
    if (!(rb & 1)) {
#pragma unroll
        for (int i = 0; i < NPB / 16; i++) {
            int item = t + i * 256;
            int childIdx = item >> 5;        // 0..NPB/2-1
            int ci = item & 31;
            int lc = childIdx * 2;           // even local node
            int cc = (nodeBase - rb * cols) + lc;
            int dn = (rb >> 1) * (cols >> 1) + (cc >> 1);
            float a = 0.0f;
#pragma unroll
            for (int k = 0; k < 32; k++) a = fmaf(sv[lc * 32 + k], swn[k * 32 + ci], a);
            SOut::st(ys_out, (size_t)dn * 32 + ci, a * dinv_c[dn]);
        }
    }
}

// ---------------- K4/K5: NPB parents/block, 2-wide gather + up-residual + prep_next ----------------
template <class SIn, class SOut, int NPB>
__global__ void k_gup(const typename SIn::T* __restrict__ ys_in, const int* __restrict__ rp,
                      const int* __restrict__ cnt, const int* __restrict__ col,
                      const float* __restrict__ dinv_p, const void* __restrict__ b,
                      const float* __restrict__ R, const void* __restrict__ wn,
                      const float* __restrict__ dinv_c, typename SOut::T* __restrict__ ys_out,
                      int cols_p, const int* __restrict__ flag) {
    int isf32 = *flag;
    __shared__ float sv[NPB * 32];
    __shared__ float sch[NPB * 128];
    __shared__ float swn[1024];
    int t = threadIdx.x;
    int nodeBase = blockIdx.x * NPB;
    stage(swn, wn, 1024, isf32);
    if (t < NPB * 16) {
        int local = t >> 4, cp = t & 15;
        int node = nodeBase + local;
        fx2 g = gather2<SIn>(ys_in, rp, cnt, col, dinv_p, node, cp);
        sv[local * 32 + 2 * cp] = fmaxf(g.x + rdf(b, 2 * cp, isf32), 0.0f);
        sv[local * 32 + 2 * cp + 1] = fmaxf(g.y + rdf(b, 2 * cp + 1, isf32), 0.0f);
    }
    __syncthreads();
    int rb = nodeBase / cols_p;
    int ccb = nodeBase - rb * cols_p;
    int cols_c = cols_p * 2;
#pragma unroll
    for (int i = 0; i < NPB / 2; i++) {
        int item = t + i * 256;
        int row = item >> 5, k = item & 31;
        int lp = row >> 2, j = row & 3;
        int ch = (2 * rb + (j >> 1)) * cols_c + 2 * (ccb + lp) + (j & 1);
        sch[item] = R[(size_t)ch * 32 + k] + sv[lp * 32 + k];
    }
    __syncthreads();
#pragma unroll
    for (int i = 0; i < NPB / 2; i++) {
        int item = t + i * 256;
        int row = item >> 5, ci = item & 31;
        int lp = row >> 2, j = row & 3;
        int ch = (2 * rb + (j >> 1)) * cols_c + 2 * (ccb + lp) + (j & 1);
        float a = 0.0f;
#pragma unroll
        for (int k = 0; k < 32; k++) a = fmaf(sch[row * 32 + k], swn[k * 32 + ci], a);
        SOut::st(ys_out, (size_t)ch * 32 + ci, a * dinv_c[ch]);
    }
}

// ---------------- K6: 32 nodes/block, 2-wide gather + relu + fc2 -> out ----------------
__global__ void k_gfc2(const u16* __restrict__ ys, const int* __restrict__ rp,
                       const int* __restrict__ cnt, const int* __restrict__ col,
                       const float* __restrict__ dinv, const void* __restrict__ b5,
                       const void* __restrict__ fw, const void* __restrict__ fb,
                       void* __restrict__ out, int n, const int* __restrict__ flag) {
    int isf32 = *flag;
    __shared__ float sv[1024];
    __shared__ float sw[96];
    __shared__ float sfb[3];
    int t = threadIdx.x;
    if (t < 96) sw[t] = rdf(fw, t, isf32);
    if (t < 3) sfb[t] = rdf(fb, t, isf32);
    int nodeBase = blockIdx.x * 32;
    int cp = t & 15;
#pragma unroll
    for (int i = 0; i < 2; i++) {
        int local = (t >> 4) + i * 16;
        int node = nodeBase + local;
        fx2 g = gather2<BF16S>(ys, rp, cnt, col, dinv, node, cp);
        sv[local * 32 + 2 * cp] = fmaxf(g.x + rdf(b5, 2 * cp, isf32), 0.0f);
        sv[local * 32 + 2 * cp + 1] = fmaxf(g.y + rdf(b5, 2 * cp + 1, isf32), 0.0f);
    }
    __syncthreads();
    if (t < 96) {
        int ln = t / 3, j = t - ln * 3;
        int gn = nodeBase + ln;
        float o = sfb[j];
#pragma unroll
        for (int k = 0; k < 32; k++) o = fmaf(sv[ln * 32 + k], sw[k * 3 + j], o);
        if (isf32) ((float*)out)[(size_t)gn * 3 + j] = o;
        else ((u16*)out)[(size_t)gn * 3 + j] = f2bf(o);
    }
}

extern "C" void kernel_launch(void* const* d_in, const int* in_sizes, int n_in,
                              void* d_out, int out_size, void* d_ws, size_t ws_size,
                              hipStream_t stream) {
    const void* x    = d_in[0];
    const void* fc1w = d_in[1];
    const void* fc1b = d_in[2];
    const void* w1 = d_in[3];  const void* b1 = d_in[4];
    const void* w2 = d_in[5];  const void* b2 = d_in[6];
    const void* w3 = d_in[7];  const void* b3 = d_in[8];
    const void* w4 = d_in[9];  const void* b4 = d_in[10];
    const void* w5 = d_in[11]; const void* b5 = d_in[12];
    const void* fc2w = d_in[13]; const void* fc2b = d_in[14];
    const int* ei0 = (const int*)d_in[18];
    const int* ei1 = (const int*)d_in[19];
    const int* ei2 = (const int*)d_in[20];

    u16* YS0 = (u16*)d_ws;                                // (N0+1)*32 u16
    float* A    = (float*)(YS0 + (size_t)(N0c + 1) * 32); // N0*32 f32
    float* YS1  = A   + (size_t)N0c * 32;
    float* H1   = YS1 + (size_t)(N1c + 1) * 32;
    float* YS2  = H1  + (size_t)N1c * 32;
    float* DINV = YS2 + (size_t)(N2c + 1) * 32;
    int* CNT   = (int*)(DINV + NTc);
    int* RPA   = CNT + NTc;
    int* COLA  = RPA + NTc;
    int2* BE   = (int2*)(COLA + Ptot);
    int* binCnt      = (int*)(BE + Etot);
    int* binStart    = binCnt + NBt;
    int* binCursor   = binStart + NBt + 1;
    int* binPadTot   = binCursor + NBt;
    int* binPadStart = binPadTot + NBt;
    int* FLAG        = binPadStart + NBt;

    float* D0 = DINV; float* D1 = D0 + N0c; float* D2 = D1 + N1c;
    int* C0 = CNT;  int* C1 = C0 + N0c;  int* C2 = C1 + N1c;
    int* RP0 = RPA; int* RP1 = RP0 + N0c; int* RP2 = RP1 + N1c;

    const int Bk = 256;

    k_detect<<<1, 256, 0, stream>>>((const u32*)x, FLAG);
    k_init<<<2, 256, 0, stream>>>(binCnt, YS0 + (size_t)N0c * 32,
                                  YS1 + (size_t)N1c * 32, YS2 + (size_t)N2c * 32);

    kA_count<<<NBt, Bk, 0, stream>>>(ei0, ei1, ei2, binCnt);
    kB_scan<<<1, 512, 0, stream>>>(binCnt, binStart, binCursor);
    kC_place<<<NBt, Bk, 0, stream>>>(ei0, ei1, ei2, binCursor, BE);
    kD1_count<<<NBt, Bk, 0, stream>>>(BE, binStart, CNT, DINV, binPadTot);
    kD2_scan<<<1, 512, 0, stream>>>(binPadTot, binPadStart);
    kD3_final<<<NBt, Bk, 0, stream>>>(BE, binStart, CNT, binPadStart, RPA, COLA);

    // K1: persistent fc1+relu+prep1 -> YS0 (bf16); 1960 blocks x 3 tiles
    k_fc1prep<<<1960, Bk, 0, stream>>>(x, fc1w, fc1b, w1, D0, YS0, FLAG);
    // K2: gather1(bf16x2, 32 nodes/block) -> A, fused prep2 -> YS1 (f32)
    k_gds<BF16S, F32S, 32><<<N0c / 32, Bk, 0, stream>>>(YS0, RP0, C0, COLA, D0, b1, A, w2, D1, YS1, NYg, FLAG);
    // K3: gather2(f32x2, 16 nodes/block) -> H1, fused prep3 -> YS2 (f32)
    k_gds<F32S, F32S, 16><<<N1c / 16, Bk, 0, stream>>>(YS1, RP1, C1, COLA, D1, b2, H1, w3, D2, YS2, NYg / 2, FLAG);
    // K4: gather3 + up-residual(H1) + prep4 -> YS1 (f32); 8 parents (120-col grid)
    k_gup<F32S, F32S, 8><<<N2c / 8, Bk, 0, stream>>>(YS2, RP2, C2, COLA, D2, b3, H1, w4, D1, YS1, NYg / 4, FLAG);
    // K5: gather4 + up-residual(A) + prep5 -> YS0 (bf16); 16 parents
    k_gup<F32S, BF16S, 16><<<N1c / 16, Bk, 0, stream>>>(YS1, RP1, C1, COLA, D1, b4, A, w5, D0, YS0, NYg / 2, FLAG);
    // K6: gather5(bf16x2, 32 nodes/block) + fc2 -> out
    k_gfc2<<<N0c / 32, Bk, 0, stream>>>(YS0, RP0, C0, COLA, D0, b5, fc2w, fc2b, d_out, N0c, FLAG);
}

// Round 11
// 356.050 us; speedup vs baseline: 1.5230x; 1.1484x over previous
//
#include <hip/hip_runtime.h>
#include <hip/hip_bf16.h>

typedef unsigned short u16;
typedef unsigned int u32;
typedef float fx2 __attribute__((ext_vector_type(2)));

#define NXg 784
#define NYg 480
constexpr int N0c = NXg * NYg;   // 376320
constexpr int N1c = N0c / 4;     // 94080
constexpr int N2c = N0c / 16;    // 23520
constexpr int NTc = N0c + N1c + N2c;
constexpr int E0c = 4 * N0c;
constexpr int E1c = 4 * N1c;
constexpr int E2c = 4 * N2c;
constexpr int Etot = E0c + E1c + E2c;
constexpr int P0c = E0c + 3 * N0c;
constexpr int P1c = E1c + 3 * N1c;
constexpr int P2c = E2c + 3 * N2c;
constexpr int Ptot = P0c + P1c + P2c;
constexpr int NB0 = (N0c + 1023) / 1024;   // 368
constexpr int NB1 = (N1c + 1023) / 1024;   // 92
constexpr int NB2 = (N2c + 1023) / 1024;   // 23
constexpr int NBt = NB0 + NB1 + NB2;       // 483

__device__ __forceinline__ float bf2f(u16 v) {
    union { u32 u; float f; } t; t.u = ((u32)v) << 16; return t.f;
}
__device__ __forceinline__ u16 f2bf(float f) {
    union { float f; u32 u; } t; t.f = f;
    u32 u = t.u;
    u32 r = (u + 0x7fffu + ((u >> 16) & 1u)) >> 16;   // RNE
    return (u16)r;
}
__device__ __forceinline__ float rdf(const void* p, int i, int isf32) {
    if (isf32) return ((const float*)p)[i];
    return bf2f(((const u16*)p)[i]);
}
__device__ __forceinline__ void stage(float* dst, const void* src, int n, int isf32) {
    int t = threadIdx.x;
    if (isf32) {
        const float* s = (const float*)src;
        for (int i = t; i < n; i += 256) dst[i] = s[i];
    } else {
        const u16* s = (const u16*)src;
        for (int i = t; i < n; i += 256) dst[i] = bf2f(s[i]);
    }
}

// ---- ys storage traits ----
struct F32S {
    typedef float T;
    static __device__ __forceinline__ float ld(const T* p, size_t i) { return p[i]; }
    static __device__ __forceinline__ void st(T* p, size_t i, float v) { p[i] = v; }
    static __device__ __forceinline__ fx2 ld2(const T* p, size_t i) {
        return ((const fx2*)p)[i];
    }
};
struct BF16S {
    typedef u16 T;
    static __device__ __forceinline__ float ld(const T* p, size_t i) { return bf2f(p[i]); }
    static __device__ __forceinline__ void st(T* p, size_t i, float v) { p[i] = f2bf(v); }
    static __device__ __forceinline__ fx2 ld2(const T* p, size_t i) {
        u32 w = ((const u32*)p)[i];
        fx2 r; r.x = bf2f((u16)(w & 0xffffu)); r.y = bf2f((u16)(w >> 16));
        return r;
    }
};

__device__ __forceinline__ void lvl_of_bin(int b, int& lv, int& bl) {
    if (b < NB0) { lv = 0; bl = b; }
    else if (b < NB0 + NB1) { lv = 1; bl = b - NB0; }
    else { lv = 2; bl = b - NB0 - NB1; }
}

// ------------- dtype detection -------------
__global__ void k_detect(const u32* __restrict__ xw, int* __restrict__ flag) {
    __shared__ int cnt;
    if (threadIdx.x == 0) cnt = 0;
    __syncthreads();
    u32 w = xw[threadIdx.x];
    int e = (int)((w >> 7) & 0xFFu);
    int hit = ((e >= 90 && e <= 135) || ((w & 0x7FFFu) == 0u)) ? 1 : 0;
    atomicAdd(&cnt, hit);
    __syncthreads();
    if (threadIdx.x == 0) *flag = (cnt < 192) ? 1 : 0;
}

// ------------- init -------------
__global__ void k_init(int* __restrict__ binCnt, u16* __restrict__ y0,
                       u16* __restrict__ y1, u16* __restrict__ y2) {
    int t = blockIdx.x * blockDim.x + threadIdx.x;
    if (t < NBt) binCnt[t] = 0;
    if (t < 32) { y0[t] = 0; y1[t] = 0; y2[t] = 0; }
}

// ------------- phase A -------------
__global__ void kA_count(const int* __restrict__ ei0, const int* __restrict__ ei1,
                         const int* __restrict__ ei2, int* __restrict__ binCnt) {
    __shared__ int lc[NB0];
    int b = blockIdx.x, t = threadIdx.x;
    int lv, bl; lvl_of_bin(b, lv, bl);
    const int* dstp; int E, nb, binB;
    if (lv == 0) { dstp = ei0 + E0c; E = E0c; nb = NB0; binB = 0; }
    else if (lv == 1) { dstp = ei1 + E1c; E = E1c; nb = NB1; binB = NB0; }
    else { dstp = ei2 + E2c; E = E2c; nb = NB2; binB = NB0 + NB1; }
    for (int i = t; i < nb; i += 256) lc[i] = 0;
    __syncthreads();
    int e0 = bl * 4096, e1 = min(E, e0 + 4096);
    for (int i = e0 + t; i < e1; i += 256) atomicAdd(&lc[dstp[i] >> 10], 1);
    __syncthreads();
    for (int i = t; i < nb; i += 256) if (lc[i]) atomicAdd(&binCnt[binB + i], lc[i]);
}

// ------------- phase B -------------
__global__ void kB_scan(const int* __restrict__ binCnt, int* __restrict__ binStart,
                        int* __restrict__ binCursor) {
    __shared__ int s[512];
    int t = threadIdx.x;
    int v = (t < NBt) ? binCnt[t] : 0;
    s[t] = v;
    __syncthreads();
    for (int off = 1; off < 512; off <<= 1) {
        int x = (t >= off) ? s[t - off] : 0;
        __syncthreads();
        s[t] += x;
        __syncthreads();
    }
    if (t < NBt) { int e = s[t] - v; binStart[t] = e; binCursor[t] = e; }
    if (t == 0) binStart[NBt] = Etot;
}

// ------------- phase C -------------
__global__ void kC_place(const int* __restrict__ ei0, const int* __restrict__ ei1,
                         const int* __restrict__ ei2, int* __restrict__ binCursor,
                         int2* __restrict__ BE) {
    __shared__ int lc[NB0];
    __shared__ int lb[NB0];
    int b = blockIdx.x, t = threadIdx.x;
    int lv, bl; lvl_of_bin(b, lv, bl);
    const int* srcp; const int* dstp; int E, nb, binB;
    if (lv == 0) { srcp = ei0; dstp = ei0 + E0c; E = E0c; nb = NB0; binB = 0; }
    else if (lv == 1) { srcp = ei1; dstp = ei1 + E1c; E = E1c; nb = NB1; binB = NB0; }
    else { srcp = ei2; dstp = ei2 + E2c; E = E2c; nb = NB2; binB = NB0 + NB1; }
    for (int i = t; i < nb; i += 256) lc[i] = 0;
    __syncthreads();
    int e0 = bl * 4096, e1 = min(E, e0 + 4096);
    for (int i = e0 + t; i < e1; i += 256) atomicAdd(&lc[dstp[i] >> 10], 1);
    __syncthreads();
    for (int i = t; i < nb; i += 256) {
        int c = lc[i];
        lb[i] = c ? atomicAdd(&binCursor[binB + i], c) : 0;
        lc[i] = 0;
    }
    __syncthreads();
    for (int i = e0 + t; i < e1; i += 256) {
        int d = dstp[i];
        int bn = d >> 10;
        int p = atomicAdd(&lc[bn], 1);
        BE[lb[bn] + p] = make_int2(srcp[i], d);
    }
}

// ------------- phase D1 -------------
__global__ void kD1_count(const int2* __restrict__ BE, const int* __restrict__ binStart,
                          int* __restrict__ CNT, float* __restrict__ DINV,
                          int* __restrict__ binPadTot) {
    __shared__ int lc[1024];
    __shared__ int red[256];
    int b = blockIdx.x, t = threadIdx.x;
    int lv, bl; lvl_of_bin(b, lv, bl);
    int cbase, nLev;
    if (lv == 0) { cbase = 0; nLev = N0c; }
    else if (lv == 1) { cbase = N0c; nLev = N1c; }
    else { cbase = N0c + N1c; nLev = N2c; }
    for (int i = t; i < 1024; i += 256) lc[i] = 0;
    __syncthreads();
    int s0 = binStart[b], s1 = binStart[b + 1];
    for (int i = s0 + t; i < s1; i += 256) {
        int2 e = BE[i];
        atomicAdd(&lc[e.y & 1023], 1);
    }
    __syncthreads();
    int nodeB = bl << 10;
    int ps = 0;
#pragma unroll
    for (int j = 0; j < 4; j++) {
        int li = t * 4 + j;
        int node = nodeB + li;
        if (node < nLev) {
            int c = lc[li];
            CNT[cbase + node] = c;
            DINV[cbase + node] = rsqrtf((float)c + 1.0f);
            ps += (c + 3) & ~3;
        }
    }
    red[t] = ps;
    __syncthreads();
    for (int off = 128; off > 0; off >>= 1) {
        if (t < off) red[t] += red[t + off];
        __syncthreads();
    }
    if (t == 0) binPadTot[b] = red[0];
}

// ------------- phase D2 -------------
__global__ void kD2_scan(const int* __restrict__ binPadTot, int* __restrict__ binPadStart) {
    __shared__ int s[512];
    __shared__ int tot0, tot01;
    int t = threadIdx.x;
    int v = (t < NBt) ? binPadTot[t] : 0;
    s[t] = v;
    __syncthreads();
    for (int off = 1; off < 512; off <<= 1) {
        int x = (t >= off) ? s[t - off] : 0;
        __syncthreads();
        s[t] += x;
        __syncthreads();
    }
    if (t == 0) { tot0 = s[NB0 - 1]; tot01 = s[NB0 + NB1 - 1]; }
    __syncthreads();
    if (t < NBt) {
        int ex = s[t] - v;
        int cb, sub;
        if (t < NB0) { cb = 0; sub = 0; }
        else if (t < NB0 + NB1) { cb = P0c; sub = tot0; }
        else { cb = P0c + P1c; sub = tot01; }
        binPadStart[t] = cb + ex - sub;
    }
}

// ------------- phase D3 -------------
__global__ void kD3_final(const int2* __restrict__ BE, const int* __restrict__ binStart,
                          const int* __restrict__ CNT, const int* __restrict__ binPadStart,
                          int* __restrict__ rowptr, int* __restrict__ colAll) {
    __shared__ int lst[1024];
    __shared__ int lcur[1024];
    __shared__ int red[256];
    int b = blockIdx.x, t = threadIdx.x;
    int lv, bl; lvl_of_bin(b, lv, bl);
    int cbase, nLev, dummy;
    if (lv == 0) { cbase = 0; nLev = N0c; dummy = N0c; }
    else if (lv == 1) { cbase = N0c; nLev = N1c; dummy = N1c; }
    else { cbase = N0c + N1c; nLev = N2c; dummy = N2c; }
    int nodeB = bl << 10;
    int pc[4];
    int ps = 0;
#pragma unroll
    for (int j = 0; j < 4; j++) {
        int li = t * 4 + j;
        int node = nodeB + li;
        int c = (node < nLev) ? CNT[cbase + node] : 0;
        pc[j] = (c + 3) & ~3;
        ps += pc[j];
    }
    red[t] = ps;
    __syncthreads();
    for (int off = 1; off < 256; off <<= 1) {
        int x = (t >= off) ? red[t - off] : 0;
        __syncthreads();
        red[t] += x;
        __syncthreads();
    }
    int ex = red[t] - ps;
    int tot = red[255];
    int off = ex;
#pragma unroll
    for (int j = 0; j < 4; j++) {
        int li = t * 4 + j;
        lst[li] = off;
        lcur[li] = off;
        off += pc[j];
    }
    int cb = binPadStart[b];
#pragma unroll
    for (int j = 0; j < 4; j++) {
        int li = t * 4 + j;
        int node = nodeB + li;
        if (node < nLev) rowptr[cbase + node] = cb + lst[li];
    }
    __syncthreads();
    for (int i = t; i < tot; i += 256) colAll[cb + i] = dummy;
    __syncthreads();
    int s0 = binStart[b], s1 = binStart[b + 1];
    for (int i = s0 + t; i < s1; i += 256) {
        int2 e = BE[i];
        int p = atomicAdd(&lcur[e.y & 1023], 1);
        colAll[cb + p] = e.x;
    }
}

// ---------------- 2-wide gather core ----------------
template <class SIn>
__device__ __forceinline__ fx2 gather2(const typename SIn::T* __restrict__ ys,
                                       const int* __restrict__ rp,
                                       const int* __restrict__ cnt,
                                       const int* __restrict__ col,
                                       const float* __restrict__ dinv,
                                       int node, int cp) {
    int s0 = rp[node];
    int nch = (cnt[node] + 3) >> 2;
    fx2 a = SIn::ld2(ys, (size_t)node * 16 + cp);
    const int4* c4 = (const int4*)(col + s0);
    for (int i = 0; i < nch; i++) {
        int4 cs = c4[i];
        fx2 a0 = SIn::ld2(ys, (size_t)cs.x * 16 + cp);
        fx2 a1 = SIn::ld2(ys, (size_t)cs.y * 16 + cp);
        fx2 a2 = SIn::ld2(ys, (size_t)cs.z * 16 + cp);
        fx2 a3 = SIn::ld2(ys, (size_t)cs.w * 16 + cp);
        a += (a0 + a1) + (a2 + a3);
    }
    float di = dinv[node];
    a *= di;
    return a;
}

// ---------------- K1: persistent fc1 + relu + prep1 -> bf16 ys (tiled matmul) ----------------
constexpr int FC1_TILES = N0c / 64;   // 5880
__global__ void k_fc1prep(const void* __restrict__ x, const void* __restrict__ fw,
                          const void* __restrict__ fb, const void* __restrict__ w1,
                          const float* __restrict__ d0, u16* __restrict__ ys1,
                          const int* __restrict__ flag) {
    int isf32 = *flag;
    __shared__ float sx[256];
    __shared__ float sh[64 * 33];
    __shared__ float sfw[128];
    __shared__ float sfb[32];
    __shared__ float sw1[1024];
    int t = threadIdx.x;
    stage(sw1, w1, 1024, isf32);
    stage(sfw, fw, 128, isf32);
    stage(sfb, fb, 32, isf32);
    __syncthreads();
    int c = t & 31;
    int ng = t >> 5;       // 0..7
    int ci0 = t & 15;
    int rgrp = t >> 4;     // 0..15
    for (int tile = blockIdx.x; tile < FC1_TILES; tile += gridDim.x) {
        int nodeBase = tile * 64;
        sx[t] = rdf(x, nodeBase * 4 + t, isf32);
        __syncthreads();
#pragma unroll
        for (int i = 0; i < 8; i++) {
            int ln = ng + i * 8;
            float a = sfb[c];
#pragma unroll
            for (int k = 0; k < 4; k++) a = fmaf(sx[ln * 4 + k], sfw[k * 32 + c], a);
            sh[ln * 33 + c] = fmaxf(a, 0.0f);
        }
        __syncthreads();
        float acc[4][2];
#pragma unroll
        for (int r = 0; r < 4; r++) { acc[r][0] = 0.0f; acc[r][1] = 0.0f; }
#pragma unroll
        for (int k = 0; k < 32; k++) {
            float w0 = sw1[k * 32 + ci0];
            float w1v = sw1[k * 32 + ci0 + 16];
#pragma unroll
            for (int r = 0; r < 4; r++) {
                float s = sh[(rgrp * 4 + r) * 33 + k];
                acc[r][0] = fmaf(s, w0, acc[r][0]);
                acc[r][1] = fmaf(s, w1v, acc[r][1]);
            }
        }
#pragma unroll
        for (int r = 0; r < 4; r++) {
            int node = nodeBase + rgrp * 4 + r;
            float dv = d0[node];
            BF16S::st(ys1, (size_t)node * 32 + ci0, acc[r][0] * dv);
            BF16S::st(ys1, (size_t)node * 32 + ci0 + 16, acc[r][1] * dv);
        }
        __syncthreads();
    }
}

// ---------------- K2/K3: NPB nodes/block, 2-wide gather + relu -> O; fused prep_next ----------------
template <class SIn, class SOut, int NPB>
__global__ void k_gds(const typename SIn::T* __restrict__ ys_in, const int* __restrict__ rp,
                      const int* __restrict__ cnt, const int* __restrict__ col,
                      const float* __restrict__ dinv_p, const void* __restrict__ b,
                      float* __restrict__ O, const void* __restrict__ wn,
                      const float* __restrict__ dinv_c, typename SOut::T* __restrict__ ys_out,
                      int cols, const int* __restrict__ flag) {
    int isf32 = *flag;
    __shared__ float sv[NPB * 32];
    __shared__ float swn[1024];
    int t = threadIdx.x;
    int nodeBase = blockIdx.x * NPB;
    int rb = nodeBase / cols;                    // cols % NPB == 0 -> whole block same row
    if (!(rb & 1)) stage(swn, wn, 1024, isf32);  // block-uniform
    int cp = t & 15;
#pragma unroll
    for (int i = 0; i < NPB / 16; i++) {
        int local = (t >> 4) + i * 16;
        int node = nodeBase + local;
        fx2 g = gather2<SIn>(ys_in, rp, cnt, col, dinv_p, node, cp);
        fx2 v;
        v.x = fmaxf(g.x + rdf(b, 2 * cp, isf32), 0.0f);
        v.y = fmaxf(g.y + rdf(b, 2 * cp + 1, isf32), 0.0f);
        __builtin_nontemporal_store(v, (fx2*)O + (size_t)node * 16 + cp);
        sv[local * 32 + 2 * cp] = v.x;
        sv[local * 32 + 2 * cp + 1] = v.y;
    }
    __syncthreads();
    if (!(rb & 1)) {
#pragma unroll
        for (int i = 0; i < NPB / 16; i++) {
            int item = t + i * 256;
            int childIdx = item >> 5;        // 0..NPB/2-1
            int ci = item & 31;
            int lc = childIdx * 2;           // even local node
            int cc = (nodeBase - rb * cols) + lc;
            int dn = (rb >> 1) * (cols >> 1) + (cc >> 1);
            float a = 0.0f;
#pragma unroll
            for (int k = 0; k < 32; k++) a = fmaf(sv[lc * 32 + k], swn[k * 32 + ci], a);
            SOut::st(ys_out, (size_t)dn * 32 + ci, a * dinv_c[dn]);
        }
    }
}

// ---------------- K4/K5: NPB parents/block, gather + up-residual + tiled prep_next ----------------
template <class SIn, class SOut, int NPB>
__global__ void k_gup(const typename SIn::T* __restrict__ ys_in, const int* __restrict__ rp,
                      const int* __restrict__ cnt, const int* __restrict__ col,
                      const float* __restrict__ dinv_p, const void* __restrict__ b,
                      const float* __restrict__ R, const void* __restrict__ wn,
                      const float* __restrict__ dinv_c, typename SOut::T* __restrict__ ys_out,
                      int cols_p, const int* __restrict__ flag) {
    constexpr int RPT = NPB / 4;            // child rows per thread
    int isf32 = *flag;
    __shared__ float sv[NPB * 32];
    __shared__ float sch[NPB * 4 * 33];     // padded child rows
    __shared__ float swn[1024];
    int t = threadIdx.x;
    int nodeBase = blockIdx.x * NPB;
    stage(swn, wn, 1024, isf32);
    if (t < NPB * 16) {
        int local = t >> 4, cp = t & 15;
        int node = nodeBase + local;
        fx2 g = gather2<SIn>(ys_in, rp, cnt, col, dinv_p, node, cp);
        sv[local * 32 + 2 * cp] = fmaxf(g.x + rdf(b, 2 * cp, isf32), 0.0f);
        sv[local * 32 + 2 * cp + 1] = fmaxf(g.y + rdf(b, 2 * cp + 1, isf32), 0.0f);
    }
    __syncthreads();
    int rb = nodeBase / cols_p;
    int ccb = nodeBase - rb * cols_p;
    int cols_c = cols_p * 2;
#pragma unroll
    for (int i = 0; i < NPB / 2; i++) {
        int item = t + i * 256;
        int row = item >> 5, k = item & 31;
        int lp = row >> 2, j = row & 3;
        int ch = (2 * rb + (j >> 1)) * cols_c + 2 * (ccb + lp) + (j & 1);
        sch[row * 33 + k] = R[(size_t)ch * 32 + k] + sv[lp * 32 + k];
    }
    __syncthreads();
    int ci0 = t & 15;
    int rgrp = t >> 4;   // 0..15
    float acc[RPT][2];
#pragma unroll
    for (int r = 0; r < RPT; r++) { acc[r][0] = 0.0f; acc[r][1] = 0.0f; }
#pragma unroll
    for (int k = 0; k < 32; k++) {
        float w0 = swn[k * 32 + ci0];
        float w1v = swn[k * 32 + ci0 + 16];
#pragma unroll
        for (int r = 0; r < RPT; r++) {
            float s = sch[(rgrp * RPT + r) * 33 + k];
            acc[r][0] = fmaf(s, w0, acc[r][0]);
            acc[r][1] = fmaf(s, w1v, acc[r][1]);
        }
    }
#pragma unroll
    for (int r = 0; r < RPT; r++) {
        int row = rgrp * RPT + r;
        int lp = row >> 2, j = row & 3;
        int ch = (2 * rb + (j >> 1)) * cols_c + 2 * (ccb + lp) + (j & 1);
        float dc = dinv_c[ch];
        SOut::st(ys_out, (size_t)ch * 32 + ci0, acc[r][0] * dc);
        SOut::st(ys_out, (size_t)ch * 32 + ci0 + 16, acc[r][1] * dc);
    }
}

// ---------------- K6: 32 nodes/block, 2-wide gather + relu + fc2 -> out ----------------
__global__ void k_gfc2(const u16* __restrict__ ys, const int* __restrict__ rp,
                       const int* __restrict__ cnt, const int* __restrict__ col,
                       const float* __restrict__ dinv, const void* __restrict__ b5,
                       const void* __restrict__ fw, const void* __restrict__ fb,
                       void* __restrict__ out, int n, const int* __restrict__ flag) {
    int isf32 = *flag;
    __shared__ float sv[1024];
    __shared__ float sw[96];
    __shared__ float sfb[3];
    int t = threadIdx.x;
    if (t < 96) sw[t] = rdf(fw, t, isf32);
    if (t < 3) sfb[t] = rdf(fb, t, isf32);
    int nodeBase = blockIdx.x * 32;
    int cp = t & 15;
#pragma unroll
    for (int i = 0; i < 2; i++) {
        int local = (t >> 4) + i * 16;
        int node = nodeBase + local;
        fx2 g = gather2<BF16S>(ys, rp, cnt, col, dinv, node, cp);
        sv[local * 32 + 2 * cp] = fmaxf(g.x + rdf(b5, 2 * cp, isf32), 0.0f);
        sv[local * 32 + 2 * cp + 1] = fmaxf(g.y + rdf(b5, 2 * cp + 1, isf32), 0.0f);
    }
    __syncthreads();
    if (t < 96) {
        int ln = t / 3, j = t - ln * 3;
        int gn = nodeBase + ln;
        float o = sfb[j];
#pragma unroll
        for (int k = 0; k < 32; k++) o = fmaf(sv[ln * 32 + k], sw[k * 3 + j], o);
        if (isf32) ((float*)out)[(size_t)gn * 3 + j] = o;
        else ((u16*)out)[(size_t)gn * 3 + j] = f2bf(o);
    }
}

extern "C" void kernel_launch(void* const* d_in, const int* in_sizes, int n_in,
                              void* d_out, int out_size, void* d_ws, size_t ws_size,
                              hipStream_t stream) {
    const void* x    = d_in[0];
    const void* fc1w = d_in[1];
    const void* fc1b = d_in[2];
    const void* w1 = d_in[3];  const void* b1 = d_in[4];
    const void* w2 = d_in[5];  const void* b2 = d_in[6];
    const void* w3 = d_in[7];  const void* b3 = d_in[8];
    const void* w4 = d_in[9];  const void* b4 = d_in[10];
    const void* w5 = d_in[11]; const void* b5 = d_in[12];
    const void* fc2w = d_in[13]; const void* fc2b = d_in[14];
    const int* ei0 = (const int*)d_in[18];
    const int* ei1 = (const int*)d_in[19];
    const int* ei2 = (const int*)d_in[20];

    u16* YS0 = (u16*)d_ws;                                  // (N0+1)*32 u16
    float* A   = (float*)(YS0 + (size_t)(N0c + 1) * 32);    // N0*32 f32
    u16* YS1   = (u16*)(A + (size_t)N0c * 32);              // (N1+1)*32 u16
    float* H1  = (float*)(YS1 + (size_t)(N1c + 1) * 32);    // N1*32 f32
    u16* YS2   = (u16*)(H1 + (size_t)N1c * 32);             // (N2+1)*32 u16
    float* DINV = (float*)(YS2 + (size_t)(N2c + 1) * 32);   // NT
    int* CNT   = (int*)(DINV + NTc);
    int* RPA   = CNT + NTc;
    int* COLA  = RPA + NTc;
    int2* BE   = (int2*)(COLA + Ptot);
    int* binCnt      = (int*)(BE + Etot);
    int* binStart    = binCnt + NBt;
    int* binCursor   = binStart + NBt + 1;
    int* binPadTot   = binCursor + NBt;
    int* binPadStart = binPadTot + NBt;
    int* FLAG        = binPadStart + NBt;

    float* D0 = DINV; float* D1 = D0 + N0c; float* D2 = D1 + N1c;
    int* C0 = CNT;  int* C1 = C0 + N0c;  int* C2 = C1 + N1c;
    int* RP0 = RPA; int* RP1 = RP0 + N0c; int* RP2 = RP1 + N1c;

    const int Bk = 256;

    k_detect<<<1, 256, 0, stream>>>((const u32*)x, FLAG);
    k_init<<<2, 256, 0, stream>>>(binCnt, YS0 + (size_t)N0c * 32,
                                  YS1 + (size_t)N1c * 32, YS2 + (size_t)N2c * 32);

    kA_count<<<NBt, Bk, 0, stream>>>(ei0, ei1, ei2, binCnt);
    kB_scan<<<1, 512, 0, stream>>>(binCnt, binStart, binCursor);
    kC_place<<<NBt, Bk, 0, stream>>>(ei0, ei1, ei2, binCursor, BE);
    kD1_count<<<NBt, Bk, 0, stream>>>(BE, binStart, CNT, DINV, binPadTot);
    kD2_scan<<<1, 512, 0, stream>>>(binPadTot, binPadStart);
    kD3_final<<<NBt, Bk, 0, stream>>>(BE, binStart, CNT, binPadStart, RPA, COLA);

    // K1: persistent fc1+relu+prep1 -> YS0 (bf16)
    k_fc1prep<<<1960, Bk, 0, stream>>>(x, fc1w, fc1b, w1, D0, YS0, FLAG);
    // K2: gather1(bf16x2, 32 nodes/block) -> A, fused prep2 -> YS1 (bf16)
    k_gds<BF16S, BF16S, 32><<<N0c / 32, Bk, 0, stream>>>(YS0, RP0, C0, COLA, D0, b1, A, w2, D1, YS1, NYg, FLAG);
    // K3: gather2(bf16x2, 16 nodes/block) -> H1, fused prep3 -> YS2 (bf16)
    k_gds<BF16S, BF16S, 16><<<N1c / 16, Bk, 0, stream>>>(YS1, RP1, C1, COLA, D1, b2, H1, w3, D2, YS2, NYg / 2, FLAG);
    // K4: gather3 + up-residual(H1) + prep4 -> YS1 (bf16); 8 parents
    k_gup<BF16S, BF16S, 8><<<N2c / 8, Bk, 0, stream>>>(YS2, RP2, C2, COLA, D2, b3, H1, w4, D1, YS1, NYg / 4, FLAG);
    // K5: gather4 + up-residual(A) + prep5 -> YS0 (bf16); 16 parents
    k_gup<BF16S, BF16S, 16><<<N1c / 16, Bk, 0, stream>>>(YS1, RP1, C1, COLA, D1, b4, A, w5, D0, YS0, NYg / 2, FLAG);
    // K6: gather5(bf16x2, 32 nodes/block) + fc2 -> out
    k_gfc2<<<N0c / 32, Bk, 0, stream>>>(YS0, RP0, C0, COLA, D0, b5, fc2w, fc2b, d_out, N0c, FLAG);
}

// Round 12
// 351.365 us; speedup vs baseline: 1.5433x; 1.0133x over previous
//
#include <hip/hip_runtime.h>
#include <hip/hip_bf16.h>

typedef unsigned short u16;
typedef unsigned int u32;
typedef float fx2 __attribute__((ext_vector_type(2)));

#define NXg 784
#define NYg 480
constexpr int N0c = NXg * NYg;   // 376320
constexpr int N1c = N0c / 4;     // 94080
constexpr int N2c = N0c / 16;    // 23520
constexpr int NTc = N0c + N1c + N2c;
constexpr int E0c = 4 * N0c;
constexpr int E1c = 4 * N1c;
constexpr int E2c = 4 * N2c;
constexpr int Etot = E0c + E1c + E2c;
constexpr int P0c = E0c + 3 * N0c;
constexpr int P1c = E1c + 3 * N1c;
constexpr int P2c = E2c + 3 * N2c;
constexpr int Ptot = P0c + P1c + P2c;
constexpr int NB0 = (N0c + 1023) / 1024;   // 368
constexpr int NB1 = (N1c + 1023) / 1024;   // 92
constexpr int NB2 = (N2c + 1023) / 1024;   // 23
constexpr int NBt = NB0 + NB1 + NB2;       // 483

__device__ __forceinline__ float bf2f(u16 v) {
    union { u32 u; float f; } t; t.u = ((u32)v) << 16; return t.f;
}
__device__ __forceinline__ u16 f2bf(float f) {
    union { float f; u32 u; } t; t.f = f;
    u32 u = t.u;
    u32 r = (u + 0x7fffu + ((u >> 16) & 1u)) >> 16;   // RNE
    return (u16)r;
}
__device__ __forceinline__ float rdf(const void* p, int i, int isf32) {
    if (isf32) return ((const float*)p)[i];
    return bf2f(((const u16*)p)[i]);
}
__device__ __forceinline__ void stage(float* dst, const void* src, int n, int isf32) {
    int t = threadIdx.x;
    if (isf32) {
        const float* s = (const float*)src;
        for (int i = t; i < n; i += 256) dst[i] = s[i];
    } else {
        const u16* s = (const u16*)src;
        for (int i = t; i < n; i += 256) dst[i] = bf2f(s[i]);
    }
}

// ---- storage traits ----
struct F32S {
    typedef float T;
    static __device__ __forceinline__ float ld(const T* p, size_t i) { return p[i]; }
    static __device__ __forceinline__ void st(T* p, size_t i, float v) { p[i] = v; }
    static __device__ __forceinline__ fx2 ld2(const T* p, size_t i) {
        return ((const fx2*)p)[i];
    }
    static __device__ __forceinline__ void st2nt(T* p, size_t i, fx2 v) {
        __builtin_nontemporal_store(v, (fx2*)p + i);
    }
};
struct BF16S {
    typedef u16 T;
    static __device__ __forceinline__ float ld(const T* p, size_t i) { return bf2f(p[i]); }
    static __device__ __forceinline__ void st(T* p, size_t i, float v) { p[i] = f2bf(v); }
    static __device__ __forceinline__ fx2 ld2(const T* p, size_t i) {
        u32 w = ((const u32*)p)[i];
        fx2 r; r.x = bf2f((u16)(w & 0xffffu)); r.y = bf2f((u16)(w >> 16));
        return r;
    }
    static __device__ __forceinline__ void st2nt(T* p, size_t i, fx2 v) {
        u32 w = (u32)f2bf(v.x) | ((u32)f2bf(v.y) << 16);
        __builtin_nontemporal_store(w, (u32*)p + i);
    }
};

__device__ __forceinline__ void lvl_of_bin(int b, int& lv, int& bl) {
    if (b < NB0) { lv = 0; bl = b; }
    else if (b < NB0 + NB1) { lv = 1; bl = b - NB0; }
    else { lv = 2; bl = b - NB0 - NB1; }
}

// ------------- detect dtype + init (merged) -------------
__global__ void k_dinit(const u32* __restrict__ xw, int* __restrict__ flag,
                        int* __restrict__ binCnt, u16* __restrict__ y0,
                        u16* __restrict__ y1, u16* __restrict__ y2) {
    __shared__ int cnt;
    int t = threadIdx.x;
    int g = blockIdx.x * 256 + t;
    if (blockIdx.x == 0) {
        if (t == 0) cnt = 0;
        __syncthreads();
        u32 w = xw[t];
        int e = (int)((w >> 7) & 0xFFu);
        int hit = ((e >= 90 && e <= 135) || ((w & 0x7FFFu) == 0u)) ? 1 : 0;
        atomicAdd(&cnt, hit);
        __syncthreads();
        if (t == 0) *flag = (cnt < 192) ? 1 : 0;
    }
    if (g < NBt) binCnt[g] = 0;
    if (blockIdx.x == 1 && t < 32) { y0[t] = 0; y1[t] = 0; y2[t] = 0; }
}

// ------------- phase A: bin counts -------------
__global__ void kA_count(const int* __restrict__ ei0, const int* __restrict__ ei1,
                         const int* __restrict__ ei2, int* __restrict__ binCnt) {
    __shared__ int lc[NB0];
    int b = blockIdx.x, t = threadIdx.x;
    int lv, bl; lvl_of_bin(b, lv, bl);
    const int* dstp; int E, nb, binB;
    if (lv == 0) { dstp = ei0 + E0c; E = E0c; nb = NB0; binB = 0; }
    else if (lv == 1) { dstp = ei1 + E1c; E = E1c; nb = NB1; binB = NB0; }
    else { dstp = ei2 + E2c; E = E2c; nb = NB2; binB = NB0 + NB1; }
    for (int i = t; i < nb; i += 256) lc[i] = 0;
    __syncthreads();
    int e0 = bl * 4096, e1 = min(E, e0 + 4096);
    for (int i = e0 + t; i < e1; i += 256) atomicAdd(&lc[dstp[i] >> 10], 1);
    __syncthreads();
    for (int i = t; i < nb; i += 256) if (lc[i]) atomicAdd(&binCnt[binB + i], lc[i]);
}

// ------------- phase B: scan bins -------------
__global__ void kB_scan(const int* __restrict__ binCnt, int* __restrict__ binStart,
                        int* __restrict__ binCursor) {
    __shared__ int s[512];
    int t = threadIdx.x;
    int v = (t < NBt) ? binCnt[t] : 0;
    s[t] = v;
    __syncthreads();
    for (int off = 1; off < 512; off <<= 1) {
        int x = (t >= off) ? s[t - off] : 0;
        __syncthreads();
        s[t] += x;
        __syncthreads();
    }
    if (t < NBt) { int e = s[t] - v; binStart[t] = e; binCursor[t] = e; }
    if (t == 0) binStart[NBt] = Etot;
}

// ------------- phase C: place packed (src<<10 | dstLow) into bin regions -------------
__global__ void kC_place(const int* __restrict__ ei0, const int* __restrict__ ei1,
                         const int* __restrict__ ei2, int* __restrict__ binCursor,
                         u32* __restrict__ BE) {
    __shared__ int lc[NB0];
    __shared__ int lb[NB0];
    int b = blockIdx.x, t = threadIdx.x;
    int lv, bl; lvl_of_bin(b, lv, bl);
    const int* srcp; const int* dstp; int E, nb, binB;
    if (lv == 0) { srcp = ei0; dstp = ei0 + E0c; E = E0c; nb = NB0; binB = 0; }
    else if (lv == 1) { srcp = ei1; dstp = ei1 + E1c; E = E1c; nb = NB1; binB = NB0; }
    else { srcp = ei2; dstp = ei2 + E2c; E = E2c; nb = NB2; binB = NB0 + NB1; }
    for (int i = t; i < nb; i += 256) lc[i] = 0;
    __syncthreads();
    int e0 = bl * 4096, e1 = min(E, e0 + 4096);
    for (int i = e0 + t; i < e1; i += 256) atomicAdd(&lc[dstp[i] >> 10], 1);
    __syncthreads();
    for (int i = t; i < nb; i += 256) {
        int c = lc[i];
        lb[i] = c ? atomicAdd(&binCursor[binB + i], c) : 0;
        lc[i] = 0;
    }
    __syncthreads();
    for (int i = e0 + t; i < e1; i += 256) {
        int d = dstp[i];
        int bn = d >> 10;
        int p = atomicAdd(&lc[bn], 1);
        BE[lb[bn] + p] = ((u32)srcp[i] << 10) | (u32)(d & 1023);
    }
}

// ------------- phase D1: per-bin node counts -> CNT, DINV, padded totals -------------
__global__ void kD1_count(const u32* __restrict__ BE, const int* __restrict__ binStart,
                          int* __restrict__ CNT, float* __restrict__ DINV,
                          int* __restrict__ binPadTot) {
    __shared__ int lc[1024];
    __shared__ int red[256];
    int b = blockIdx.x, t = threadIdx.x;
    int lv, bl; lvl_of_bin(b, lv, bl);
    int cbase, nLev;
    if (lv == 0) { cbase = 0; nLev = N0c; }
    else if (lv == 1) { cbase = N0c; nLev = N1c; }
    else { cbase = N0c + N1c; nLev = N2c; }
    for (int i = t; i < 1024; i += 256) lc[i] = 0;
    __syncthreads();
    int s0 = binStart[b], s1 = binStart[b + 1];
    for (int i = s0 + t; i < s1; i += 256) {
        atomicAdd(&lc[BE[i] & 1023u], 1);
    }
    __syncthreads();
    int nodeB = bl << 10;
    int ps = 0;
#pragma unroll
    for (int j = 0; j < 4; j++) {
        int li = t * 4 + j;
        int node = nodeB + li;
        if (node < nLev) {
            int c = lc[li];
            CNT[cbase + node] = c;
            DINV[cbase + node] = rsqrtf((float)c + 1.0f);
            ps += (c + 3) & ~3;
        }
    }
    red[t] = ps;
    __syncthreads();
    for (int off = 128; off > 0; off >>= 1) {
        if (t < off) red[t] += red[t + off];
        __syncthreads();
    }
    if (t == 0) binPadTot[b] = red[0];
}

// ------------- phase D2: scan padded bin totals -------------
__global__ void kD2_scan(const int* __restrict__ binPadTot, int* __restrict__ binPadStart) {
    __shared__ int s[512];
    __shared__ int tot0, tot01;
    int t = threadIdx.x;
    int v = (t < NBt) ? binPadTot[t] : 0;
    s[t] = v;
    __syncthreads();
    for (int off = 1; off < 512; off <<= 1) {
        int x = (t >= off) ? s[t - off] : 0;
        __syncthreads();
        s[t] += x;
        __syncthreads();
    }
    if (t == 0) { tot0 = s[NB0 - 1]; tot01 = s[NB0 + NB1 - 1]; }
    __syncthreads();
    if (t < NBt) {
        int ex = s[t] - v;
        int cb, sub;
        if (t < NB0) { cb = 0; sub = 0; }
        else if (t < NB0 + NB1) { cb = P0c; sub = tot0; }
        else { cb = P0c + P1c; sub = tot01; }
        binPadStart[t] = cb + ex - sub;
    }
}

// ------------- phase D3: per-bin rowptr + COL scatter -------------
__global__ void kD3_final(const u32* __restrict__ BE, const int* __restrict__ binStart,
                          const int* __restrict__ CNT, const int* __restrict__ binPadStart,
                          int* __restrict__ rowptr, int* __restrict__ colAll) {
    __shared__ int lst[1024];
    __shared__ int lcur[1024];
    __shared__ int red[256];
    int b = blockIdx.x, t = threadIdx.x;
    int lv, bl; lvl_of_bin(b, lv, bl);
    int cbase, nLev, dummy;
    if (lv == 0) { cbase = 0; nLev = N0c; dummy = N0c; }
    else if (lv == 1) { cbase = N0c; nLev = N1c; dummy = N1c; }
    else { cbase = N0c + N1c; nLev = N2c; dummy = N2c; }
    int nodeB = bl << 10;
    int pc[4];
    int ps = 0;
#pragma unroll
    for (int j = 0; j < 4; j++) {
        int li = t * 4 + j;
        int node = nodeB + li;
        int c = (node < nLev) ? CNT[cbase + node] : 0;
        pc[j] = (c + 3) & ~3;
        ps += pc[j];
    }
    red[t] = ps;
    __syncthreads();
    for (int off = 1; off < 256; off <<= 1) {
        int x = (t >= off) ? red[t - off] : 0;
        __syncthreads();
        red[t] += x;
        __syncthreads();
    }
    int ex = red[t] - ps;
    int tot = red[255];
    int off = ex;
#pragma unroll
    for (int j = 0; j < 4; j++) {
        int li = t * 4 + j;
        lst[li] = off;
        lcur[li] = off;
        off += pc[j];
    }
    int cb = binPadStart[b];
#pragma unroll
    for (int j = 0; j < 4; j++) {
        int li = t * 4 + j;
        int node = nodeB + li;
        if (node < nLev) rowptr[cbase + node] = cb + lst[li];
    }
    __syncthreads();
    for (int i = t; i < tot; i += 256) colAll[cb + i] = dummy;
    __syncthreads();
    int s0 = binStart[b], s1 = binStart[b + 1];
    for (int i = s0 + t; i < s1; i += 256) {
        u32 e = BE[i];
        int p = atomicAdd(&lcur[e & 1023u], 1);
        colAll[cb + p] = (int)(e >> 10);
    }
}

// ---------------- 2-wide gather core ----------------
template <class SIn>
__device__ __forceinline__ fx2 gather2(const typename SIn::T* __restrict__ ys,
                                       const int* __restrict__ rp,
                                       const int* __restrict__ cnt,
                                       const int* __restrict__ col,
                                       const float* __restrict__ dinv,
                                       int node, int cp) {
    int s0 = rp[node];
    int nch = (cnt[node] + 3) >> 2;
    fx2 a = SIn::ld2(ys, (size_t)node * 16 + cp);
    const int4* c4 = (const int4*)(col + s0);
    for (int i = 0; i < nch; i++) {
        int4 cs = c4[i];
        fx2 a0 = SIn::ld2(ys, (size_t)cs.x * 16 + cp);
        fx2 a1 = SIn::ld2(ys, (size_t)cs.y * 16 + cp);
        fx2 a2 = SIn::ld2(ys, (size_t)cs.z * 16 + cp);
        fx2 a3 = SIn::ld2(ys, (size_t)cs.w * 16 + cp);
        a += (a0 + a1) + (a2 + a3);
    }
    float di = dinv[node];
    a *= di;
    return a;
}

// ---------------- K1: persistent fc1 + relu + prep1 -> bf16 ys (tiled) ----------------
constexpr int FC1_TILES = N0c / 64;   // 5880
__global__ void k_fc1prep(const void* __restrict__ x, const void* __restrict__ fw,
                          const void* __restrict__ fb, const void* __restrict__ w1,
                          const float* __restrict__ d0, u16* __restrict__ ys1,
                          const int* __restrict__ flag) {
    int isf32 = *flag;
    __shared__ float sx[256];
    __shared__ float sh[64 * 33];
    __shared__ float sfw[128];
    __shared__ float sfb[32];
    __shared__ float sw1[1024];
    int t = threadIdx.x;
    stage(sw1, w1, 1024, isf32);
    stage(sfw, fw, 128, isf32);
    stage(sfb, fb, 32, isf32);
    __syncthreads();
    int c = t & 31;
    int ng = t >> 5;       // 0..7
    int ci0 = t & 15;
    int rgrp = t >> 4;     // 0..15
    for (int tile = blockIdx.x; tile < FC1_TILES; tile += gridDim.x) {
        int nodeBase = tile * 64;
        sx[t] = rdf(x, nodeBase * 4 + t, isf32);
        __syncthreads();
#pragma unroll
        for (int i = 0; i < 8; i++) {
            int ln = ng + i * 8;
            float a = sfb[c];
#pragma unroll
            for (int k = 0; k < 4; k++) a = fmaf(sx[ln * 4 + k], sfw[k * 32 + c], a);
            sh[ln * 33 + c] = fmaxf(a, 0.0f);
        }
        __syncthreads();
        float acc[4][2];
#pragma unroll
        for (int r = 0; r < 4; r++) { acc[r][0] = 0.0f; acc[r][1] = 0.0f; }
#pragma unroll
        for (int k = 0; k < 32; k++) {
            float w0 = sw1[k * 32 + ci0];
            float w1v = sw1[k * 32 + ci0 + 16];
#pragma unroll
            for (int r = 0; r < 4; r++) {
                float s = sh[(rgrp * 4 + r) * 33 + k];
                acc[r][0] = fmaf(s, w0, acc[r][0]);
                acc[r][1] = fmaf(s, w1v, acc[r][1]);
            }
        }
#pragma unroll
        for (int r = 0; r < 4; r++) {
            int node = nodeBase + rgrp * 4 + r;
            float dv = d0[node];
            BF16S::st(ys1, (size_t)node * 32 + ci0, acc[r][0] * dv);
            BF16S::st(ys1, (size_t)node * 32 + ci0 + 16, acc[r][1] * dv);
        }
        __syncthreads();
    }
}

// ---------------- K2/K3: NPB nodes/block, gather + relu -> O(res dtype); fused prep_next ----------------
template <class SIn, class SRes, class SOut, int NPB>
__global__ void k_gds(const typename SIn::T* __restrict__ ys_in, const int* __restrict__ rp,
                      const int* __restrict__ cnt, const int* __restrict__ col,
                      const float* __restrict__ dinv_p, const void* __restrict__ b,
                      typename SRes::T* __restrict__ O, const void* __restrict__ wn,
                      const float* __restrict__ dinv_c, typename SOut::T* __restrict__ ys_out,
                      int cols, const int* __restrict__ flag) {
    int isf32 = *flag;
    __shared__ float sv[NPB * 32];
    __shared__ float swn[1024];
    int t = threadIdx.x;
    int nodeBase = blockIdx.x * NPB;
    int rb = nodeBase / cols;                    // cols % NPB == 0 -> whole block same row
    if (!(rb & 1)) stage(swn, wn, 1024, isf32);  // block-uniform
    int cp = t & 15;
#pragma unroll
    for (int i = 0; i < NPB / 16; i++) {
        int local = (t >> 4) + i * 16;
        int node = nodeBase + local;
        fx2 g = gather2<SIn>(ys_in, rp, cnt, col, dinv_p, node, cp);
        fx2 v;
        v.x = fmaxf(g.x + rdf(b, 2 * cp, isf32), 0.0f);
        v.y = fmaxf(g.y + rdf(b, 2 * cp + 1, isf32), 0.0f);
        SRes::st2nt(O, (size_t)node * 16 + cp, v);
        sv[local * 32 + 2 * cp] = v.x;
        sv[local * 32 + 2 * cp + 1] = v.y;
    }
    __syncthreads();
    if (!(rb & 1)) {
#pragma unroll
        for (int i = 0; i < NPB / 16; i++) {
            int item = t + i * 256;
            int childIdx = item >> 5;        // 0..NPB/2-1
            int ci = item & 31;
            int lc = childIdx * 2;           // even local node
            int cc = (nodeBase - rb * cols) + lc;
            int dn = (rb >> 1) * (cols >> 1) + (cc >> 1);
            float a = 0.0f;
#pragma unroll
            for (int k = 0; k < 32; k++) a = fmaf(sv[lc * 32 + k], swn[k * 32 + ci], a);
            SOut::st(ys_out, (size_t)dn * 32 + ci, a * dinv_c[dn]);
        }
    }
}

// ---------------- K4/K5: NPB parents/block, gather + up-residual + tiled prep_next ----------------
template <class SIn, class SRes, class SOut, int NPB>
__global__ void k_gup(const typename SIn::T* __restrict__ ys_in, const int* __restrict__ rp,
                      const int* __restrict__ cnt, const int* __restrict__ col,
                      const float* __restrict__ dinv_p, const void* __restrict__ b,
                      const typename SRes::T* __restrict__ R, const void* __restrict__ wn,
                      const float* __restrict__ dinv_c, typename SOut::T* __restrict__ ys_out,
                      int cols_p, const int* __restrict__ flag) {
    constexpr int RPT = NPB / 4;            // child rows per thread
    int isf32 = *flag;
    __shared__ float sv[NPB * 32];
    __shared__ float sch[NPB * 4 * 33];     // padded child rows
    __shared__ float swn[1024];
    int t = threadIdx.x;
    int nodeBase = blockIdx.x * NPB;
    stage(swn, wn, 1024, isf32);
    if (t < NPB * 16) {
        int local = t >> 4, cp = t & 15;
        int node = nodeBase + local;
        fx2 g = gather2<SIn>(ys_in, rp, cnt, col, dinv_p, node, cp);
        sv[local * 32 + 2 * cp] = fmaxf(g.x + rdf(b, 2 * cp, isf32), 0.0f);
        sv[local * 32 + 2 * cp + 1] = fmaxf(g.y + rdf(b, 2 * cp + 1, isf32), 0.0f);
    }
    __syncthreads();
    int rb = nodeBase / cols_p;
    int ccb = nodeBase - rb * cols_p;
    int cols_c = cols_p * 2;
#pragma unroll
    for (int i = 0; i < NPB / 2; i++) {
        int item = t + i * 256;
        int row = item >> 5, k = item & 31;
        int lp = row >> 2, j = row & 3;
        int ch = (2 * rb + (j >> 1)) * cols_c + 2 * (ccb + lp) + (j & 1);
        sch[row * 33 + k] = SRes::ld(R, (size_t)ch * 32 + k) + sv[lp * 32 + k];
    }
    __syncthreads();
    int ci0 = t & 15;
    int rgrp = t >> 4;   // 0..15
    float acc[RPT][2];
#pragma unroll
    for (int r = 0; r < RPT; r++) { acc[r][0] = 0.0f; acc[r][1] = 0.0f; }
#pragma unroll
    for (int k = 0; k < 32; k++) {
        float w0 = swn[k * 32 + ci0];
        float w1v = swn[k * 32 + ci0 + 16];
#pragma unroll
        for (int r = 0; r < RPT; r++) {
            float s = sch[(rgrp * RPT + r) * 33 + k];
            acc[r][0] = fmaf(s, w0, acc[r][0]);
            acc[r][1] = fmaf(s, w1v, acc[r][1]);
        }
    }
#pragma unroll
    for (int r = 0; r < RPT; r++) {
        int row = rgrp * RPT + r;
        int lp = row >> 2, j = row & 3;
        int ch = (2 * rb + (j >> 1)) * cols_c + 2 * (ccb + lp) + (j & 1);
        float dc = dinv_c[ch];
        SOut::st(ys_out, (size_t)ch * 32 + ci0, acc[r][0] * dc);
        SOut::st(ys_out, (size_t)ch * 32 + ci0 + 16, acc[r][1] * dc);
    }
}

// ---------------- K6: 32 nodes/block, gather + relu + fc2 -> out ----------------
__global__ void k_gfc2(const u16* __restrict__ ys, const int* __restrict__ rp,
                       const int* __restrict__ cnt, const int* __restrict__ col,
                       const float* __restrict__ dinv, const void* __restrict__ b5,
                       const void* __restrict__ fw, const void* __restrict__ fb,
                       void* __restrict__ out, int n, const int* __restrict__ flag) {
    int isf32 = *flag;
    __shared__ float sv[1024];
    __shared__ float sw[96];
    __shared__ float sfb[3];
    int t = threadIdx.x;
    if (t < 96) sw[t] = rdf(fw, t, isf32);
    if (t < 3) sfb[t] = rdf(fb, t, isf32);
    int nodeBase = blockIdx.x * 32;
    int cp = t & 15;
#pragma unroll
    for (int i = 0; i < 2; i++) {
        int local = (t >> 4) + i * 16;
        int node = nodeBase + local;
        fx2 g = gather2<BF16S>(ys, rp, cnt, col, dinv, node, cp);
        sv[local * 32 + 2 * cp] = fmaxf(g.x + rdf(b5, 2 * cp, isf32), 0.0f);
        sv[local * 32 + 2 * cp + 1] = fmaxf(g.y + rdf(b5, 2 * cp + 1, isf32), 0.0f);
    }
    __syncthreads();
    if (t < 96) {
        int ln = t / 3, j = t - ln * 3;
        int gn = nodeBase + ln;
        float o = sfb[j];
#pragma unroll
        for (int k = 0; k < 32; k++) o = fmaf(sv[ln * 32 + k], sw[k * 3 + j], o);
        if (isf32) ((float*)out)[(size_t)gn * 3 + j] = o;
        else ((u16*)out)[(size_t)gn * 3 + j] = f2bf(o);
    }
}

extern "C" void kernel_launch(void* const* d_in, const int* in_sizes, int n_in,
                              void* d_out, int out_size, void* d_ws, size_t ws_size,
                              hipStream_t stream) {
    const void* x    = d_in[0];
    const void* fc1w = d_in[1];
    const void* fc1b = d_in[2];
    const void* w1 = d_in[3];  const void* b1 = d_in[4];
    const void* w2 = d_in[5];  const void* b2 = d_in[6];
    const void* w3 = d_in[7];  const void* b3 = d_in[8];
    const void* w4 = d_in[9];  const void* b4 = d_in[10];
    const void* w5 = d_in[11]; const void* b5 = d_in[12];
    const void* fc2w = d_in[13]; const void* fc2b = d_in[14];
    const int* ei0 = (const int*)d_in[18];
    const int* ei1 = (const int*)d_in[19];
    const int* ei2 = (const int*)d_in[20];

    // all residuals + ys in bf16 now
    u16* YS0 = (u16*)d_ws;                                  // (N0+1)*32
    u16* A   = YS0 + (size_t)(N0c + 1) * 32;                // N0*32  (h_b residual, bf16)
    u16* YS1 = A + (size_t)N0c * 32;                        // (N1+1)*32
    u16* H1  = YS1 + (size_t)(N1c + 1) * 32;                // N1*32  (h1_b residual, bf16)
    u16* YS2 = H1 + (size_t)N1c * 32;                       // (N2+1)*32
    float* DINV = (float*)(YS2 + (size_t)(N2c + 1) * 32);   // NT
    int* CNT   = (int*)(DINV + NTc);
    int* RPA   = CNT + NTc;
    int* COLA  = RPA + NTc;
    u32* BE    = (u32*)(COLA + Ptot);                       // Etot packed edges
    int* binCnt      = (int*)(BE + Etot);
    int* binStart    = binCnt + NBt;
    int* binCursor   = binStart + NBt + 1;
    int* binPadTot   = binCursor + NBt;
    int* binPadStart = binPadTot + NBt;
    int* FLAG        = binPadStart + NBt;

    float* D0 = DINV; float* D1 = D0 + N0c; float* D2 = D1 + N1c;
    int* C0 = CNT;  int* C1 = C0 + N0c;  int* C2 = C1 + N1c;
    int* RP0 = RPA; int* RP1 = RP0 + N0c; int* RP2 = RP1 + N1c;

    const int Bk = 256;

    k_dinit<<<2, Bk, 0, stream>>>((const u32*)x, FLAG, binCnt,
                                  YS0 + (size_t)N0c * 32, YS1 + (size_t)N1c * 32,
                                  YS2 + (size_t)N2c * 32);

    kA_count<<<NBt, Bk, 0, stream>>>(ei0, ei1, ei2, binCnt);
    kB_scan<<<1, 512, 0, stream>>>(binCnt, binStart, binCursor);
    kC_place<<<NBt, Bk, 0, stream>>>(ei0, ei1, ei2, binCursor, BE);
    kD1_count<<<NBt, Bk, 0, stream>>>(BE, binStart, CNT, DINV, binPadTot);
    kD2_scan<<<1, 512, 0, stream>>>(binPadTot, binPadStart);
    kD3_final<<<NBt, Bk, 0, stream>>>(BE, binStart, CNT, binPadStart, RPA, COLA);

    // K1: persistent fc1+relu+prep1 -> YS0 (bf16)
    k_fc1prep<<<1960, Bk, 0, stream>>>(x, fc1w, fc1b, w1, D0, YS0, FLAG);
    // K2: gather1 -> A (bf16 res), fused prep2 -> YS1 (bf16)
    k_gds<BF16S, BF16S, BF16S, 32><<<N0c / 32, Bk, 0, stream>>>(YS0, RP0, C0, COLA, D0, b1, A, w2, D1, YS1, NYg, FLAG);
    // K3: gather2 -> H1 (bf16 res), fused prep3 -> YS2 (bf16)
    k_gds<BF16S, BF16S, BF16S, 16><<<N1c / 16, Bk, 0, stream>>>(YS1, RP1, C1, COLA, D1, b2, H1, w3, D2, YS2, NYg / 2, FLAG);
    // K4: gather3 + up-residual(H1 bf16) + prep4 -> YS1 (bf16); 8 parents
    k_gup<BF16S, BF16S, BF16S, 8><<<N2c / 8, Bk, 0, stream>>>(YS2, RP2, C2, COLA, D2, b3, H1, w4, D1, YS1, NYg / 4, FLAG);
    // K5: gather4 + up-residual(A bf16) + prep5 -> YS0 (bf16); 16 parents
    k_gup<BF16S, BF16S, BF16S, 16><<<N1c / 16, Bk, 0, stream>>>(YS1, RP1, C1, COLA, D1, b4, A, w5, D0, YS0, NYg / 2, FLAG);
    // K6: gather5 + fc2 -> out
    k_gfc2<<<N0c / 32, Bk, 0, stream>>>(YS0, RP0, C0, COLA, D0, b5, fc2w, fc2b, d_out, N0c, FLAG);
}

// Round 13
// 337.841 us; speedup vs baseline: 1.6051x; 1.0400x over previous
//
#include <hip/hip_runtime.h>
#include <hip/hip_bf16.h>

typedef unsigned short u16;
typedef unsigned int u32;
typedef float fx2 __attribute__((ext_vector_type(2)));

#define NXg 784
#define NYg 480
constexpr int N0c = NXg * NYg;   // 376320
constexpr int N1c = N0c / 4;     // 94080
constexpr int N2c = N0c / 16;    // 23520
constexpr int NTc = N0c + N1c + N2c;
constexpr int E0c = 4 * N0c;
constexpr int E1c = 4 * N1c;
constexpr int E2c = 4 * N2c;
constexpr int Etot = E0c + E1c + E2c;
constexpr int NB0 = (N0c + 1023) / 1024;   // 368
constexpr int NB1 = (N1c + 1023) / 1024;   // 92
constexpr int NB2 = (N2c + 1023) / 1024;   // 23
constexpr int NBt = NB0 + NB1 + NB2;       // 483
constexpr int COLcap = Etot + 3076 * NBt + 16;   // fixed-capacity COL regions

__device__ __forceinline__ float bf2f(u16 v) {
    union { u32 u; float f; } t; t.u = ((u32)v) << 16; return t.f;
}
__device__ __forceinline__ u16 f2bf(float f) {
    union { float f; u32 u; } t; t.f = f;
    u32 u = t.u;
    u32 r = (u + 0x7fffu + ((u >> 16) & 1u)) >> 16;   // RNE
    return (u16)r;
}
__device__ __forceinline__ float rdf(const void* p, int i, int isf32) {
    if (isf32) return ((const float*)p)[i];
    return bf2f(((const u16*)p)[i]);
}
__device__ __forceinline__ void stage(float* dst, const void* src, int n, int isf32) {
    int t = threadIdx.x;
    if (isf32) {
        const float* s = (const float*)src;
        for (int i = t; i < n; i += 256) dst[i] = s[i];
    } else {
        const u16* s = (const u16*)src;
        for (int i = t; i < n; i += 256) dst[i] = bf2f(s[i]);
    }
}

// ---- storage traits ----
struct BF16S {
    typedef u16 T;
    static __device__ __forceinline__ float ld(const T* p, size_t i) { return bf2f(p[i]); }
    static __device__ __forceinline__ void st(T* p, size_t i, float v) { p[i] = f2bf(v); }
    static __device__ __forceinline__ fx2 ld2(const T* p, size_t i) {
        u32 w = ((const u32*)p)[i];
        fx2 r; r.x = bf2f((u16)(w & 0xffffu)); r.y = bf2f((u16)(w >> 16));
        return r;
    }
    static __device__ __forceinline__ void st2nt(T* p, size_t i, fx2 v) {
        u32 w = (u32)f2bf(v.x) | ((u32)f2bf(v.y) << 16);
        __builtin_nontemporal_store(w, (u32*)p + i);
    }
};

__device__ __forceinline__ void lvl_of_bin(int b, int& lv, int& bl) {
    if (b < NB0) { lv = 0; bl = b; }
    else if (b < NB0 + NB1) { lv = 1; bl = b - NB0; }
    else { lv = 2; bl = b - NB0 - NB1; }
}

// ------------- detect dtype + init (merged) -------------
__global__ void k_dinit(const u32* __restrict__ xw, int* __restrict__ flag,
                        int* __restrict__ binCnt, u16* __restrict__ y0,
                        u16* __restrict__ y1, u16* __restrict__ y2) {
    __shared__ int cnt;
    int t = threadIdx.x;
    int g = blockIdx.x * 256 + t;
    if (blockIdx.x == 0) {
        if (t == 0) cnt = 0;
        __syncthreads();
        u32 w = xw[t];
        int e = (int)((w >> 7) & 0xFFu);
        int hit = ((e >= 90 && e <= 135) || ((w & 0x7FFFu) == 0u)) ? 1 : 0;
        atomicAdd(&cnt, hit);
        __syncthreads();
        if (t == 0) *flag = (cnt < 192) ? 1 : 0;
    }
    if (g < NBt) binCnt[g] = 0;
    if (blockIdx.x == 1 && t < 32) { y0[t] = 0; y1[t] = 0; y2[t] = 0; }
}

// ------------- phase A: bin counts -------------
__global__ void kA_count(const int* __restrict__ ei0, const int* __restrict__ ei1,
                         const int* __restrict__ ei2, int* __restrict__ binCnt) {
    __shared__ int lc[NB0];
    int b = blockIdx.x, t = threadIdx.x;
    int lv, bl; lvl_of_bin(b, lv, bl);
    const int* dstp; int E, nb, binB;
    if (lv == 0) { dstp = ei0 + E0c; E = E0c; nb = NB0; binB = 0; }
    else if (lv == 1) { dstp = ei1 + E1c; E = E1c; nb = NB1; binB = NB0; }
    else { dstp = ei2 + E2c; E = E2c; nb = NB2; binB = NB0 + NB1; }
    for (int i = t; i < nb; i += 256) lc[i] = 0;
    __syncthreads();
    int e0 = bl * 4096, e1 = min(E, e0 + 4096);
    for (int i = e0 + t; i < e1; i += 256) atomicAdd(&lc[dstp[i] >> 10], 1);
    __syncthreads();
    for (int i = t; i < nb; i += 256) if (lc[i]) atomicAdd(&binCnt[binB + i], lc[i]);
}

// ------------- phase B: scan bins -------------
__global__ void kB_scan(const int* __restrict__ binCnt, int* __restrict__ binStart,
                        int* __restrict__ binCursor) {
    __shared__ int s[512];
    int t = threadIdx.x;
    int v = (t < NBt) ? binCnt[t] : 0;
    s[t] = v;
    __syncthreads();
    for (int off = 1; off < 512; off <<= 1) {
        int x = (t >= off) ? s[t - off] : 0;
        __syncthreads();
        s[t] += x;
        __syncthreads();
    }
    if (t < NBt) { int e = s[t] - v; binStart[t] = e; binCursor[t] = e; }
    if (t == 0) binStart[NBt] = Etot;
}

// ------------- phase C: place packed (src<<10 | dstLow) into bin regions -------------
__global__ void kC_place(const int* __restrict__ ei0, const int* __restrict__ ei1,
                         const int* __restrict__ ei2, int* __restrict__ binCursor,
                         u32* __restrict__ BE) {
    __shared__ int lc[NB0];
    __shared__ int lb[NB0];
    int b = blockIdx.x, t = threadIdx.x;
    int lv, bl; lvl_of_bin(b, lv, bl);
    const int* srcp; const int* dstp; int E, nb, binB;
    if (lv == 0) { srcp = ei0; dstp = ei0 + E0c; E = E0c; nb = NB0; binB = 0; }
    else if (lv == 1) { srcp = ei1; dstp = ei1 + E1c; E = E1c; nb = NB1; binB = NB0; }
    else { srcp = ei2; dstp = ei2 + E2c; E = E2c; nb = NB2; binB = NB0 + NB1; }
    for (int i = t; i < nb; i += 256) lc[i] = 0;
    __syncthreads();
    int e0 = bl * 4096, e1 = min(E, e0 + 4096);
    for (int i = e0 + t; i < e1; i += 256) atomicAdd(&lc[dstp[i] >> 10], 1);
    __syncthreads();
    for (int i = t; i < nb; i += 256) {
        int c = lc[i];
        lb[i] = c ? atomicAdd(&binCursor[binB + i], c) : 0;
        lc[i] = 0;
    }
    __syncthreads();
    for (int i = e0 + t; i < e1; i += 256) {
        int d = dstp[i];
        int bn = d >> 10;
        int p = atomicAdd(&lc[bn], 1);
        BE[lb[bn] + p] = ((u32)srcp[i] << 10) | (u32)(d & 1023);
    }
}

// ------------- phase D (merged): counts -> DINV + RPC + COL fill/scatter -------------
// Fixed-capacity COL region per bin: cb = (binStart[b]&~3) + 3076*b (capacity >= binCnt+3073)
__global__ void kD_all(const u32* __restrict__ BE, const int* __restrict__ binStart,
                       float* __restrict__ DINV, u32* __restrict__ RPC,
                       int* __restrict__ colAll) {
    __shared__ int lc[1024];
    __shared__ int lst[1024];
    __shared__ int lcur[1024];
    __shared__ int red[256];
    int b = blockIdx.x, t = threadIdx.x;
    int lv, bl; lvl_of_bin(b, lv, bl);
    int cbase, nLev, dummy;
    if (lv == 0) { cbase = 0; nLev = N0c; dummy = N0c; }
    else if (lv == 1) { cbase = N0c; nLev = N1c; dummy = N1c; }
    else { cbase = N0c + N1c; nLev = N2c; dummy = N2c; }
    for (int i = t; i < 1024; i += 256) lc[i] = 0;
    __syncthreads();
    int s0 = binStart[b], s1 = binStart[b + 1];
    for (int i = s0 + t; i < s1; i += 256) atomicAdd(&lc[BE[i] & 1023u], 1);
    __syncthreads();
    int nodeB = bl << 10;
    int pc[4];
    int ps = 0;
#pragma unroll
    for (int j = 0; j < 4; j++) {
        int li = t * 4 + j;
        int node = nodeB + li;
        int c = (node < nLev) ? lc[li] : 0;
        pc[j] = (c + 3) & ~3;
        ps += pc[j];
    }
    red[t] = ps;
    __syncthreads();
    for (int off = 1; off < 256; off <<= 1) {
        int x = (t >= off) ? red[t - off] : 0;
        __syncthreads();
        red[t] += x;
        __syncthreads();
    }
    int ex = red[t] - ps;
    int tot = red[255];
    int cb = (s0 & ~3) + 3076 * b;
    int off = ex;
#pragma unroll
    for (int j = 0; j < 4; j++) {
        int li = t * 4 + j;
        lst[li] = off;
        lcur[li] = off;
        off += pc[j];
    }
    __syncthreads();   // lst/lcur visible before scatter; also lc reads done
#pragma unroll
    for (int j = 0; j < 4; j++) {
        int li = t * 4 + j;
        int node = nodeB + li;
        if (node < nLev) {
            int c = lc[li];
            DINV[cbase + node] = rsqrtf((float)c + 1.0f);
            int rp = cb + lst[li];                    // multiple of 4
            u32 nch = (u32)((c + 3) >> 2);
            RPC[cbase + node] = ((u32)(rp >> 2) << 10) | nch;
        }
    }
    // fill bin region with dummy, then scatter (BE re-read is L2-hot)
    for (int i = t; i < tot; i += 256) colAll[cb + i] = dummy;
    __syncthreads();
    for (int i = s0 + t; i < s1; i += 256) {
        u32 e = BE[i];
        int p = atomicAdd(&lcur[e & 1023u], 1);
        colAll[cb + p] = (int)(e >> 10);
    }
}

// ---------------- 2-wide gather core (RPC: packed rowptr|nch) ----------------
__device__ __forceinline__ fx2 gather2(const u16* __restrict__ ys,
                                       const u32* __restrict__ rpc,
                                       const int* __restrict__ col,
                                       const float* __restrict__ dinv,
                                       int node, int cp) {
    u32 v = rpc[node];
    int s0 = (int)((v >> 10) << 2);
    int nch = (int)(v & 1023u);
    fx2 a = BF16S::ld2(ys, (size_t)node * 16 + cp);
    const int4* c4 = (const int4*)(col + s0);
    for (int i = 0; i < nch; i++) {
        int4 cs = c4[i];
        fx2 a0 = BF16S::ld2(ys, (size_t)cs.x * 16 + cp);
        fx2 a1 = BF16S::ld2(ys, (size_t)cs.y * 16 + cp);
        fx2 a2 = BF16S::ld2(ys, (size_t)cs.z * 16 + cp);
        fx2 a3 = BF16S::ld2(ys, (size_t)cs.w * 16 + cp);
        a += (a0 + a1) + (a2 + a3);
    }
    float di = dinv[node];
    a *= di;
    return a;
}

// ---------------- K1: persistent fc1 + relu + prep1 -> bf16 ys (tiled) ----------------
constexpr int FC1_TILES = N0c / 64;   // 5880
__global__ void k_fc1prep(const void* __restrict__ x, const void* __restrict__ fw,
                          const void* __restrict__ fb, const void* __restrict__ w1,
                          const float* __restrict__ d0, u16* __restrict__ ys1,
                          const int* __restrict__ flag) {
    int isf32 = *flag;
    __shared__ float sx[256];
    __shared__ float sh[64 * 33];
    __shared__ float sfw[128];
    __shared__ float sfb[32];
    __shared__ float sw1[1024];
    int t = threadIdx.x;
    stage(sw1, w1, 1024, isf32);
    stage(sfw, fw, 128, isf32);
    stage(sfb, fb, 32, isf32);
    __syncthreads();
    int c = t & 31;
    int ng = t >> 5;       // 0..7
    int ci0 = t & 15;
    int rgrp = t >> 4;     // 0..15
    for (int tile = blockIdx.x; tile < FC1_TILES; tile += gridDim.x) {
        int nodeBase = tile * 64;
        sx[t] = rdf(x, nodeBase * 4 + t, isf32);
        __syncthreads();
#pragma unroll
        for (int i = 0; i < 8; i++) {
            int ln = ng + i * 8;
            float a = sfb[c];
#pragma unroll
            for (int k = 0; k < 4; k++) a = fmaf(sx[ln * 4 + k], sfw[k * 32 + c], a);
            sh[ln * 33 + c] = fmaxf(a, 0.0f);
        }
        __syncthreads();
        float acc[4][2];
#pragma unroll
        for (int r = 0; r < 4; r++) { acc[r][0] = 0.0f; acc[r][1] = 0.0f; }
#pragma unroll
        for (int k = 0; k < 32; k++) {
            float w0 = sw1[k * 32 + ci0];
            float w1v = sw1[k * 32 + ci0 + 16];
#pragma unroll
            for (int r = 0; r < 4; r++) {
                float s = sh[(rgrp * 4 + r) * 33 + k];
                acc[r][0] = fmaf(s, w0, acc[r][0]);
                acc[r][1] = fmaf(s, w1v, acc[r][1]);
            }
        }
#pragma unroll
        for (int r = 0; r < 4; r++) {
            int node = nodeBase + rgrp * 4 + r;
            float dv = d0[node];
            BF16S::st(ys1, (size_t)node * 32 + ci0, acc[r][0] * dv);
            BF16S::st(ys1, (size_t)node * 32 + ci0 + 16, acc[r][1] * dv);
        }
        __syncthreads();
    }
}

// ---------------- K2/K3: NPB nodes/block, gather + relu -> O; fused prep_next ----------------
template <int NPB>
__global__ void k_gds(const u16* __restrict__ ys_in, const u32* __restrict__ rpc,
                      const int* __restrict__ col,
                      const float* __restrict__ dinv_p, const void* __restrict__ b,
                      u16* __restrict__ O, const void* __restrict__ wn,
                      const float* __restrict__ dinv_c, u16* __restrict__ ys_out,
                      int cols, const int* __restrict__ flag) {
    int isf32 = *flag;
    __shared__ float sv[NPB * 32];
    __shared__ float swn[1024];
    int t = threadIdx.x;
    int nodeBase = blockIdx.x * NPB;
    int rb = nodeBase / cols;                    // cols % NPB == 0 -> whole block same row
    if (!(rb & 1)) stage(swn, wn, 1024, isf32);  // block-uniform
    int cp = t & 15;
#pragma unroll
    for (int i = 0; i < NPB / 16; i++) {
        int local = (t >> 4) + i * 16;
        int node = nodeBase + local;
        fx2 g = gather2(ys_in, rpc, col, dinv_p, node, cp);
        fx2 v;
        v.x = fmaxf(g.x + rdf(b, 2 * cp, isf32), 0.0f);
        v.y = fmaxf(g.y + rdf(b, 2 * cp + 1, isf32), 0.0f);
        BF16S::st2nt(O, (size_t)node * 16 + cp, v);
        sv[local * 32 + 2 * cp] = v.x;
        sv[local * 32 + 2 * cp + 1] = v.y;
    }
    __syncthreads();
    if (!(rb & 1)) {
#pragma unroll
        for (int i = 0; i < NPB / 16; i++) {
            int item = t + i * 256;
            int childIdx = item >> 5;        // 0..NPB/2-1
            int ci = item & 31;
            int lc = childIdx * 2;           // even local node
            int cc = (nodeBase - rb * cols) + lc;
            int dn = (rb >> 1) * (cols >> 1) + (cc >> 1);
            float a = 0.0f;
#pragma unroll
            for (int k = 0; k < 32; k++) a = fmaf(sv[lc * 32 + k], swn[k * 32 + ci], a);
            BF16S::st(ys_out, (size_t)dn * 32 + ci, a * dinv_c[dn]);
        }
    }
}

// ---------------- K4/K5: NPB parents/block, gather + up-residual + tiled prep_next ----------------
template <int NPB>
__global__ void k_gup(const u16* __restrict__ ys_in, const u32* __restrict__ rpc,
                      const int* __restrict__ col,
                      const float* __restrict__ dinv_p, const void* __restrict__ b,
                      const u16* __restrict__ R, const void* __restrict__ wn,
                      const float* __restrict__ dinv_c, u16* __restrict__ ys_out,
                      int cols_p, const int* __restrict__ flag) {
    constexpr int RPT = NPB / 4;            // child rows per thread
    int isf32 = *flag;
    __shared__ float sv[NPB * 32];
    __shared__ float sch[NPB * 4 * 33];     // padded child rows
    __shared__ float swn[1024];
    int t = threadIdx.x;
    int nodeBase = blockIdx.x * NPB;
    stage(swn, wn, 1024, isf32);
    if (t < NPB * 16) {
        int local = t >> 4, cp = t & 15;
        int node = nodeBase + local;
        fx2 g = gather2(ys_in, rpc, col, dinv_p, node, cp);
        sv[local * 32 + 2 * cp] = fmaxf(g.x + rdf(b, 2 * cp, isf32), 0.0f);
        sv[local * 32 + 2 * cp + 1] = fmaxf(g.y + rdf(b, 2 * cp + 1, isf32), 0.0f);
    }
    __syncthreads();
    int rb = nodeBase / cols_p;
    int ccb = nodeBase - rb * cols_p;
    int cols_c = cols_p * 2;
#pragma unroll
    for (int i = 0; i < NPB / 2; i++) {
        int item = t + i * 256;
        int row = item >> 5, k = item & 31;
        int lp = row >> 2, j = row & 3;
        int ch = (2 * rb + (j >> 1)) * cols_c + 2 * (ccb + lp) + (j & 1);
        sch[row * 33 + k] = bf2f(R[(size_t)ch * 32 + k]) + sv[lp * 32 + k];
    }
    __syncthreads();
    int ci0 = t & 15;
    int rgrp = t >> 4;   // 0..15
    float acc[RPT][2];
#pragma unroll
    for (int r = 0; r < RPT; r++) { acc[r][0] = 0.0f; acc[r][1] = 0.0f; }
#pragma unroll
    for (int k = 0; k < 32; k++) {
        float w0 = swn[k * 32 + ci0];
        float w1v = swn[k * 32 + ci0 + 16];
#pragma unroll
        for (int r = 0; r < RPT; r++) {
            float s = sch[(rgrp * RPT + r) * 33 + k];
            acc[r][0] = fmaf(s, w0, acc[r][0]);
            acc[r][1] = fmaf(s, w1v, acc[r][1]);
        }
    }
#pragma unroll
    for (int r = 0; r < RPT; r++) {
        int row = rgrp * RPT + r;
        int lp = row >> 2, j = row & 3;
        int ch = (2 * rb + (j >> 1)) * cols_c + 2 * (ccb + lp) + (j & 1);
        float dc = dinv_c[ch];
        BF16S::st(ys_out, (size_t)ch * 32 + ci0, acc[r][0] * dc);
        BF16S::st(ys_out, (size_t)ch * 32 + ci0 + 16, acc[r][1] * dc);
    }
}

// ---------------- K6: 32 nodes/block, gather + relu + fc2 -> out ----------------
__global__ void k_gfc2(const u16* __restrict__ ys, const u32* __restrict__ rpc,
                       const int* __restrict__ col,
                       const float* __restrict__ dinv, const void* __restrict__ b5,
                       const void* __restrict__ fw, const void* __restrict__ fb,
                       void* __restrict__ out, int n, const int* __restrict__ flag) {
    int isf32 = *flag;
    __shared__ float sv[1024];
    __shared__ float sw[96];
    __shared__ float sfb[3];
    int t = threadIdx.x;
    if (t < 96) sw[t] = rdf(fw, t, isf32);
    if (t < 3) sfb[t] = rdf(fb, t, isf32);
    int nodeBase = blockIdx.x * 32;
    int cp = t & 15;
#pragma unroll
    for (int i = 0; i < 2; i++) {
        int local = (t >> 4) + i * 16;
        int node = nodeBase + local;
        fx2 g = gather2(ys, rpc, col, dinv, node, cp);
        sv[local * 32 + 2 * cp] = fmaxf(g.x + rdf(b5, 2 * cp, isf32), 0.0f);
        sv[local * 32 + 2 * cp + 1] = fmaxf(g.y + rdf(b5, 2 * cp + 1, isf32), 0.0f);
    }
    __syncthreads();
    if (t < 96) {
        int ln = t / 3, j = t - ln * 3;
        int gn = nodeBase + ln;
        float o = sfb[j];
#pragma unroll
        for (int k = 0; k < 32; k++) o = fmaf(sv[ln * 32 + k], sw[k * 3 + j], o);
        if (isf32) ((float*)out)[(size_t)gn * 3 + j] = o;
        else ((u16*)out)[(size_t)gn * 3 + j] = f2bf(o);
    }
}

extern "C" void kernel_launch(void* const* d_in, const int* in_sizes, int n_in,
                              void* d_out, int out_size, void* d_ws, size_t ws_size,
                              hipStream_t stream) {
    const void* x    = d_in[0];
    const void* fc1w = d_in[1];
    const void* fc1b = d_in[2];
    const void* w1 = d_in[3];  const void* b1 = d_in[4];
    const void* w2 = d_in[5];  const void* b2 = d_in[6];
    const void* w3 = d_in[7];  const void* b3 = d_in[8];
    const void* w4 = d_in[9];  const void* b4 = d_in[10];
    const void* w5 = d_in[11]; const void* b5 = d_in[12];
    const void* fc2w = d_in[13]; const void* fc2b = d_in[14];
    const int* ei0 = (const int*)d_in[18];
    const int* ei1 = (const int*)d_in[19];
    const int* ei2 = (const int*)d_in[20];

    u16* YS0 = (u16*)d_ws;                                  // (N0+1)*32
    u16* A   = YS0 + (size_t)(N0c + 1) * 32;                // N0*32  (h_b residual)
    u16* YS1 = A + (size_t)N0c * 32;                        // (N1+1)*32
    u16* H1  = YS1 + (size_t)(N1c + 1) * 32;                // N1*32  (h1_b residual)
    u16* YS2 = H1 + (size_t)N1c * 32;                       // (N2+1)*32
    float* DINV = (float*)(YS2 + (size_t)(N2c + 1) * 32);   // NT
    u32* RPC  = (u32*)(DINV + NTc);                         // NT (packed rowptr|nch)
    int* COLA = (int*)(RPC + NTc);                          // COLcap
    u32* BE   = (u32*)(COLA + COLcap);                      // Etot packed edges
    int* binCnt    = (int*)(BE + Etot);
    int* binStart  = binCnt + NBt;                          // NBt+1
    int* binCursor = binStart + NBt + 1;
    int* FLAG      = binCursor + NBt;

    float* D0 = DINV; float* D1 = D0 + N0c; float* D2 = D1 + N1c;
    u32* RPC0 = RPC; u32* RPC1 = RPC0 + N0c; u32* RPC2 = RPC1 + N1c;

    const int Bk = 256;

    k_dinit<<<2, Bk, 0, stream>>>((const u32*)x, FLAG, binCnt,
                                  YS0 + (size_t)N0c * 32, YS1 + (size_t)N1c * 32,
                                  YS2 + (size_t)N2c * 32);

    kA_count<<<NBt, Bk, 0, stream>>>(ei0, ei1, ei2, binCnt);
    kB_scan<<<1, 512, 0, stream>>>(binCnt, binStart, binCursor);
    kC_place<<<NBt, Bk, 0, stream>>>(ei0, ei1, ei2, binCursor, BE);
    kD_all<<<NBt, Bk, 0, stream>>>(BE, binStart, DINV, RPC, COLA);

    // K1: persistent fc1+relu+prep1 -> YS0
    k_fc1prep<<<1960, Bk, 0, stream>>>(x, fc1w, fc1b, w1, D0, YS0, FLAG);
    // K2: gather1 -> A, fused prep2 -> YS1
    k_gds<32><<<N0c / 32, Bk, 0, stream>>>(YS0, RPC0, COLA, D0, b1, A, w2, D1, YS1, NYg, FLAG);
    // K3: gather2 -> H1, fused prep3 -> YS2
    k_gds<16><<<N1c / 16, Bk, 0, stream>>>(YS1, RPC1, COLA, D1, b2, H1, w3, D2, YS2, NYg / 2, FLAG);
    // K4: gather3 + up-residual(H1) + prep4 -> YS1; 8 parents
    k_gup<8><<<N2c / 8, Bk, 0, stream>>>(YS2, RPC2, COLA, D2, b3, H1, w4, D1, YS1, NYg / 4, FLAG);
    // K5: gather4 + up-residual(A) + prep5 -> YS0; 16 parents
    k_gup<16><<<N1c / 16, Bk, 0, stream>>>(YS1, RPC1, COLA, D1, b4, A, w5, D0, YS0, NYg / 2, FLAG);
    // K6: gather5 + fc2 -> out
    k_gfc2<<<N0c / 32, Bk, 0, stream>>>(YS0, RPC0, COLA, D0, b5, fc2w, fc2b, d_out, N0c, FLAG);
}

// Round 14
// 331.165 us; speedup vs baseline: 1.6374x; 1.0202x over previous
//
#include <hip/hip_runtime.h>
#include <hip/hip_bf16.h>

typedef unsigned short u16;
typedef unsigned int u32;
typedef float fx2 __attribute__((ext_vector_type(2)));

#define NXg 784
#define NYg 480
constexpr int N0c = NXg * NYg;   // 376320
constexpr int N1c = N0c / 4;     // 94080
constexpr int N2c = N0c / 16;    // 23520
constexpr int NTc = N0c + N1c + N2c;
constexpr int E0c = 4 * N0c;
constexpr int E1c = 4 * N1c;
constexpr int E2c = 4 * N2c;
// 512-node bins
constexpr int NB0 = (N0c + 511) / 512;   // 735
constexpr int NB1 = (N1c + 511) / 512;   // 184
constexpr int NB2 = (N2c + 511) / 512;   // 46
constexpr int NBt = NB0 + NB1 + NB2;     // 965
constexpr int ECAP = 2560;               // BE capacity per bin (mean 2048, +11 sigma)
constexpr int CCAP = 4096;               // COL capacity per bin (exact worst-case padded bound)

__device__ __forceinline__ float bf2f(u16 v) {
    union { u32 u; float f; } t; t.u = ((u32)v) << 16; return t.f;
}
__device__ __forceinline__ u16 f2bf(float f) {
    union { float f; u32 u; } t; t.f = f;
    u32 u = t.u;
    u32 r = (u + 0x7fffu + ((u >> 16) & 1u)) >> 16;   // RNE
    return (u16)r;
}
__device__ __forceinline__ float rdf(const void* p, int i, int isf32) {
    if (isf32) return ((const float*)p)[i];
    return bf2f(((const u16*)p)[i]);
}
__device__ __forceinline__ void stage(float* dst, const void* src, int n, int isf32) {
    int t = threadIdx.x;
    if (isf32) {
        const float* s = (const float*)src;
        for (int i = t; i < n; i += 256) dst[i] = s[i];
    } else {
        const u16* s = (const u16*)src;
        for (int i = t; i < n; i += 256) dst[i] = bf2f(s[i]);
    }
}

struct BF16S {
    typedef u16 T;
    static __device__ __forceinline__ float ld(const T* p, size_t i) { return bf2f(p[i]); }
    static __device__ __forceinline__ void st(T* p, size_t i, float v) { p[i] = f2bf(v); }
    static __device__ __forceinline__ fx2 ld2(const T* p, size_t i) {
        u32 w = ((const u32*)p)[i];
        fx2 r; r.x = bf2f((u16)(w & 0xffffu)); r.y = bf2f((u16)(w >> 16));
        return r;
    }
    static __device__ __forceinline__ void st2nt(T* p, size_t i, fx2 v) {
        u32 w = (u32)f2bf(v.x) | ((u32)f2bf(v.y) << 16);
        __builtin_nontemporal_store(w, (u32*)p + i);
    }
};

__device__ __forceinline__ void lvl_of_bin(int b, int& lv, int& bl) {
    if (b < NB0) { lv = 0; bl = b; }
    else if (b < NB0 + NB1) { lv = 1; bl = b - NB0; }
    else { lv = 2; bl = b - NB0 - NB1; }
}

// ------------- detect dtype + init cursors + dummy ys rows -------------
__global__ void k_dinit(const u32* __restrict__ xw, int* __restrict__ flag,
                        int* __restrict__ binCursor, u16* __restrict__ y0,
                        u16* __restrict__ y1, u16* __restrict__ y2) {
    __shared__ int cnt;
    int t = threadIdx.x;
    int g = blockIdx.x * 256 + t;
    if (blockIdx.x == 0) {
        if (t == 0) cnt = 0;
        __syncthreads();
        u32 w = xw[t];
        int e = (int)((w >> 7) & 0xFFu);
        int hit = ((e >= 90 && e <= 135) || ((w & 0x7FFFu) == 0u)) ? 1 : 0;
        atomicAdd(&cnt, hit);
        __syncthreads();
        if (t == 0) *flag = (cnt < 192) ? 1 : 0;
    }
    if (g < NBt) binCursor[g] = g * ECAP;     // fixed-capacity BE bases
    if (blockIdx.x == 1 && t < 32) { y0[t] = 0; y1[t] = 0; y2[t] = 0; }
}

// ------------- phase C: hist + reserve + place packed (src<<9 | dstLow) -------------
__global__ void kC_place(const int* __restrict__ ei0, const int* __restrict__ ei1,
                         const int* __restrict__ ei2, int* __restrict__ binCursor,
                         u32* __restrict__ BE) {
    __shared__ int lc[NB0];
    __shared__ int lb[NB0];
    int b = blockIdx.x, t = threadIdx.x;
    int lv, bl; lvl_of_bin(b, lv, bl);
    const int* srcp; const int* dstp; int E, nb, binB;
    if (lv == 0) { srcp = ei0; dstp = ei0 + E0c; E = E0c; nb = NB0; binB = 0; }
    else if (lv == 1) { srcp = ei1; dstp = ei1 + E1c; E = E1c; nb = NB1; binB = NB0; }
    else { srcp = ei2; dstp = ei2 + E2c; E = E2c; nb = NB2; binB = NB0 + NB1; }
    for (int i = t; i < nb; i += 256) lc[i] = 0;
    __syncthreads();
    int e0 = bl * 2048, e1 = min(E, e0 + 2048);
    for (int i = e0 + t; i < e1; i += 256) atomicAdd(&lc[dstp[i] >> 9], 1);
    __syncthreads();
    for (int i = t; i < nb; i += 256) {
        int c = lc[i];
        lb[i] = c ? atomicAdd(&binCursor[binB + i], c) : 0;
        lc[i] = 0;
    }
    __syncthreads();
    for (int i = e0 + t; i < e1; i += 256) {
        int d = dstp[i];
        int bn = d >> 9;
        int p = atomicAdd(&lc[bn], 1);
        BE[lb[bn] + p] = ((u32)srcp[i] << 9) | (u32)(d & 511);
    }
}

// ------------- phase D: counts -> DINV + RPC + COL fill/scatter (fixed regions) -------------
__global__ void kD_all(const u32* __restrict__ BE, const int* __restrict__ binCursor,
                       float* __restrict__ DINV, u32* __restrict__ RPC,
                       int* __restrict__ colAll) {
    __shared__ int lc[512];
    __shared__ int lst[512];
    __shared__ int lcur[512];
    __shared__ int red[256];
    int b = blockIdx.x, t = threadIdx.x;
    int lv, bl; lvl_of_bin(b, lv, bl);
    int cbase, nLev, dummy;
    if (lv == 0) { cbase = 0; nLev = N0c; dummy = N0c; }
    else if (lv == 1) { cbase = N0c; nLev = N1c; dummy = N1c; }
    else { cbase = N0c + N1c; nLev = N2c; dummy = N2c; }
    lc[t] = 0; lc[t + 256] = 0;
    __syncthreads();
    int s0 = b * ECAP, s1 = binCursor[b];
    for (int i = s0 + t; i < s1; i += 256) atomicAdd(&lc[BE[i] & 511u], 1);
    __syncthreads();
    int nodeB = bl << 9;
    int pc[2];
    int ps = 0;
#pragma unroll
    for (int j = 0; j < 2; j++) {
        int li = t * 2 + j;
        int node = nodeB + li;
        int c = (node < nLev) ? lc[li] : 0;
        pc[j] = (c + 3) & ~3;
        ps += pc[j];
    }
    red[t] = ps;
    __syncthreads();
    for (int off = 1; off < 256; off <<= 1) {
        int x = (t >= off) ? red[t - off] : 0;
        __syncthreads();
        red[t] += x;
        __syncthreads();
    }
    int ex = red[t] - ps;
    int tot = red[255];
    int cb = b * CCAP;
    int off = ex;
#pragma unroll
    for (int j = 0; j < 2; j++) {
        int li = t * 2 + j;
        lst[li] = off;
        lcur[li] = off;
        off += pc[j];
    }
    __syncthreads();
#pragma unroll
    for (int j = 0; j < 2; j++) {
        int li = t * 2 + j;
        int node = nodeB + li;
        if (node < nLev) {
            int c = lc[li];
            DINV[cbase + node] = rsqrtf((float)c + 1.0f);
            int rp = cb + lst[li];                    // multiple of 4
            u32 nch = (u32)((c + 3) >> 2);
            RPC[cbase + node] = ((u32)(rp >> 2) << 10) | nch;
        }
    }
    for (int i = t; i < tot; i += 256) colAll[cb + i] = dummy;
    __syncthreads();
    for (int i = s0 + t; i < s1; i += 256) {
        u32 e = BE[i];
        int p = atomicAdd(&lcur[e & 511u], 1);
        colAll[cb + p] = (int)(e >> 9);
    }
}

// ---------------- 2-wide gather core (RPC: packed rowptr|nch) ----------------
__device__ __forceinline__ fx2 gather2(const u16* __restrict__ ys,
                                       const u32* __restrict__ rpc,
                                       const int* __restrict__ col,
                                       const float* __restrict__ dinv,
                                       int node, int cp) {
    u32 v = rpc[node];
    int s0 = (int)((v >> 10) << 2);
    int nch = (int)(v & 1023u);
    fx2 a = BF16S::ld2(ys, (size_t)node * 16 + cp);
    const int4* c4 = (const int4*)(col + s0);
    for (int i = 0; i < nch; i++) {
        int4 cs = c4[i];
        fx2 a0 = BF16S::ld2(ys, (size_t)cs.x * 16 + cp);
        fx2 a1 = BF16S::ld2(ys, (size_t)cs.y * 16 + cp);
        fx2 a2 = BF16S::ld2(ys, (size_t)cs.z * 16 + cp);
        fx2 a3 = BF16S::ld2(ys, (size_t)cs.w * 16 + cp);
        a += (a0 + a1) + (a2 + a3);
    }
    float di = dinv[node];
    a *= di;
    return a;
}

// ---------------- K1: persistent fc1 + relu + prep1 -> bf16 ys (tiled) ----------------
constexpr int FC1_TILES = N0c / 64;   // 5880
__global__ void k_fc1prep(const void* __restrict__ x, const void* __restrict__ fw,
                          const void* __restrict__ fb, const void* __restrict__ w1,
                          const float* __restrict__ d0, u16* __restrict__ ys1,
                          const int* __restrict__ flag) {
    int isf32 = *flag;
    __shared__ float sx[256];
    __shared__ float sh[64 * 33];
    __shared__ float sfw[128];
    __shared__ float sfb[32];
    __shared__ float sw1[1024];
    int t = threadIdx.x;
    stage(sw1, w1, 1024, isf32);
    stage(sfw, fw, 128, isf32);
    stage(sfb, fb, 32, isf32);
    __syncthreads();
    int c = t & 31;
    int ng = t >> 5;       // 0..7
    int ci0 = t & 15;
    int rgrp = t >> 4;     // 0..15
    for (int tile = blockIdx.x; tile < FC1_TILES; tile += gridDim.x) {
        int nodeBase = tile * 64;
        sx[t] = rdf(x, nodeBase * 4 + t, isf32);
        __syncthreads();
#pragma unroll
        for (int i = 0; i < 8; i++) {
            int ln = ng + i * 8;
            float a = sfb[c];
#pragma unroll
            for (int k = 0; k < 4; k++) a = fmaf(sx[ln * 4 + k], sfw[k * 32 + c], a);
            sh[ln * 33 + c] = fmaxf(a, 0.0f);
        }
        __syncthreads();
        float acc[4][2];
#pragma unroll
        for (int r = 0; r < 4; r++) { acc[r][0] = 0.0f; acc[r][1] = 0.0f; }
#pragma unroll
        for (int k = 0; k < 32; k++) {
            float w0 = sw1[k * 32 + ci0];
            float w1v = sw1[k * 32 + ci0 + 16];
#pragma unroll
            for (int r = 0; r < 4; r++) {
                float s = sh[(rgrp * 4 + r) * 33 + k];
                acc[r][0] = fmaf(s, w0, acc[r][0]);
                acc[r][1] = fmaf(s, w1v, acc[r][1]);
            }
        }
#pragma unroll
        for (int r = 0; r < 4; r++) {
            int node = nodeBase + rgrp * 4 + r;
            float dv = d0[node];
            BF16S::st(ys1, (size_t)node * 32 + ci0, acc[r][0] * dv);
            BF16S::st(ys1, (size_t)node * 32 + ci0 + 16, acc[r][1] * dv);
        }
        __syncthreads();
    }
}

// ---------------- K2/K3: NPB nodes/block, gather + relu -> O; fused prep_next ----------------
template <int NPB>
__global__ void k_gds(const u16* __restrict__ ys_in, const u32* __restrict__ rpc,
                      const int* __restrict__ col,
                      const float* __restrict__ dinv_p, const void* __restrict__ b,
                      u16* __restrict__ O, const void* __restrict__ wn,
                      const float* __restrict__ dinv_c, u16* __restrict__ ys_out,
                      int cols, const int* __restrict__ flag) {
    int isf32 = *flag;
    __shared__ float sv[NPB * 32];
    __shared__ float swn[1024];
    int t = threadIdx.x;
    int nodeBase = blockIdx.x * NPB;
    int rb = nodeBase / cols;                    // cols % NPB == 0 -> whole block same row
    if (!(rb & 1)) stage(swn, wn, 1024, isf32);  // block-uniform
    int cp = t & 15;
#pragma unroll
    for (int i = 0; i < NPB / 16; i++) {
        int local = (t >> 4) + i * 16;
        int node = nodeBase + local;
        fx2 g = gather2(ys_in, rpc, col, dinv_p, node, cp);
        fx2 v;
        v.x = fmaxf(g.x + rdf(b, 2 * cp, isf32), 0.0f);
        v.y = fmaxf(g.y + rdf(b, 2 * cp + 1, isf32), 0.0f);
        BF16S::st2nt(O, (size_t)node * 16 + cp, v);
        sv[local * 32 + 2 * cp] = v.x;
        sv[local * 32 + 2 * cp + 1] = v.y;
    }
    __syncthreads();
    if (!(rb & 1)) {
#pragma unroll
        for (int i = 0; i < NPB / 16; i++) {
            int item = t + i * 256;
            int childIdx = item >> 5;        // 0..NPB/2-1
            int ci = item & 31;
            int lc = childIdx * 2;           // even local node
            int cc = (nodeBase - rb * cols) + lc;
            int dn = (rb >> 1) * (cols >> 1) + (cc >> 1);
            float a = 0.0f;
#pragma unroll
            for (int k = 0; k < 32; k++) a = fmaf(sv[lc * 32 + k], swn[k * 32 + ci], a);
            BF16S::st(ys_out, (size_t)dn * 32 + ci, a * dinv_c[dn]);
        }
    }
}

// ---------------- K4/K5: NPB parents/block, gather + up-residual + tiled prep_next ----------------
template <int NPB>
__global__ void k_gup(const u16* __restrict__ ys_in, const u32* __restrict__ rpc,
                      const int* __restrict__ col,
                      const float* __restrict__ dinv_p, const void* __restrict__ b,
                      const u16* __restrict__ R, const void* __restrict__ wn,
                      const float* __restrict__ dinv_c, u16* __restrict__ ys_out,
                      int cols_p, const int* __restrict__ flag) {
    constexpr int RPT = NPB / 4;            // child rows per thread
    int isf32 = *flag;
    __shared__ float sv[NPB * 32];
    __shared__ float sch[NPB * 4 * 33];     // padded child rows
    __shared__ float swn[1024];
    int t = threadIdx.x;
    int nodeBase = blockIdx.x * NPB;
    stage(swn, wn, 1024, isf32);
    if (t < NPB * 16) {
        int local = t >> 4, cp = t & 15;
        int node = nodeBase + local;
        fx2 g = gather2(ys_in, rpc, col, dinv_p, node, cp);
        sv[local * 32 + 2 * cp] = fmaxf(g.x + rdf(b, 2 * cp, isf32), 0.0f);
        sv[local * 32 + 2 * cp + 1] = fmaxf(g.y + rdf(b, 2 * cp + 1, isf32), 0.0f);
    }
    __syncthreads();
    int rb = nodeBase / cols_p;
    int ccb = nodeBase - rb * cols_p;
    int cols_c = cols_p * 2;
#pragma unroll
    for (int i = 0; i < NPB / 2; i++) {
        int item = t + i * 256;
        int row = item >> 5, k = item & 31;
        int lp = row >> 2, j = row & 3;
        int ch = (2 * rb + (j >> 1)) * cols_c + 2 * (ccb + lp) + (j & 1);
        sch[row * 33 + k] = bf2f(R[(size_t)ch * 32 + k]) + sv[lp * 32 + k];
    }
    __syncthreads();
    int ci0 = t & 15;
    int rgrp = t >> 4;   // 0..15
    float acc[RPT][2];
#pragma unroll
    for (int r = 0; r < RPT; r++) { acc[r][0] = 0.0f; acc[r][1] = 0.0f; }
#pragma unroll
    for (int k = 0; k < 32; k++) {
        float w0 = swn[k * 32 + ci0];
        float w1v = swn[k * 32 + ci0 + 16];
#pragma unroll
        for (int r = 0; r < RPT; r++) {
            float s = sch[(rgrp * RPT + r) * 33 + k];
            acc[r][0] = fmaf(s, w0, acc[r][0]);
            acc[r][1] = fmaf(s, w1v, acc[r][1]);
        }
    }
#pragma unroll
    for (int r = 0; r < RPT; r++) {
        int row = rgrp * RPT + r;
        int lp = row >> 2, j = row & 3;
        int ch = (2 * rb + (j >> 1)) * cols_c + 2 * (ccb + lp) + (j & 1);
        float dc = dinv_c[ch];
        BF16S::st(ys_out, (size_t)ch * 32 + ci0, acc[r][0] * dc);
        BF16S::st(ys_out, (size_t)ch * 32 + ci0 + 16, acc[r][1] * dc);
    }
}

// ---------------- K6: 32 nodes/block, gather + relu + fc2 -> out ----------------
__global__ void k_gfc2(const u16* __restrict__ ys, const u32* __restrict__ rpc,
                       const int* __restrict__ col,
                       const float* __restrict__ dinv, const void* __restrict__ b5,
                       const void* __restrict__ fw, const void* __restrict__ fb,
                       void* __restrict__ out, int n, const int* __restrict__ flag) {
    int isf32 = *flag;
    __shared__ float sv[1024];
    __shared__ float sw[96];
    __shared__ float sfb[3];
    int t = threadIdx.x;
    if (t < 96) sw[t] = rdf(fw, t, isf32);
    if (t < 3) sfb[t] = rdf(fb, t, isf32);
    int nodeBase = blockIdx.x * 32;
    int cp = t & 15;
#pragma unroll
    for (int i = 0; i < 2; i++) {
        int local = (t >> 4) + i * 16;
        int node = nodeBase + local;
        fx2 g = gather2(ys, rpc, col, dinv, node, cp);
        sv[local * 32 + 2 * cp] = fmaxf(g.x + rdf(b5, 2 * cp, isf32), 0.0f);
        sv[local * 32 + 2 * cp + 1] = fmaxf(g.y + rdf(b5, 2 * cp + 1, isf32), 0.0f);
    }
    __syncthreads();
    if (t < 96) {
        int ln = t / 3, j = t - ln * 3;
        int gn = nodeBase + ln;
        float o = sfb[j];
#pragma unroll
        for (int k = 0; k < 32; k++) o = fmaf(sv[ln * 32 + k], sw[k * 3 + j], o);
        if (isf32) ((float*)out)[(size_t)gn * 3 + j] = o;
        else ((u16*)out)[(size_t)gn * 3 + j] = f2bf(o);
    }
}

extern "C" void kernel_launch(void* const* d_in, const int* in_sizes, int n_in,
                              void* d_out, int out_size, void* d_ws, size_t ws_size,
                              hipStream_t stream) {
    const void* x    = d_in[0];
    const void* fc1w = d_in[1];
    const void* fc1b = d_in[2];
    const void* w1 = d_in[3];  const void* b1 = d_in[4];
    const void* w2 = d_in[5];  const void* b2 = d_in[6];
    const void* w3 = d_in[7];  const void* b3 = d_in[8];
    const void* w4 = d_in[9];  const void* b4 = d_in[10];
    const void* w5 = d_in[11]; const void* b5 = d_in[12];
    const void* fc2w = d_in[13]; const void* fc2b = d_in[14];
    const int* ei0 = (const int*)d_in[18];
    const int* ei1 = (const int*)d_in[19];
    const int* ei2 = (const int*)d_in[20];

    u16* YS0 = (u16*)d_ws;                                  // (N0+1)*32
    u16* A   = YS0 + (size_t)(N0c + 1) * 32;                // N0*32  (h_b residual)
    u16* YS1 = A + (size_t)N0c * 32;                        // (N1+1)*32
    u16* H1  = YS1 + (size_t)(N1c + 1) * 32;                // N1*32  (h1_b residual)
    u16* YS2 = H1 + (size_t)N1c * 32;                       // (N2+1)*32
    float* DINV = (float*)(YS2 + (size_t)(N2c + 1) * 32);   // NT
    u32* RPC  = (u32*)(DINV + NTc);                         // NT
    int* COLA = (int*)(RPC + NTc);                          // NBt*CCAP
    u32* BE   = (u32*)(COLA + (size_t)NBt * CCAP);          // NBt*ECAP
    int* binCursor = (int*)(BE + (size_t)NBt * ECAP);       // NBt
    int* FLAG      = binCursor + NBt;

    float* D0 = DINV; float* D1 = D0 + N0c; float* D2 = D1 + N1c;
    u32* RPC0 = RPC; u32* RPC1 = RPC0 + N0c; u32* RPC2 = RPC1 + N1c;

    const int Bk = 256;

    k_dinit<<<4, Bk, 0, stream>>>((const u32*)x, FLAG, binCursor,
                                  YS0 + (size_t)N0c * 32, YS1 + (size_t)N1c * 32,
                                  YS2 + (size_t)N2c * 32);
    kC_place<<<NBt, Bk, 0, stream>>>(ei0, ei1, ei2, binCursor, BE);
    kD_all<<<NBt, Bk, 0, stream>>>(BE, binCursor, DINV, RPC, COLA);

    // K1: persistent fc1+relu+prep1 -> YS0
    k_fc1prep<<<1960, Bk, 0, stream>>>(x, fc1w, fc1b, w1, D0, YS0, FLAG);
    // K2: gather1 -> A, fused prep2 -> YS1
    k_gds<32><<<N0c / 32, Bk, 0, stream>>>(YS0, RPC0, COLA, D0, b1, A, w2, D1, YS1, NYg, FLAG);
    // K3: gather2 -> H1, fused prep3 -> YS2
    k_gds<16><<<N1c / 16, Bk, 0, stream>>>(YS1, RPC1, COLA, D1, b2, H1, w3, D2, YS2, NYg / 2, FLAG);
    // K4: gather3 + up-residual(H1) + prep4 -> YS1; 8 parents
    k_gup<8><<<N2c / 8, Bk, 0, stream>>>(YS2, RPC2, COLA, D2, b3, H1, w4, D1, YS1, NYg / 4, FLAG);
    // K5: gather4 + up-residual(A) + prep5 -> YS0; 16 parents
    k_gup<16><<<N1c / 16, Bk, 0, stream>>>(YS1, RPC1, COLA, D1, b4, A, w5, D0, YS0, NYg / 2, FLAG);
    // K6: gather5 + fc2 -> out
    k_gfc2<<<N0c / 32, Bk, 0, stream>>>(YS0, RPC0, COLA, D0, b5, fc2w, fc2b, d_out, N0c, FLAG);
}